// Round 1
// 54333.502 us; speedup vs baseline: 1.0545x; 1.0545x over previous
//
#include <hip/hip_runtime.h>

typedef unsigned short u16;
typedef unsigned int   u32;

#define SCALE_F 0.08838834764831845f  // 1/sqrt(128)

// ---------- ws layout (float offsets) ----------
#define O_QUERY  0           // 512
#define O_NQ     512         // 512
#define O_WK     1024        // 2048
#define O_KB     3072        // 4  (flag at int ofs 3080, nan counter at 3081, grid barrier at 3082)
#define O_FLAG   3080
#define O_AV     4096        // 64*4*512 = 131072
#define O_HEAD   135168      // 64*512  = 32768
#define O_CTXT   167936      // 512*64  = 32768  (contextT[i][b])
#define O_EMBG   200704      // 4096*34 = 139264
#define O_CTXG   339968      // 4096*64 = 262144
#define O_CTXP1  602112      // 512*64  = 32768
#define O_H0T    634880      // 2 * 1024*64 = 131072
#define O_C0T    765952      // 1024*64 = 65536
#define O_H1T    831488      // 2 * 1024*64 = 131072
#define O_C1T    962560      // 65536
#define O_H2T    1028096     // 2 * 512*64 = 65536
#define O_C2T    1093632     // 32768
#define O_YT     1126400     // 32768
#define O_LABT   1159168     // 255*64 ints = 16320
#define O_CANON  1175552     // canonical bf16 weights start (u16 ofs = 2*O_CANON)

__device__ __forceinline__ float bfc(u16 x) {
    return __uint_as_float(((u32)x) << 16);
}
__device__ __forceinline__ float2 bfpair(u32 u) {
    return make_float2(__uint_as_float(u << 16), __uint_as_float(u & 0xffff0000u));
}
__device__ __forceinline__ u16 f2bf(float f) {
    u32 u = __float_as_uint(f);
    u += 0x7fffu + ((u >> 16) & 1u);
    return (u16)(u >> 16);
}
__device__ __forceinline__ float sigf(float x) { return 1.0f / (1.0f + __expf(-x)); }
__device__ __forceinline__ float tanh_(float x) { return 2.0f / (1.0f + __expf(-2.0f * x)) - 1.0f; }

__device__ __forceinline__ void fma8(float& acc, uint4 a, const float h[8]) {
    float2 p;
    p = bfpair(a.x); acc = fmaf(h[0], p.x, acc); acc = fmaf(h[1], p.y, acc);
    p = bfpair(a.y); acc = fmaf(h[2], p.x, acc); acc = fmaf(h[3], p.y, acc);
    p = bfpair(a.z); acc = fmaf(h[4], p.x, acc); acc = fmaf(h[5], p.y, acc);
    p = bfpair(a.w); acc = fmaf(h[6], p.x, acc); acc = fmaf(h[7], p.y, acc);
}

// ---------------- dtype detect + canonicalize ----------------

__global__ __launch_bounds__(256) void las_detect(const u16* w, int* flag) {
    __shared__ int s[256];
    int bad = 0;
    for (int i = threadIdx.x; i < 65536; i += 256) {
        u16 v = w[i];
        if ((v & 0x7F80u) == 0x7F80u) bad++;                  // inf/NaN pattern
        else if (fabsf(bfc(v)) > 1e4f) bad++;                 // absurd magnitude
    }
    s[threadIdx.x] = bad; __syncthreads();
    for (int o = 128; o; o >>= 1) {
        if (threadIdx.x < o) s[threadIdx.x] += s[threadIdx.x + o];
        __syncthreads();
    }
    if (threadIdx.x == 0) { flag[0] = (s[0] == 0) ? 1 : 0; flag[1] = 0; flag[2] = 0; }
}

#define NSEG 32
struct Cvt {
    const void* src[NSEG];
    unsigned ofs[NSEG + 1];   // padded cumulative offsets (u16 units, each 8-aligned)
    unsigned len[NSEG];       // true element counts (all even)
};

__global__ __launch_bounds__(256) void las_convert(Cvt c, const int* flag, u16* dst) {
    int isb = flag[0];
    unsigned total = c.ofs[NSEG] >> 1;   // u16 pairs
    for (unsigned p = blockIdx.x * 256 + threadIdx.x; p < total; p += gridDim.x * 256) {
        unsigned e = p << 1;
        int lo = 0, hi = NSEG;
        while (hi - lo > 1) { int mid = (lo + hi) >> 1; if (c.ofs[mid] <= e) lo = mid; else hi = mid; }
        unsigned local = e - c.ofs[lo];
        u32 out;
        if (local >= c.len[lo]) {
            out = 0;                                          // padding
        } else if (isb) {
            out = ((const u32*)c.src[lo])[local >> 1];        // plain bf16 copy
        } else {
            const float* s = (const float*)c.src[lo];
            u32 a = f2bf(s[local]), b = f2bf(s[local + 1]);
            out = a | (b << 16);
        }
        ((u32*)dst)[p] = out;
    }
}

// ---------------- one-time kernels (all read canonical bf16) ----------------

__global__ __launch_bounds__(256) void las_init(
    const u16* h00, const u16* c00, const u16* h01, const u16* c01,
    const u16* h02, const u16* c02, const int* label,
    float* h0T0, float* c0T, float* h1T0, float* c1T, float* h2T0, float* c2T, int* labT) {
    int idx = blockIdx.x * 256 + threadIdx.x;   // 65536 threads
    int j = idx >> 6, b = idx & 63;
    h0T0[idx] = bfc(h00[j]); c0T[idx] = bfc(c00[j]);
    h1T0[idx] = bfc(h01[j]); c1T[idx] = bfc(c01[j]);
    if (j < 512) { h2T0[idx] = bfc(h02[j]); c2T[idx] = bfc(c02[j]); }
    if (j < 255) { labT[idx] = label[b * 256 + j]; }
}

__global__ __launch_bounds__(256) void las_query(const u16* h02, const u16* W_query,
                                                 const u16* b_query, float* query) {
    int i = blockIdx.x * 256 + threadIdx.x;     // < 512
    float acc = bfc(b_query[i]);
    const u32* wr = (const u32*)(W_query + (size_t)i * 512);
    const u32* hp = (const u32*)h02;
    for (int h = 0; h < 512; h += 8) {
        uint4 wv = *(const uint4*)(wr + (h >> 1));
        uint4 hv = *(const uint4*)(hp + (h >> 1));
        float2 a, c;
        a = bfpair(wv.x); c = bfpair(hv.x); acc = fmaf(a.x, c.x, acc); acc = fmaf(a.y, c.y, acc);
        a = bfpair(wv.y); c = bfpair(hv.y); acc = fmaf(a.x, c.x, acc); acc = fmaf(a.y, c.y, acc);
        a = bfpair(wv.z); c = bfpair(hv.z); acc = fmaf(a.x, c.x, acc); acc = fmaf(a.y, c.y, acc);
        a = bfpair(wv.w); c = bfpair(hv.w); acc = fmaf(a.x, c.x, acc); acc = fmaf(a.y, c.y, acc);
    }
    query[i] = acc;
}

__global__ __launch_bounds__(256) void las_nq(const float* query, const u16* Wq,
                                              const u16* bq, float* nq) {
    int nd = blockIdx.x * 256 + threadIdx.x;    // < 512
    float acc = bfc(bq[nd]);
    const u32* wr = (const u32*)(Wq + (size_t)nd * 512);
    for (int h = 0; h < 512; h += 8) {
        uint4 wv = *(const uint4*)(wr + (h >> 1));
        float2 p;
        p = bfpair(wv.x); acc = fmaf(p.x, query[h + 0], acc); acc = fmaf(p.y, query[h + 1], acc);
        p = bfpair(wv.y); acc = fmaf(p.x, query[h + 2], acc); acc = fmaf(p.y, query[h + 3], acc);
        p = bfpair(wv.z); acc = fmaf(p.x, query[h + 4], acc); acc = fmaf(p.y, query[h + 5], acc);
        p = bfpair(wv.w); acc = fmaf(p.x, query[h + 6], acc); acc = fmaf(p.y, query[h + 7], acc);
    }
    nq[nd] = acc;
}

__global__ __launch_bounds__(256) void las_wk(const float* nq, const u16* Wk, const u16* bk,
                                              float* wk, float* kb) {
    int idx = blockIdx.x * 256 + threadIdx.x;   // < 2048
    int n = idx >> 9, h = idx & 511;
    float acc = 0.0f;
    for (int d = 0; d < 128; d++)
        acc = fmaf(nq[n * 128 + d], bfc(Wk[((size_t)(n * 128 + d)) * 512 + h]), acc);
    wk[idx] = acc;
    if (idx < 4) {
        float kk = 0.0f;
        for (int d = 0; d < 128; d++) kk = fmaf(nq[idx * 128 + d], bfc(bk[idx * 128 + d]), kk);
        kb[idx] = kk;
    }
}

__global__ __launch_bounds__(256) void las_attn(const void* keysv, const void* valuesv,
                                                const int* input_len, const int* flag,
                                                const float* wk, const float* kb, float* av) {
    __shared__ float wk_s[2048];
    __shared__ float kb_s[4];
    __shared__ float sm[4][1024];
    __shared__ float red[256];
    __shared__ float stat[4];
    const u16* keysB = (const u16*)keysv;
    const float* keysF = (const float*)keysv;
    const u16* valB = (const u16*)valuesv;
    const float* valF = (const float*)valuesv;
    int b = blockIdx.x;
    int tid = threadIdx.x;
    int isb = flag[0];
    for (int i = tid; i < 2048; i += 256) wk_s[i] = wk[i];
    if (tid < 4) kb_s[tid] = kb[tid];
    __syncthreads();
    int len = input_len[b];

    {
        float acc[4][4];
#pragma unroll
        for (int tl = 0; tl < 4; tl++)
#pragma unroll
            for (int n = 0; n < 4; n++) acc[tl][n] = kb_s[n];
        for (int h = 0; h < 512; h += 8) {
            float kf[4][8];
#pragma unroll
            for (int tl = 0; tl < 4; tl++) {
                int t = tid + 256 * tl;
                size_t base = ((size_t)t * 64 + b) * 512 + h;
                if (isb) {
                    uint4 kv = *(const uint4*)(keysB + base);
                    float2 p;
                    p = bfpair(kv.x); kf[tl][0] = p.x; kf[tl][1] = p.y;
                    p = bfpair(kv.y); kf[tl][2] = p.x; kf[tl][3] = p.y;
                    p = bfpair(kv.z); kf[tl][4] = p.x; kf[tl][5] = p.y;
                    p = bfpair(kv.w); kf[tl][6] = p.x; kf[tl][7] = p.y;
                } else {
                    const float4* kp = (const float4*)(keysF + base);
                    float4 q0 = kp[0], q1 = kp[1];
                    kf[tl][0] = q0.x; kf[tl][1] = q0.y; kf[tl][2] = q0.z; kf[tl][3] = q0.w;
                    kf[tl][4] = q1.x; kf[tl][5] = q1.y; kf[tl][6] = q1.z; kf[tl][7] = q1.w;
                }
            }
#pragma unroll
            for (int i = 0; i < 8; i++) {
                float w0 = wk_s[h + i], w1 = wk_s[512 + h + i];
                float w2 = wk_s[1024 + h + i], w3 = wk_s[1536 + h + i];
#pragma unroll
                for (int tl = 0; tl < 4; tl++) {
                    acc[tl][0] = fmaf(kf[tl][i], w0, acc[tl][0]);
                    acc[tl][1] = fmaf(kf[tl][i], w1, acc[tl][1]);
                    acc[tl][2] = fmaf(kf[tl][i], w2, acc[tl][2]);
                    acc[tl][3] = fmaf(kf[tl][i], w3, acc[tl][3]);
                }
            }
        }
#pragma unroll
        for (int tl = 0; tl < 4; tl++) {
            int t = tid + 256 * tl;
#pragma unroll
            for (int n = 0; n < 4; n++)
                sm[n][t] = (t < len) ? acc[tl][n] * SCALE_F : -1e30f;
        }
    }
    __syncthreads();

    for (int n = 0; n < 4; n++) {
        float m = -1e30f;
        for (int tl = 0; tl < 4; tl++) m = fmaxf(m, sm[n][tid + 256 * tl]);
        red[tid] = m; __syncthreads();
        for (int off = 128; off; off >>= 1) {
            if (tid < off) red[tid] = fmaxf(red[tid], red[tid + off]);
            __syncthreads();
        }
        m = red[0]; __syncthreads();
        float e = 0.0f;
        for (int tl = 0; tl < 4; tl++) {
            int t = tid + 256 * tl;
            float x = (t < len) ? __expf(sm[n][t] - m) : 0.0f;
            sm[n][t] = x; e += x;
        }
        red[tid] = e; __syncthreads();
        for (int off = 128; off; off >>= 1) {
            if (tid < off) red[tid] += red[tid + off];
            __syncthreads();
        }
        if (tid == 0) stat[n] = 1.0f / red[0];
        __syncthreads();
    }

    {
        float a[4][2] = {};
        int h0 = 2 * tid;
        for (int t = 0; t < len; t++) {
            size_t base = ((size_t)t * 64 + b) * 512 + h0;
            float2 p;
            if (isb) p = bfpair(*(const u32*)(valB + base));
            else     p = *(const float2*)(valF + base);
            float s0 = sm[0][t], s1 = sm[1][t], s2 = sm[2][t], s3 = sm[3][t];
            a[0][0] = fmaf(s0, p.x, a[0][0]); a[0][1] = fmaf(s0, p.y, a[0][1]);
            a[1][0] = fmaf(s1, p.x, a[1][0]); a[1][1] = fmaf(s1, p.y, a[1][1]);
            a[2][0] = fmaf(s2, p.x, a[2][0]); a[2][1] = fmaf(s2, p.y, a[2][1]);
            a[3][0] = fmaf(s3, p.x, a[3][0]); a[3][1] = fmaf(s3, p.y, a[3][1]);
        }
#pragma unroll
        for (int n = 0; n < 4; n++) {
            av[((size_t)b * 4 + n) * 512 + h0]     = a[n][0] * stat[n];
            av[((size_t)b * 4 + n) * 512 + h0 + 1] = a[n][1] * stat[n];
        }
    }
}

__global__ __launch_bounds__(256) void las_head(const float* av, const u16* Wv, const u16* bv,
                                                float* head) {
    int idx = blockIdx.x * 256 + threadIdx.x;   // < 32768
    int b = idx >> 9, nd = idx & 511, n = nd >> 7;
    float acc = bfc(bv[nd]);
    const u32* wr = (const u32*)(Wv + (size_t)nd * 512);
    const float* ap = av + ((size_t)b * 4 + n) * 512;
    for (int h = 0; h < 512; h += 8) {
        uint4 wv = *(const uint4*)(wr + (h >> 1));
        float2 p;
        p = bfpair(wv.x); acc = fmaf(p.x, ap[h + 0], acc); acc = fmaf(p.y, ap[h + 1], acc);
        p = bfpair(wv.y); acc = fmaf(p.x, ap[h + 2], acc); acc = fmaf(p.y, ap[h + 3], acc);
        p = bfpair(wv.z); acc = fmaf(p.x, ap[h + 4], acc); acc = fmaf(p.y, ap[h + 5], acc);
        p = bfpair(wv.w); acc = fmaf(p.x, ap[h + 6], acc); acc = fmaf(p.y, ap[h + 7], acc);
    }
    head[idx] = acc;
}

__global__ __launch_bounds__(256) void las_ctx(const float* head, const u16* W_mh, const u16* b_mh,
                                               float* ctxT) {
    int idx = blockIdx.x * 256 + threadIdx.x;   // < 32768
    int b = idx >> 9, i = idx & 511;
    float acc = bfc(b_mh[i]);
    const u32* wr = (const u32*)(W_mh + (size_t)i * 512);
    const float* hp = head + (size_t)b * 512;
    for (int h = 0; h < 512; h += 8) {
        uint4 wv = *(const uint4*)(wr + (h >> 1));
        float2 p;
        p = bfpair(wv.x); acc = fmaf(p.x, hp[h + 0], acc); acc = fmaf(p.y, hp[h + 1], acc);
        p = bfpair(wv.y); acc = fmaf(p.x, hp[h + 2], acc); acc = fmaf(p.y, hp[h + 3], acc);
        p = bfpair(wv.z); acc = fmaf(p.x, hp[h + 4], acc); acc = fmaf(p.y, hp[h + 5], acc);
        p = bfpair(wv.w); acc = fmaf(p.x, hp[h + 6], acc); acc = fmaf(p.y, hp[h + 7], acc);
    }
    ctxT[(size_t)i * 64 + b] = acc;
}

__global__ __launch_bounds__(256) void las_embg(const u16* W_emb, const u16* Wih0, float* embg) {
    int idx = blockIdx.x * 256 + threadIdx.x;
    if (idx >= 4096 * 34) return;
    int row = idx / 34, v = idx - row * 34;
    const u32* wr = (const u32*)(Wih0 + (size_t)row * 1024);  // x-part: first 512 cols
    const u32* er = (const u32*)(W_emb + (size_t)v * 512);
    float acc = 0.0f;
    for (int h = 0; h < 512; h += 8) {
        uint4 wv = *(const uint4*)(wr + (h >> 1));
        uint4 ev = *(const uint4*)(er + (h >> 1));
        float2 a, c;
        a = bfpair(wv.x); c = bfpair(ev.x); acc = fmaf(a.x, c.x, acc); acc = fmaf(a.y, c.y, acc);
        a = bfpair(wv.y); c = bfpair(ev.y); acc = fmaf(a.x, c.x, acc); acc = fmaf(a.y, c.y, acc);
        a = bfpair(wv.z); c = bfpair(ev.z); acc = fmaf(a.x, c.x, acc); acc = fmaf(a.y, c.y, acc);
        a = bfpair(wv.w); c = bfpair(ev.w); acc = fmaf(a.x, c.x, acc); acc = fmaf(a.y, c.y, acc);
    }
    embg[idx] = acc;
}

__global__ __launch_bounds__(256) void las_ctxg(const float* ctxT, const u16* Wih0,
                                                const u16* bih0, const u16* bhh0, float* ctxg) {
    int lane = threadIdx.x & 63, w = threadIdx.x >> 6;
    int row = blockIdx.x * 4 + w;               // < 4096
    float acc = bfc(bih0[row]) + bfc(bhh0[row]);
    const u32* wr = (const u32*)(Wih0 + (size_t)row * 1024 + 512);  // context-part
    for (int h = 0; h < 512; h += 8) {
        float hv[8];
#pragma unroll
        for (int i = 0; i < 8; i++) hv[i] = ctxT[(size_t)(h + i) * 64 + lane];
        uint4 wv = *(const uint4*)(wr + (h >> 1));
        fma8(acc, wv, hv);
    }
    ctxg[(size_t)row * 64 + lane] = acc;
}

__global__ __launch_bounds__(256) void las_ctxp1(const float* ctxT, const u16* W_p1,
                                                 const u16* b_p1, float* ctxp1) {
    int lane = threadIdx.x & 63, w = threadIdx.x >> 6;
    int i = blockIdx.x * 4 + w;                 // < 512
    float acc = bfc(b_p1[i]);
    const u32* wr = (const u32*)(W_p1 + (size_t)i * 1024 + 512);
    for (int h = 0; h < 512; h += 8) {
        float hv[8];
#pragma unroll
        for (int k = 0; k < 8; k++) hv[k] = ctxT[(size_t)(h + k) * 64 + lane];
        uint4 wv = *(const uint4*)(wr + (h >> 1));
        fma8(acc, wv, hv);
    }
    ctxp1[(size_t)i * 64 + lane] = acc;
}

// ---------------- persistent decode kernel ----------------
// 256 blocks x 256 threads; 158KB LDS forces 1 block/CU; grid == #CUs so all
// blocks are co-resident -> device-scope atomic grid barrier is safe.
// Weights for l0/l1/l2 are staged to LDS ONCE and reused for all 255 steps.
// Activations are staged per-block into LDS in 128-k chunks (coalesced).
// Cell states c0/c1/c2 live in registers for the entire loop.
// 3 grid barriers per step; p3(t-1) runs on blocks 0..63 shadowed under l0(t).

__device__ __forceinline__ void gridbar(int* ctr, int target) {
    __syncthreads();
    if (threadIdx.x == 0) {
        __threadfence();                       // publish this block's writes
        atomicAdd(ctr, 1);
        int iters = 0;
        while (atomicAdd(ctr, 0) < target) {   // device-scope coherent poll
            __builtin_amdgcn_s_sleep(4);
            if (++iters > (1 << 20)) break;    // bounded: corrupts (absmax) instead of hanging
        }
        __threadfence();                       // acquire others' writes
    }
    __syncthreads();
}

__global__ __launch_bounds__(256, 1) void las_decode(
    const float* embg, const float* ctxg, const float* ctxp1, const int* labT,
    const u16* Whh0, const u16* Wih1, const u16* Whh1,
    const u16* bih1, const u16* bhh1,
    const u16* Wih2, const u16* Whh2, const u16* bih2, const u16* bhh2,
    const u16* W_p1, const u16* W_emb, const u16* b_proj2,
    const u16* c00, const u16* c01, const u16* c02,
    float* h0a, float* h0b, float* h1a, float* h1b, float* h2a, float* h2b,
    const int* flag, int* bar, void* outp) {

    __shared__ __align__(16) u16 w0s[16][1024];     // 32 KB  Whh0 rows {g*1024 + bx*4 + w}
    __shared__ __align__(16) u16 w1s[16][2048];     // 64 KB  Wih1|Whh1 rows
    __shared__ __align__(16) u16 w2s[8][1536];      // 24 KB  Wih2|Whh2 rows {g*512 + bx*2 + jj}
    __shared__ __align__(16) float hs[8192];        // 32 KB  activation chunk [128 k][64 b]
    __shared__ float gbuf[4][2][64];                //  2 KB  l2 gate exchange

    const int tid = threadIdx.x, lane = tid & 63, w = tid >> 6;
    const int bx = blockIdx.x;
    const int isb = flag[0];
    const int j = bx * 4 + w;                       // l0/l1 j-index (0..1023)

    // ---- stage weights to LDS (once) ----
    for (int i = tid; i < 2048; i += 256) {         // w0s: 2048 uint4
        int rl = i >> 7, kk = (i & 127) << 3;
        int grow = (rl >> 2) * 1024 + bx * 4 + (rl & 3);
        *(uint4*)&w0s[rl][kk] = *(const uint4*)(Whh0 + (size_t)grow * 1024 + kk);
    }
    for (int i = tid; i < 4096; i += 256) {         // w1s: 4096 uint4
        int rl = i >> 8, kk = (i & 255) << 3;
        int grow = (rl >> 2) * 1024 + bx * 4 + (rl & 3);
        const u16* src = (kk < 1024) ? (Wih1 + (size_t)grow * 1024 + kk)
                                     : (Whh1 + (size_t)grow * 1024 + (kk - 1024));
        *(uint4*)&w1s[rl][kk] = *(const uint4*)src;
    }
    for (int i = tid; i < 1536; i += 256) {         // w2s: 1536 uint4
        int rl = i / 192, kk = (i - rl * 192) << 3;
        int grow = (rl >> 1) * 512 + bx * 2 + (rl & 1);
        const u16* src = (kk < 1024) ? (Wih2 + (size_t)grow * 1024 + kk)
                                     : (Whh2 + (size_t)grow * 512 + (kk - 1024));
        *(uint4*)&w2s[rl][kk] = *(const uint4*)src;
    }

    // ---- persistent per-thread state ----
    float c0reg = bfc(c00[j]);
    float c1reg = bfc(c01[j]);
    float b1b0 = bfc(bih1[j])        + bfc(bhh1[j]);
    float b1b1 = bfc(bih1[1024 + j]) + bfc(bhh1[1024 + j]);
    float b1b2 = bfc(bih1[2048 + j]) + bfc(bhh1[2048 + j]);
    float b1b3 = bfc(bih1[3072 + j]) + bfc(bhh1[3072 + j]);
    float b2b0, b2b1;
    {
        int r0 = w * 512 + bx * 2 + 0, r1 = w * 512 + bx * 2 + 1;
        b2b0 = bfc(bih2[r0]) + bfc(bhh2[r0]);
        b2b1 = bfc(bih2[r1]) + bfc(bhh2[r1]);
    }
    float c2reg = (w < 2) ? bfc(c02[bx * 2 + w]) : 0.0f;

    float* h0buf[2] = { h0a, h0b };
    float* h1buf[2] = { h1a, h1b };
    float* h2buf[2] = { h2a, h2b };

    __syncthreads();

    // ---- fused p3a+p3b for one batch (blocks 0..63), uses hs as scratch ----
    auto p3 = [&](int tp, const float* h2c) {
        float* ph2 = hs;          // [512] h2 column for batch bx
        float* py  = hs + 512;    // [512] y
        __syncthreads();
        for (int i = tid; i < 512; i += 256) ph2[i] = h2c[(size_t)i * 64 + bx];
        __syncthreads();
        for (int i = tid; i < 512; i += 256) {
            float acc = ctxp1[(size_t)i * 64 + bx];
            const u32* wr = (const u32*)(W_p1 + (size_t)i * 1024);  // h2-part: first 512 cols
            for (int k = 0; k < 512; k += 8) {
                float h[8];
#pragma unroll
                for (int q = 0; q < 8; q++) h[q] = ph2[k + q];
                uint4 wv = *(const uint4*)(wr + (k >> 1));
                fma8(acc, wv, h);
            }
            py[i] = acc > 0.0f ? acc : 0.01f * acc;              // leaky_relu
        }
        __syncthreads();
        if (w == 0) {
            int v = lane;
            float acc = -1e30f;
            if (v < 34) {
                acc = bfc(b_proj2[v]);
                const u32* wr = (const u32*)(W_emb + (size_t)v * 512);
                for (int k = 0; k < 512; k += 8) {
                    uint4 wv = *(const uint4*)(wr + (k >> 1));
                    float2 p;
                    p = bfpair(wv.x); acc = fmaf(p.x, py[k + 0], acc); acc = fmaf(p.y, py[k + 1], acc);
                    p = bfpair(wv.y); acc = fmaf(p.x, py[k + 2], acc); acc = fmaf(p.y, py[k + 3], acc);
                    p = bfpair(wv.z); acc = fmaf(p.x, py[k + 4], acc); acc = fmaf(p.y, py[k + 5], acc);
                    p = bfpair(wv.w); acc = fmaf(p.x, py[k + 6], acc); acc = fmaf(p.y, py[k + 7], acc);
                }
            }
            float m = acc;
            for (int off = 32; off; off >>= 1) m = fmaxf(m, __shfl_xor(m, off, 64));
            float e = (v < 34) ? __expf(acc - m) : 0.0f;
            float s = e;
            for (int off = 32; off; off >>= 1) s += __shfl_xor(s, off, 64);
            if (v < 34) {
                float r = acc - m - __logf(s);
                size_t o = ((size_t)bx * 255 + tp) * 34 + v;
                if (isb) ((u16*)outp)[o] = f2bf(r);
                else     ((float*)outp)[o] = r;
            }
        }
        // no trailing sync needed: next hs use begins with __syncthreads
    };

    int bcnt = 0;
    for (int t = 0; t < 255; t++) {
        const int cc = t & 1, nn = cc ^ 1;

        // ==== Phase A: p3(t-1) on blocks<64 (shadowed), then l0(t) on all ====
        if (bx < 64 && t > 0) p3(t - 1, h2buf[cc]);
        {
            const float* hc = h0buf[cc];
            int vb = labT[t * 64 + lane];
            float a0 = embg[(size_t)j * 34 + vb]          + ctxg[(size_t)j * 64 + lane];
            float a1 = embg[(size_t)(1024 + j) * 34 + vb] + ctxg[(size_t)(1024 + j) * 64 + lane];
            float a2 = embg[(size_t)(2048 + j) * 34 + vb] + ctxg[(size_t)(2048 + j) * 64 + lane];
            float a3 = embg[(size_t)(3072 + j) * 34 + vb] + ctxg[(size_t)(3072 + j) * 64 + lane];
            for (int kc = 0; kc < 1024; kc += 128) {
                __syncthreads();
                const float4* src = (const float4*)(hc + (size_t)kc * 64);
                float4* dst = (float4*)hs;
#pragma unroll
                for (int i = 0; i < 8; i++) dst[tid + 256 * i] = src[tid + 256 * i];
                __syncthreads();
#pragma unroll 2
                for (int k = 0; k < 128; k += 8) {
                    float h[8];
#pragma unroll
                    for (int i = 0; i < 8; i++) h[i] = hs[(k + i) * 64 + lane];
                    uint4 q0 = *(const uint4*)&w0s[w][kc + k];
                    uint4 q1 = *(const uint4*)&w0s[4 + w][kc + k];
                    uint4 q2 = *(const uint4*)&w0s[8 + w][kc + k];
                    uint4 q3 = *(const uint4*)&w0s[12 + w][kc + k];
                    fma8(a0, q0, h); fma8(a1, q1, h); fma8(a2, q2, h); fma8(a3, q3, h);
                }
            }
            float c2v = fmaf(sigf(a1), c0reg, sigf(a0) * tanh_(a2));
            c0reg = c2v;
            h0buf[nn][(size_t)j * 64 + lane] = sigf(a3) * tanh_(c2v);
        }
        bcnt += 256; gridbar(bar, bcnt);

        // ==== Phase B: l1(t) ====
        {
            const float* hx = h0buf[nn];
            const float* hh = h1buf[cc];
            float a0 = b1b0, a1 = b1b1, a2 = b1b2, a3 = b1b3;
            for (int kc = 0; kc < 1024; kc += 128) {
                __syncthreads();
                const float4* src = (const float4*)(hx + (size_t)kc * 64);
                float4* dst = (float4*)hs;
#pragma unroll
                for (int i = 0; i < 8; i++) dst[tid + 256 * i] = src[tid + 256 * i];
                __syncthreads();
#pragma unroll 2
                for (int k = 0; k < 128; k += 8) {
                    float h[8];
#pragma unroll
                    for (int i = 0; i < 8; i++) h[i] = hs[(k + i) * 64 + lane];
                    uint4 q0 = *(const uint4*)&w1s[w][kc + k];
                    uint4 q1 = *(const uint4*)&w1s[4 + w][kc + k];
                    uint4 q2 = *(const uint4*)&w1s[8 + w][kc + k];
                    uint4 q3 = *(const uint4*)&w1s[12 + w][kc + k];
                    fma8(a0, q0, h); fma8(a1, q1, h); fma8(a2, q2, h); fma8(a3, q3, h);
                }
            }
            for (int kc = 0; kc < 1024; kc += 128) {
                __syncthreads();
                const float4* src = (const float4*)(hh + (size_t)kc * 64);
                float4* dst = (float4*)hs;
#pragma unroll
                for (int i = 0; i < 8; i++) dst[tid + 256 * i] = src[tid + 256 * i];
                __syncthreads();
#pragma unroll 2
                for (int k = 0; k < 128; k += 8) {
                    float h[8];
#pragma unroll
                    for (int i = 0; i < 8; i++) h[i] = hs[(k + i) * 64 + lane];
                    uint4 q0 = *(const uint4*)&w1s[w][1024 + kc + k];
                    uint4 q1 = *(const uint4*)&w1s[4 + w][1024 + kc + k];
                    uint4 q2 = *(const uint4*)&w1s[8 + w][1024 + kc + k];
                    uint4 q3 = *(const uint4*)&w1s[12 + w][1024 + kc + k];
                    fma8(a0, q0, h); fma8(a1, q1, h); fma8(a2, q2, h); fma8(a3, q3, h);
                }
            }
            float c2v = fmaf(sigf(a1), c1reg, sigf(a0) * tanh_(a2));
            c1reg = c2v;
            h1buf[nn][(size_t)j * 64 + lane] = sigf(a3) * tanh_(c2v);
        }
        bcnt += 256; gridbar(bar, bcnt);

        // ==== Phase C: l2(t) — wave w computes gate w for both block j's ====
        {
            const float* hx = h1buf[nn];
            const float* hh = h2buf[cc];
            const int rl0 = w * 2, rl1 = rl0 + 1;
            float a0 = b2b0, a1 = b2b1;
            for (int kc = 0; kc < 1024; kc += 128) {
                __syncthreads();
                const float4* src = (const float4*)(hx + (size_t)kc * 64);
                float4* dst = (float4*)hs;
#pragma unroll
                for (int i = 0; i < 8; i++) dst[tid + 256 * i] = src[tid + 256 * i];
                __syncthreads();
#pragma unroll 2
                for (int k = 0; k < 128; k += 8) {
                    float h[8];
#pragma unroll
                    for (int i = 0; i < 8; i++) h[i] = hs[(k + i) * 64 + lane];
                    uint4 q0 = *(const uint4*)&w2s[rl0][kc + k];
                    uint4 q1 = *(const uint4*)&w2s[rl1][kc + k];
                    fma8(a0, q0, h); fma8(a1, q1, h);
                }
            }
            for (int kc = 0; kc < 512; kc += 128) {
                __syncthreads();
                const float4* src = (const float4*)(hh + (size_t)kc * 64);
                float4* dst = (float4*)hs;
#pragma unroll
                for (int i = 0; i < 8; i++) dst[tid + 256 * i] = src[tid + 256 * i];
                __syncthreads();
#pragma unroll 2
                for (int k = 0; k < 128; k += 8) {
                    float h[8];
#pragma unroll
                    for (int i = 0; i < 8; i++) h[i] = hs[(k + i) * 64 + lane];
                    uint4 q0 = *(const uint4*)&w2s[rl0][1024 + kc + k];
                    uint4 q1 = *(const uint4*)&w2s[rl1][1024 + kc + k];
                    fma8(a0, q0, h); fma8(a1, q1, h);
                }
            }
            gbuf[w][0][lane] = a0;
            gbuf[w][1][lane] = a1;
            __syncthreads();
            if (w < 2) {
                float gi = gbuf[0][w][lane], gf = gbuf[1][w][lane];
                float gG = gbuf[2][w][lane], go = gbuf[3][w][lane];
                float c2v = fmaf(sigf(gf), c2reg, sigf(gi) * tanh_(gG));
                c2reg = c2v;
                h2buf[nn][(size_t)(bx * 2 + w) * 64 + lane] = sigf(go) * tanh_(c2v);
            }
        }
        bcnt += 256; gridbar(bar, bcnt);
    }

    // final output step: h2(254) is in h2buf[1]
    if (bx < 64) p3(254, h2buf[1]);
}

// ---------------- failure instrumentation ----------------

__global__ __launch_bounds__(256) void las_nanscan(const void* outp, const int* flag, int* cnt, int n) {
    int g = blockIdx.x * 256 + threadIdx.x;
    if (g >= n) return;
    bool bad;
    if (flag[0]) {
        u16 v = ((const u16*)outp)[g];
        bad = ((v & 0x7F80u) == 0x7F80u);
    } else {
        float f = ((const float*)outp)[g];
        bad = !isfinite(f);
    }
    if (bad) atomicAdd(cnt, 1);
}

__global__ __launch_bounds__(64) void las_nansig(void* outp, const int* flag, const int* cnt) {
    if (threadIdx.x != 0) return;
    int c = cnt[0];
    if (c > 0) {
        int cc = c < 9999 ? c : 9999;
        float sig = 10000.0f * (float)(1 + flag[0]) + (float)cc;
        if (flag[0]) ((u16*)outp)[0] = f2bf(sig);
        else         ((float*)outp)[0] = sig;
    }
}

// ---------------- host ----------------

extern "C" void kernel_launch(void* const* d_in, const int* in_sizes, int n_in,
                              void* d_out, int out_size, void* d_ws, size_t ws_size,
                              hipStream_t stream) {
    const void* keys     = d_in[0];
    const void* values   = d_in[1];
    const int* label     = (const int*)d_in[2];
    const int* input_len = (const int*)d_in[4];

    float* F     = (float*)d_ws;
    float* q     = F + O_QUERY;
    float* nq    = F + O_NQ;
    float* wk    = F + O_WK;
    float* kb    = F + O_KB;
    int*   flag  = (int*)(F + O_FLAG);          // flag[0]=is_bf16, flag[1]=nan ctr, flag[2]=grid barrier
    float* av    = F + O_AV;
    float* head  = F + O_HEAD;
    float* ctxT  = F + O_CTXT;
    float* embg  = F + O_EMBG;
    float* ctxg  = F + O_CTXG;
    float* ctxp1 = F + O_CTXP1;
    float* c0T   = F + O_C0T;
    float* c1T   = F + O_C1T;
    float* c2T   = F + O_C2T;
    int*   labT  = (int*)(F + O_LABT);
    float* h0buf[2] = { F + O_H0T, F + O_H0T + 65536 };
    float* h1buf[2] = { F + O_H1T, F + O_H1T + 65536 };
    float* h2buf[2] = { F + O_H2T, F + O_H2T + 32768 };
    u16*   cw    = (u16*)d_ws + 2 * (size_t)O_CANON;

    // canonicalization descriptor: d_in[6..37] in order
    static const unsigned kLen[NSEG] = {
        17408, 34, 262144, 512, 262144, 512, 262144, 512, 262144, 512,
        262144, 512, 524288, 512, 4194304, 4194304, 4096, 4096, 1024, 1024,
        4194304, 4194304, 4096, 4096, 1024, 1024, 2097152, 1048576, 2048, 2048,
        512, 512
    };
    Cvt cv;
    const u16* cwp[NSEG];
    unsigned o = 0;
    for (int i = 0; i < NSEG; i++) {
        cv.src[i] = d_in[6 + i];
        cv.ofs[i] = o;
        cv.len[i] = kLen[i];
        cwp[i] = cw + o;
        o += (kLen[i] + 7u) & ~7u;
    }
    cv.ofs[NSEG] = o;

    const u16 *W_emb = cwp[0], *b_proj2 = cwp[1], *W_query = cwp[2], *b_query = cwp[3];
    const u16 *Wk = cwp[4], *bk = cwp[5], *Wq = cwp[6], *bq = cwp[7];
    const u16 *Wv = cwp[8], *bv = cwp[9], *W_mh = cwp[10], *b_mh = cwp[11];
    const u16 *W_p1 = cwp[12], *b_p1 = cwp[13], *Wih0 = cwp[14], *Whh0 = cwp[15];
    const u16 *bih0 = cwp[16], *bhh0 = cwp[17], *h00 = cwp[18], *c00 = cwp[19];
    const u16 *Wih1 = cwp[20], *Whh1 = cwp[21], *bih1 = cwp[22], *bhh1 = cwp[23];
    const u16 *h01 = cwp[24], *c01 = cwp[25], *Wih2 = cwp[26], *Whh2 = cwp[27];
    const u16 *bih2 = cwp[28], *bhh2 = cwp[29], *h02 = cwp[30], *c02 = cwp[31];
    (void)h01;

    // dtype detect + canonicalize to bf16 (also zeroes nan ctr + barrier ctr)
    las_detect<<<1, 256, 0, stream>>>((const u16*)d_in[8], flag);
    las_convert<<<4096, 256, 0, stream>>>(cv, flag, cw);

    // one-time setup
    las_init<<<256, 256, 0, stream>>>(h00, c00, cwp[24], cwp[25], h02, c02, label,
                                      h0buf[0], c0T, h1buf[0], c1T, h2buf[0], c2T, labT);
    las_query<<<2, 256, 0, stream>>>(h02, W_query, b_query, q);
    las_nq<<<2, 256, 0, stream>>>(q, Wq, bq, nq);
    las_wk<<<8, 256, 0, stream>>>(nq, Wk, bk, wk, kb);
    las_attn<<<64, 256, 0, stream>>>(keys, values, input_len, flag, wk, kb, av);
    las_head<<<128, 256, 0, stream>>>(av, Wv, bv, head);
    las_ctx<<<128, 256, 0, stream>>>(head, W_mh, b_mh, ctxT);
    las_embg<<<545, 256, 0, stream>>>(W_emb, Wih0, embg);
    las_ctxg<<<1024, 256, 0, stream>>>(ctxT, Wih0, bih0, bhh0, ctxg);
    las_ctxp1<<<128, 256, 0, stream>>>(ctxT, W_p1, b_p1, ctxp1);

    // 255 decode steps in ONE persistent kernel (3 grid barriers per step)
    las_decode<<<256, 256, 0, stream>>>(
        embg, ctxg, ctxp1, labT,
        Whh0, Wih1, Whh1, bih1, bhh1,
        Wih2, Whh2, bih2, bhh2,
        W_p1, W_emb, b_proj2,
        c00, c01, c02,
        h0buf[0], h0buf[1], h1buf[0], h1buf[1], h2buf[0], h2buf[1],
        flag, flag + 2, d_out);

    // if anything non-finite leaked into the output, stamp a diagnostic signature
    int n_out = 64 * 255 * 34;
    las_nanscan<<<(n_out + 255) / 256, 256, 0, stream>>>(d_out, flag, flag + 1, n_out);
    las_nansig<<<1, 64, 0, stream>>>(d_out, flag, flag + 1);
}

// Round 2
// 21181.613 us; speedup vs baseline: 2.7049x; 2.5651x over previous
//
#include <hip/hip_runtime.h>

typedef unsigned short u16;
typedef unsigned int   u32;
typedef float f32x4 __attribute__((ext_vector_type(4)));
typedef short short8 __attribute__((ext_vector_type(8)));

#define SCALE_F 0.08838834764831845f  // 1/sqrt(128)

// ---------- ws layout (float offsets) ----------
#define O_QUERY  0           // 512
#define O_NQ     512         // 512
#define O_WK     1024        // 2048
#define O_KB     3072        // 4  (flag at int ofs 3080, nan counter 3081, barrier 3082)
#define O_FLAG   3080
#define O_AV     4096        // 64*4*512 = 131072
#define O_HEAD   135168      // 64*512  = 32768
#define O_CTXT   167936      // 512*64  = 32768
#define O_EMBG   200704      // 4096*34 = 139264
#define O_CTXG   339968      // 4096*64 = 262144
#define O_CTXP1  602112      // 512*64  = 32768
#define O_H0T    634880      // h0 frag bf16 [2 parity][2 hi/lo][65536] = 131072 floats
#define O_C0T    765952      // y[2][32768] f32 = 65536 floats (repurposed)
#define O_H1T    831488      // h1 frag = 131072 floats
#define O_C1T    962560      // (unused)
#define O_H2T    1028096     // h2 frag [2][2][32768] = 65536 floats
#define O_C2T    1093632     // (unused)
#define O_YT     1126400     // (unused)
#define O_LABT   1159168     // 255*64 ints
#define O_CANON  1175552     // canonical bf16 weights start (u16 ofs = 2*O_CANON)

__device__ __forceinline__ float bfc(u16 x) {
    return __uint_as_float(((u32)x) << 16);
}
__device__ __forceinline__ float2 bfpair(u32 u) {
    return make_float2(__uint_as_float(u << 16), __uint_as_float(u & 0xffff0000u));
}
__device__ __forceinline__ u16 f2bf(float f) {
    u32 u = __float_as_uint(f);
    u += 0x7fffu + ((u >> 16) & 1u);
    return (u16)(u >> 16);
}
__device__ __forceinline__ float sigf(float x) { return 1.0f / (1.0f + __expf(-x)); }
__device__ __forceinline__ float tanh_(float x) { return 2.0f / (1.0f + __expf(-2.0f * x)) - 1.0f; }

__device__ __forceinline__ void fma8(float& acc, uint4 a, const float h[8]) {
    float2 p;
    p = bfpair(a.x); acc = fmaf(h[0], p.x, acc); acc = fmaf(h[1], p.y, acc);
    p = bfpair(a.y); acc = fmaf(h[2], p.x, acc); acc = fmaf(h[3], p.y, acc);
    p = bfpair(a.z); acc = fmaf(h[4], p.x, acc); acc = fmaf(h[5], p.y, acc);
    p = bfpair(a.w); acc = fmaf(h[6], p.x, acc); acc = fmaf(h[7], p.y, acc);
}

__device__ __forceinline__ f32x4 mfma16(short8 a, short8 b, f32x4 c) {
    return __builtin_amdgcn_mfma_f32_16x16x32_bf16(a, b, c, 0, 0, 0);
}
__device__ __forceinline__ short8 ld8g(const u16* p) {
    uint4 v = *(const uint4*)p;
    return __builtin_bit_cast(short8, v);
}
// frag index of element (k,col) in a B-frag-layout h buffer
__device__ __forceinline__ int fidx(int k, int col) {
    return ((k >> 5) * 4 + (col >> 4)) * 512 + (((k >> 2) & 3) * 16 + (col & 15)) * 8 +
           ((k >> 4) & 1) * 4 + (k & 3);
}
// producer store: lane's h value for cell k=4*bx+(l>>4), col=w*16+(l&15); hi+lo split
__device__ __forceinline__ void storeH(u16* buf, int HL, int bx, int w, int l, float v) {
    int idx = ((bx >> 3) * 4 + w) * 512 + ((bx & 3) * 16 + (l & 15)) * 8 +
              ((bx >> 2) & 1) * 4 + (l >> 4);
    u16 hi = f2bf(v);
    buf[idx] = hi;
    buf[idx + HL] = f2bf(v - bfc(hi));
}

// ---------------- dtype detect + canonicalize ----------------

__global__ __launch_bounds__(256) void las_detect(const u16* w, int* flag) {
    __shared__ int s[256];
    int bad = 0;
    for (int i = threadIdx.x; i < 65536; i += 256) {
        u16 v = w[i];
        if ((v & 0x7F80u) == 0x7F80u) bad++;
        else if (fabsf(bfc(v)) > 1e4f) bad++;
    }
    s[threadIdx.x] = bad; __syncthreads();
    for (int o = 128; o; o >>= 1) {
        if (threadIdx.x < o) s[threadIdx.x] += s[threadIdx.x + o];
        __syncthreads();
    }
    if (threadIdx.x == 0) { flag[0] = (s[0] == 0) ? 1 : 0; flag[1] = 0; flag[2] = 0; }
}

#define NSEG 32
struct Cvt {
    const void* src[NSEG];
    unsigned ofs[NSEG + 1];
    unsigned len[NSEG];
};

__global__ __launch_bounds__(256) void las_convert(Cvt c, const int* flag, u16* dst) {
    int isb = flag[0];
    unsigned total = c.ofs[NSEG] >> 1;
    for (unsigned p = blockIdx.x * 256 + threadIdx.x; p < total; p += gridDim.x * 256) {
        unsigned e = p << 1;
        int lo = 0, hi = NSEG;
        while (hi - lo > 1) { int mid = (lo + hi) >> 1; if (c.ofs[mid] <= e) lo = mid; else hi = mid; }
        unsigned local = e - c.ofs[lo];
        u32 out;
        if (local >= c.len[lo]) {
            out = 0;
        } else if (isb) {
            out = ((const u32*)c.src[lo])[local >> 1];
        } else {
            const float* s = (const float*)c.src[lo];
            u32 a = f2bf(s[local]), b = f2bf(s[local + 1]);
            out = a | (b << 16);
        }
        ((u32*)dst)[p] = out;
    }
}

// ---------------- one-time kernels ----------------

__global__ __launch_bounds__(256) void las_init(
    const u16* h00, const u16* h01, const u16* h02, const int* label,
    u16* h0f, u16* h1f, u16* h2f, int* labT) {
    int idx = blockIdx.x * 256 + threadIdx.x;   // 65536 threads
    int k = idx >> 6, col = idx & 63;
    int fi = fidx(k, col);
    h0f[fi] = h00[k]; h0f[fi + 65536] = 0;      // parity0 hi / lo=0
    h1f[fi] = h01[k]; h1f[fi + 65536] = 0;
    if (k < 512) { h2f[fi] = h02[k]; h2f[fi + 32768] = 0; }
    if (k < 255) labT[idx] = label[col * 256 + k];
}

__global__ __launch_bounds__(256) void las_query(const u16* h02, const u16* W_query,
                                                 const u16* b_query, float* query) {
    int i = blockIdx.x * 256 + threadIdx.x;     // < 512
    float acc = bfc(b_query[i]);
    const u32* wr = (const u32*)(W_query + (size_t)i * 512);
    const u32* hp = (const u32*)h02;
    for (int h = 0; h < 512; h += 8) {
        uint4 wv = *(const uint4*)(wr + (h >> 1));
        uint4 hv = *(const uint4*)(hp + (h >> 1));
        float2 a, c;
        a = bfpair(wv.x); c = bfpair(hv.x); acc = fmaf(a.x, c.x, acc); acc = fmaf(a.y, c.y, acc);
        a = bfpair(wv.y); c = bfpair(hv.y); acc = fmaf(a.x, c.x, acc); acc = fmaf(a.y, c.y, acc);
        a = bfpair(wv.z); c = bfpair(hv.z); acc = fmaf(a.x, c.x, acc); acc = fmaf(a.y, c.y, acc);
        a = bfpair(wv.w); c = bfpair(hv.w); acc = fmaf(a.x, c.x, acc); acc = fmaf(a.y, c.y, acc);
    }
    query[i] = acc;
}

__global__ __launch_bounds__(256) void las_nq(const float* query, const u16* Wq,
                                              const u16* bq, float* nq) {
    int nd = blockIdx.x * 256 + threadIdx.x;    // < 512
    float acc = bfc(bq[nd]);
    const u32* wr = (const u32*)(Wq + (size_t)nd * 512);
    for (int h = 0; h < 512; h += 8) {
        uint4 wv = *(const uint4*)(wr + (h >> 1));
        float2 p;
        p = bfpair(wv.x); acc = fmaf(p.x, query[h + 0], acc); acc = fmaf(p.y, query[h + 1], acc);
        p = bfpair(wv.y); acc = fmaf(p.x, query[h + 2], acc); acc = fmaf(p.y, query[h + 3], acc);
        p = bfpair(wv.z); acc = fmaf(p.x, query[h + 4], acc); acc = fmaf(p.y, query[h + 5], acc);
        p = bfpair(wv.w); acc = fmaf(p.x, query[h + 6], acc); acc = fmaf(p.y, query[h + 7], acc);
    }
    nq[nd] = acc;
}

__global__ __launch_bounds__(256) void las_wk(const float* nq, const u16* Wk, const u16* bk,
                                              float* wk, float* kb) {
    int idx = blockIdx.x * 256 + threadIdx.x;   // < 2048
    int n = idx >> 9, h = idx & 511;
    float acc = 0.0f;
    for (int d = 0; d < 128; d++)
        acc = fmaf(nq[n * 128 + d], bfc(Wk[((size_t)(n * 128 + d)) * 512 + h]), acc);
    wk[idx] = acc;
    if (idx < 4) {
        float kk = 0.0f;
        for (int d = 0; d < 128; d++) kk = fmaf(nq[idx * 128 + d], bfc(bk[idx * 128 + d]), kk);
        kb[idx] = kk;
    }
}

__global__ __launch_bounds__(256) void las_attn(const void* keysv, const void* valuesv,
                                                const int* input_len, const int* flag,
                                                const float* wk, const float* kb, float* av) {
    __shared__ float wk_s[2048];
    __shared__ float kb_s[4];
    __shared__ float sm[4][1024];
    __shared__ float red[256];
    __shared__ float stat[4];
    const u16* keysB = (const u16*)keysv;
    const float* keysF = (const float*)keysv;
    const u16* valB = (const u16*)valuesv;
    const float* valF = (const float*)valuesv;
    int b = blockIdx.x;
    int tid = threadIdx.x;
    int isb = flag[0];
    for (int i = tid; i < 2048; i += 256) wk_s[i] = wk[i];
    if (tid < 4) kb_s[tid] = kb[tid];
    __syncthreads();
    int len = input_len[b];

    {
        float acc[4][4];
#pragma unroll
        for (int tl = 0; tl < 4; tl++)
#pragma unroll
            for (int n = 0; n < 4; n++) acc[tl][n] = kb_s[n];
        for (int h = 0; h < 512; h += 8) {
            float kf[4][8];
#pragma unroll
            for (int tl = 0; tl < 4; tl++) {
                int t = tid + 256 * tl;
                size_t base = ((size_t)t * 64 + b) * 512 + h;
                if (isb) {
                    uint4 kv = *(const uint4*)(keysB + base);
                    float2 p;
                    p = bfpair(kv.x); kf[tl][0] = p.x; kf[tl][1] = p.y;
                    p = bfpair(kv.y); kf[tl][2] = p.x; kf[tl][3] = p.y;
                    p = bfpair(kv.z); kf[tl][4] = p.x; kf[tl][5] = p.y;
                    p = bfpair(kv.w); kf[tl][6] = p.x; kf[tl][7] = p.y;
                } else {
                    const float4* kp = (const float4*)(keysF + base);
                    float4 q0 = kp[0], q1 = kp[1];
                    kf[tl][0] = q0.x; kf[tl][1] = q0.y; kf[tl][2] = q0.z; kf[tl][3] = q0.w;
                    kf[tl][4] = q1.x; kf[tl][5] = q1.y; kf[tl][6] = q1.z; kf[tl][7] = q1.w;
                }
            }
#pragma unroll
            for (int i = 0; i < 8; i++) {
                float w0 = wk_s[h + i], w1 = wk_s[512 + h + i];
                float w2 = wk_s[1024 + h + i], w3 = wk_s[1536 + h + i];
#pragma unroll
                for (int tl = 0; tl < 4; tl++) {
                    acc[tl][0] = fmaf(kf[tl][i], w0, acc[tl][0]);
                    acc[tl][1] = fmaf(kf[tl][i], w1, acc[tl][1]);
                    acc[tl][2] = fmaf(kf[tl][i], w2, acc[tl][2]);
                    acc[tl][3] = fmaf(kf[tl][i], w3, acc[tl][3]);
                }
            }
        }
#pragma unroll
        for (int tl = 0; tl < 4; tl++) {
            int t = tid + 256 * tl;
#pragma unroll
            for (int n = 0; n < 4; n++)
                sm[n][t] = (t < len) ? acc[tl][n] * SCALE_F : -1e30f;
        }
    }
    __syncthreads();

    for (int n = 0; n < 4; n++) {
        float m = -1e30f;
        for (int tl = 0; tl < 4; tl++) m = fmaxf(m, sm[n][tid + 256 * tl]);
        red[tid] = m; __syncthreads();
        for (int off = 128; off; off >>= 1) {
            if (tid < off) red[tid] = fmaxf(red[tid], red[tid + off]);
            __syncthreads();
        }
        m = red[0]; __syncthreads();
        float e = 0.0f;
        for (int tl = 0; tl < 4; tl++) {
            int t = tid + 256 * tl;
            float x = (t < len) ? __expf(sm[n][t] - m) : 0.0f;
            sm[n][t] = x; e += x;
        }
        red[tid] = e; __syncthreads();
        for (int off = 128; off; off >>= 1) {
            if (tid < off) red[tid] += red[tid + off];
            __syncthreads();
        }
        if (tid == 0) stat[n] = 1.0f / red[0];
        __syncthreads();
    }

    {
        float a[4][2] = {};
        int h0 = 2 * tid;
        for (int t = 0; t < len; t++) {
            size_t base = ((size_t)t * 64 + b) * 512 + h0;
            float2 p;
            if (isb) p = bfpair(*(const u32*)(valB + base));
            else     p = *(const float2*)(valF + base);
            float s0 = sm[0][t], s1 = sm[1][t], s2 = sm[2][t], s3 = sm[3][t];
            a[0][0] = fmaf(s0, p.x, a[0][0]); a[0][1] = fmaf(s0, p.y, a[0][1]);
            a[1][0] = fmaf(s1, p.x, a[1][0]); a[1][1] = fmaf(s1, p.y, a[1][1]);
            a[2][0] = fmaf(s2, p.x, a[2][0]); a[2][1] = fmaf(s2, p.y, a[2][1]);
            a[3][0] = fmaf(s3, p.x, a[3][0]); a[3][1] = fmaf(s3, p.y, a[3][1]);
        }
#pragma unroll
        for (int n = 0; n < 4; n++) {
            av[((size_t)b * 4 + n) * 512 + h0]     = a[n][0] * stat[n];
            av[((size_t)b * 4 + n) * 512 + h0 + 1] = a[n][1] * stat[n];
        }
    }
}

__global__ __launch_bounds__(256) void las_head(const float* av, const u16* Wv, const u16* bv,
                                                float* head) {
    int idx = blockIdx.x * 256 + threadIdx.x;   // < 32768
    int b = idx >> 9, nd = idx & 511, n = nd >> 7;
    float acc = bfc(bv[nd]);
    const u32* wr = (const u32*)(Wv + (size_t)nd * 512);
    const float* ap = av + ((size_t)b * 4 + n) * 512;
    for (int h = 0; h < 512; h += 8) {
        uint4 wv = *(const uint4*)(wr + (h >> 1));
        float2 p;
        p = bfpair(wv.x); acc = fmaf(p.x, ap[h + 0], acc); acc = fmaf(p.y, ap[h + 1], acc);
        p = bfpair(wv.y); acc = fmaf(p.x, ap[h + 2], acc); acc = fmaf(p.y, ap[h + 3], acc);
        p = bfpair(wv.z); acc = fmaf(p.x, ap[h + 4], acc); acc = fmaf(p.y, ap[h + 5], acc);
        p = bfpair(wv.w); acc = fmaf(p.x, ap[h + 6], acc); acc = fmaf(p.y, ap[h + 7], acc);
    }
    head[idx] = acc;
}

__global__ __launch_bounds__(256) void las_ctx(const float* head, const u16* W_mh, const u16* b_mh,
                                               float* ctxT) {
    int idx = blockIdx.x * 256 + threadIdx.x;   // < 32768
    int b = idx >> 9, i = idx & 511;
    float acc = bfc(b_mh[i]);
    const u32* wr = (const u32*)(W_mh + (size_t)i * 512);
    const float* hp = head + (size_t)b * 512;
    for (int h = 0; h < 512; h += 8) {
        uint4 wv = *(const uint4*)(wr + (h >> 1));
        float2 p;
        p = bfpair(wv.x); acc = fmaf(p.x, hp[h + 0], acc); acc = fmaf(p.y, hp[h + 1], acc);
        p = bfpair(wv.y); acc = fmaf(p.x, hp[h + 2], acc); acc = fmaf(p.y, hp[h + 3], acc);
        p = bfpair(wv.z); acc = fmaf(p.x, hp[h + 4], acc); acc = fmaf(p.y, hp[h + 5], acc);
        p = bfpair(wv.w); acc = fmaf(p.x, hp[h + 6], acc); acc = fmaf(p.y, hp[h + 7], acc);
    }
    ctxT[(size_t)i * 64 + b] = acc;
}

__global__ __launch_bounds__(256) void las_embg(const u16* W_emb, const u16* Wih0, float* embg) {
    int idx = blockIdx.x * 256 + threadIdx.x;
    if (idx >= 4096 * 34) return;
    int row = idx / 34, v = idx - row * 34;
    const u32* wr = (const u32*)(Wih0 + (size_t)row * 1024);
    const u32* er = (const u32*)(W_emb + (size_t)v * 512);
    float acc = 0.0f;
    for (int h = 0; h < 512; h += 8) {
        uint4 wv = *(const uint4*)(wr + (h >> 1));
        uint4 ev = *(const uint4*)(er + (h >> 1));
        float2 a, c;
        a = bfpair(wv.x); c = bfpair(ev.x); acc = fmaf(a.x, c.x, acc); acc = fmaf(a.y, c.y, acc);
        a = bfpair(wv.y); c = bfpair(ev.y); acc = fmaf(a.x, c.x, acc); acc = fmaf(a.y, c.y, acc);
        a = bfpair(wv.z); c = bfpair(ev.z); acc = fmaf(a.x, c.x, acc); acc = fmaf(a.y, c.y, acc);
        a = bfpair(wv.w); c = bfpair(ev.w); acc = fmaf(a.x, c.x, acc); acc = fmaf(a.y, c.y, acc);
    }
    embg[idx] = acc;
}

__global__ __launch_bounds__(256) void las_ctxg(const float* ctxT, const u16* Wih0,
                                                const u16* bih0, const u16* bhh0, float* ctxg) {
    int lane = threadIdx.x & 63, w = threadIdx.x >> 6;
    int row = blockIdx.x * 4 + w;               // < 4096
    float acc = bfc(bih0[row]) + bfc(bhh0[row]);
    const u32* wr = (const u32*)(Wih0 + (size_t)row * 1024 + 512);
    for (int h = 0; h < 512; h += 8) {
        float hv[8];
#pragma unroll
        for (int i = 0; i < 8; i++) hv[i] = ctxT[(size_t)(h + i) * 64 + lane];
        uint4 wv = *(const uint4*)(wr + (h >> 1));
        fma8(acc, wv, hv);
    }
    ctxg[(size_t)row * 64 + lane] = acc;
}

__global__ __launch_bounds__(256) void las_ctxp1(const float* ctxT, const u16* W_p1,
                                                 const u16* b_p1, float* ctxp1) {
    int lane = threadIdx.x & 63, w = threadIdx.x >> 6;
    int i = blockIdx.x * 4 + w;                 // < 512
    float acc = bfc(b_p1[i]);
    const u32* wr = (const u32*)(W_p1 + (size_t)i * 1024 + 512);
    for (int h = 0; h < 512; h += 8) {
        float hv[8];
#pragma unroll
        for (int k = 0; k < 8; k++) hv[k] = ctxT[(size_t)(h + k) * 64 + lane];
        uint4 wv = *(const uint4*)(wr + (h >> 1));
        fma8(acc, wv, hv);
    }
    ctxp1[(size_t)i * 64 + lane] = acc;
}

// ---------------- persistent MFMA decode kernel ----------------
// 256 blocks x 256 threads (4 waves = 4 batch n-tiles). Each block owns one
// 16-row M-tile per layer (4 cells x 4 gates interleaved: tile row = 4*cell+gate,
// so MFMA C/D reg 0..3 = gates i,f,g,o of one cell in each lane). Weights are
// reshuffled ONCE into A-fragment layout in LDS (A read = contiguous 1KB
// ds_read_b128). h vectors live in global in B-fragment layout, split bf16
// hi+lo (product precision ~= f32), so B load = one coalesced dwordx4/lane.
// Cell states stay in registers. 3 grid barriers per step.

__device__ __forceinline__ void gridbar(int* ctr, int target) {
    __syncthreads();
    if (threadIdx.x == 0) {
        __threadfence();
        atomicAdd(ctr, 1);
        int iters = 0;
        while (atomicAdd(ctr, 0) < target) {
            __builtin_amdgcn_s_sleep(4);
            if (++iters > (1 << 20)) break;    // bounded: corrupts instead of hanging
        }
        __threadfence();
    }
    __syncthreads();
}

__global__ __launch_bounds__(256, 1) void las_decode(
    const float* embg, const float* ctxg, const float* ctxp1, const int* labT,
    const u16* Whh0, const u16* Wih1, const u16* Whh1,
    const u16* bih1, const u16* bhh1,
    const u16* Wih2, const u16* Whh2, const u16* bih2, const u16* bhh2,
    const u16* W_p1, const u16* W_emb, const u16* b_proj2,
    const u16* c00, const u16* c01, const u16* c02,
    u16* h0f, u16* h1f, u16* h2f, float* ybuf,
    const int* flag, int* bar, void* outp) {

    __shared__ __align__(16) u16 A0[32 * 64 * 8];   // 32 KB  Whh0 A-frags
    __shared__ __align__(16) u16 A1[64 * 64 * 8];   // 64 KB  Wih1|Whh1 A-frags
    __shared__ __align__(16) u16 A2[48 * 64 * 8];   // 48 KB  Wih2|Whh2 (bx<128) or W_p1 (128..159)
    __shared__ float ylds[512];                     //  2 KB  p3b scratch

    const int tid = threadIdx.x, l = tid & 63, w = tid >> 6;
    const int bx = blockIdx.x;
    const int isb = flag[0];
    const int HL0 = 65536, HL2 = 32768;

    // ---- stage A-fragments once ----
    for (int i = tid; i < 32 * 64 * 2; i += 256) {
        int kt = i >> 7, ll = (i >> 1) & 63, half = i & 1;
        int r = ll & 15;
        int row = (r & 3) * 1024 + 4 * bx + (r >> 2);
        int kc = kt * 32 + half * 16 + 4 * (ll >> 4);
        *(uint2*)&A0[(kt * 64 + ll) * 8 + half * 4] = *(const uint2*)(Whh0 + (size_t)row * 1024 + kc);
    }
    for (int i = tid; i < 64 * 64 * 2; i += 256) {
        int kt = i >> 7, ll = (i >> 1) & 63, half = i & 1;
        int r = ll & 15;
        int row = (r & 3) * 1024 + 4 * bx + (r >> 2);
        int kc = kt * 32 + half * 16 + 4 * (ll >> 4);
        const u16* src = (kc < 1024) ? (Wih1 + (size_t)row * 1024 + kc)
                                     : (Whh1 + (size_t)row * 1024 + (kc - 1024));
        *(uint2*)&A1[(kt * 64 + ll) * 8 + half * 4] = *(const uint2*)src;
    }
    if (bx < 128) {
        for (int i = tid; i < 48 * 64 * 2; i += 256) {
            int kt = i >> 7, ll = (i >> 1) & 63, half = i & 1;
            int r = ll & 15;
            int row = (r & 3) * 512 + 4 * bx + (r >> 2);
            int kc = kt * 32 + half * 16 + 4 * (ll >> 4);
            const u16* src = (kc < 1024) ? (Wih2 + (size_t)row * 1024 + kc)
                                         : (Whh2 + (size_t)row * 512 + (kc - 1024));
            *(uint2*)&A2[(kt * 64 + ll) * 8 + half * 4] = *(const uint2*)src;
        }
    } else if (bx < 160) {
        int mt = bx - 128;
        for (int i = tid; i < 16 * 64 * 2; i += 256) {
            int kt = i >> 7, ll = (i >> 1) & 63, half = i & 1;
            int row = 16 * mt + (ll & 15);
            int kc = kt * 32 + half * 16 + 4 * (ll >> 4);
            *(uint2*)&A2[(kt * 64 + ll) * 8 + half * 4] = *(const uint2*)(W_p1 + (size_t)row * 1024 + kc);
        }
    }

    // ---- persistent per-lane state ----
    const int cell01 = 4 * bx + (l >> 4);
    const int bcol = w * 16 + (l & 15);
    float c0reg = bfc(c00[cell01]);
    float c1reg = bfc(c01[cell01]);
    float pre0c[4], pre1c[4], pre2c[4], prep3[4];
#pragma unroll
    for (int r = 0; r < 4; r++) {
        int row = r * 1024 + cell01;
        pre0c[r] = ctxg[(size_t)row * 64 + bcol];
        pre1c[r] = bfc(bih1[row]) + bfc(bhh1[row]);
        pre2c[r] = 0.0f; prep3[r] = 0.0f;
    }
    float c2reg = 0.0f;
    if (bx < 128) {
        int cell2 = 4 * bx + (l >> 4);
        c2reg = bfc(c02[cell2]);
#pragma unroll
        for (int r = 0; r < 4; r++) {
            int row = r * 512 + cell2;
            pre2c[r] = bfc(bih2[row]) + bfc(bhh2[row]);
        }
    } else if (bx < 160) {
#pragma unroll
        for (int r = 0; r < 4; r++) {
            int yi = 16 * (bx - 128) + 4 * (l >> 4) + r;
            prep3[r] = ctxp1[(size_t)yi * 64 + bcol];
        }
    }
    __syncthreads();

    int bcnt = 0;
    for (int t = 0; t <= 256; t++) {
        const int pc = t & 1, pn = pc ^ 1;
        const u16* h0c = h0f + pc * 131072;
        u16* h0n = h0f + pn * 131072;
        const u16* h1c = h1f + pc * 131072;
        u16* h1n = h1f + pn * 131072;
        const u16* h2c = h2f + pc * 65536;
        u16* h2n = h2f + pn * 65536;

        // ==== Phase A: l0(t) ====
        if (t < 255) {
            int vb = labT[t * 64 + bcol];
            float e0 = embg[(size_t)(0 * 1024 + cell01) * 34 + vb];
            float e1 = embg[(size_t)(1 * 1024 + cell01) * 34 + vb];
            float e2 = embg[(size_t)(2 * 1024 + cell01) * 34 + vb];
            float e3 = embg[(size_t)(3 * 1024 + cell01) * 34 + vb];
            f32x4 ah = {0.f, 0.f, 0.f, 0.f}, al = {0.f, 0.f, 0.f, 0.f};
#pragma unroll 4
            for (int kt = 0; kt < 32; kt++) {
                short8 a = *(const short8*)&A0[(kt * 64 + l) * 8];
                const u16* bp = h0c + (kt * 4 + w) * 512 + l * 8;
                ah = mfma16(a, ld8g(bp), ah);
                al = mfma16(a, ld8g(bp + HL0), al);
            }
            float g0 = ah[0] + al[0] + pre0c[0] + e0;
            float g1 = ah[1] + al[1] + pre0c[1] + e1;
            float g2 = ah[2] + al[2] + pre0c[2] + e2;
            float g3 = ah[3] + al[3] + pre0c[3] + e3;
            float c2 = fmaf(sigf(g1), c0reg, sigf(g0) * tanh_(g2));
            c0reg = c2;
            storeH(h0n, HL0, bx, w, l, sigf(g3) * tanh_(c2));
        }
        bcnt += 256; gridbar(bar, bcnt);

        // ==== Phase B: l1(t) ====
        if (t < 255) {
            f32x4 ah = {0.f, 0.f, 0.f, 0.f}, al = {0.f, 0.f, 0.f, 0.f};
#pragma unroll 4
            for (int kt = 0; kt < 32; kt++) {
                short8 a = *(const short8*)&A1[(kt * 64 + l) * 8];
                const u16* bp = h0n + (kt * 4 + w) * 512 + l * 8;   // x = h0n (this step)
                ah = mfma16(a, ld8g(bp), ah);
                al = mfma16(a, ld8g(bp + HL0), al);
            }
#pragma unroll 4
            for (int kt = 0; kt < 32; kt++) {
                short8 a = *(const short8*)&A1[((kt + 32) * 64 + l) * 8];
                const u16* bp = h1c + (kt * 4 + w) * 512 + l * 8;   // h = h1(t-1)
                ah = mfma16(a, ld8g(bp), ah);
                al = mfma16(a, ld8g(bp + HL0), al);
            }
            float g0 = ah[0] + al[0] + pre1c[0];
            float g1 = ah[1] + al[1] + pre1c[1];
            float g2 = ah[2] + al[2] + pre1c[2];
            float g3 = ah[3] + al[3] + pre1c[3];
            float c2 = fmaf(sigf(g1), c1reg, sigf(g0) * tanh_(g2));
            c1reg = c2;
            storeH(h1n, HL0, bx, w, l, sigf(g3) * tanh_(c2));
        }
        bcnt += 256; gridbar(bar, bcnt);

        // ==== Phase C: l2(t) | p3a(t-1) | p3b(t-2) ====
        if (bx < 128) {
            if (t < 255) {
                f32x4 ah = {0.f, 0.f, 0.f, 0.f}, al = {0.f, 0.f, 0.f, 0.f};
#pragma unroll 4
                for (int kt = 0; kt < 32; kt++) {
                    short8 a = *(const short8*)&A2[(kt * 64 + l) * 8];
                    const u16* bp = h1n + (kt * 4 + w) * 512 + l * 8;   // x = h1n
                    ah = mfma16(a, ld8g(bp), ah);
                    al = mfma16(a, ld8g(bp + HL0), al);
                }
#pragma unroll 4
                for (int kt = 0; kt < 16; kt++) {
                    short8 a = *(const short8*)&A2[((kt + 32) * 64 + l) * 8];
                    const u16* bp = h2c + (kt * 4 + w) * 512 + l * 8;   // h = h2(t-1)
                    ah = mfma16(a, ld8g(bp), ah);
                    al = mfma16(a, ld8g(bp + HL2), al);
                }
                float g0 = ah[0] + al[0] + pre2c[0];
                float g1 = ah[1] + al[1] + pre2c[1];
                float g2 = ah[2] + al[2] + pre2c[2];
                float g3 = ah[3] + al[3] + pre2c[3];
                float c2 = fmaf(sigf(g1), c2reg, sigf(g0) * tanh_(g2));
                c2reg = c2;
                storeH(h2n, HL2, bx, w, l, sigf(g3) * tanh_(c2));
            }
        } else if (bx < 160) {
            if (t >= 1 && t <= 255) {               // p3a(t-1): y = leaky(Wp1a*h2 + ctxp1)
                f32x4 ah = {0.f, 0.f, 0.f, 0.f}, al = {0.f, 0.f, 0.f, 0.f};
#pragma unroll 4
                for (int kt = 0; kt < 16; kt++) {
                    short8 a = *(const short8*)&A2[(kt * 64 + l) * 8];
                    const u16* bp = h2c + (kt * 4 + w) * 512 + l * 8;   // h2(t-1)
                    ah = mfma16(a, ld8g(bp), ah);
                    al = mfma16(a, ld8g(bp + HL2), al);
                }
                float* yw = ybuf + (size_t)pn * 32768;
#pragma unroll
                for (int r = 0; r < 4; r++) {
                    float v = ah[r] + al[r] + prep3[r];
                    v = v > 0.0f ? v : 0.01f * v;
                    yw[(size_t)(16 * (bx - 128) + 4 * (l >> 4) + r) * 64 + bcol] = v;
                }
            }
        } else if (bx < 224) {
            if (t >= 2) {                           // p3b(t-2)
                int b = bx - 160;
                const float* yp = ybuf + (size_t)pc * 32768;
                for (int i = tid; i < 512; i += 256) ylds[i] = yp[(size_t)i * 64 + b];
                __syncthreads();
                if (w == 0) {
                    int v = l;
                    float acc = -1e30f;
                    if (v < 34) {
                        acc = bfc(b_proj2[v]);
                        const u32* wr = (const u32*)(W_emb + (size_t)v * 512);
                        for (int k2 = 0; k2 < 512; k2 += 8) {
                            uint4 wv = *(const uint4*)(wr + (k2 >> 1));
                            float2 p;
                            p = bfpair(wv.x); acc = fmaf(p.x, ylds[k2 + 0], acc); acc = fmaf(p.y, ylds[k2 + 1], acc);
                            p = bfpair(wv.y); acc = fmaf(p.x, ylds[k2 + 2], acc); acc = fmaf(p.y, ylds[k2 + 3], acc);
                            p = bfpair(wv.z); acc = fmaf(p.x, ylds[k2 + 4], acc); acc = fmaf(p.y, ylds[k2 + 5], acc);
                            p = bfpair(wv.w); acc = fmaf(p.x, ylds[k2 + 6], acc); acc = fmaf(p.y, ylds[k2 + 7], acc);
                        }
                    }
                    float m = acc;
                    for (int off = 32; off; off >>= 1) m = fmaxf(m, __shfl_xor(m, off, 64));
                    float e = (v < 34) ? __expf(acc - m) : 0.0f;
                    float s = e;
                    for (int off = 32; off; off >>= 1) s += __shfl_xor(s, off, 64);
                    if (v < 34) {
                        float rr = acc - m - __logf(s);
                        size_t o = ((size_t)b * 255 + (t - 2)) * 34 + v;
                        if (isb) ((u16*)outp)[o] = f2bf(rr);
                        else     ((float*)outp)[o] = rr;
                    }
                }
            }
        }
        bcnt += 256; gridbar(bar, bcnt);
    }
}

// ---------------- failure instrumentation ----------------

__global__ __launch_bounds__(256) void las_nanscan(const void* outp, const int* flag, int* cnt, int n) {
    int g = blockIdx.x * 256 + threadIdx.x;
    if (g >= n) return;
    bool bad;
    if (flag[0]) {
        u16 v = ((const u16*)outp)[g];
        bad = ((v & 0x7F80u) == 0x7F80u);
    } else {
        float f = ((const float*)outp)[g];
        bad = !isfinite(f);
    }
    if (bad) atomicAdd(cnt, 1);
}

__global__ __launch_bounds__(64) void las_nansig(void* outp, const int* flag, const int* cnt) {
    if (threadIdx.x != 0) return;
    int c = cnt[0];
    if (c > 0) {
        int cc = c < 9999 ? c : 9999;
        float sig = 10000.0f * (float)(1 + flag[0]) + (float)cc;
        if (flag[0]) ((u16*)outp)[0] = f2bf(sig);
        else         ((float*)outp)[0] = sig;
    }
}

// ---------------- host ----------------

extern "C" void kernel_launch(void* const* d_in, const int* in_sizes, int n_in,
                              void* d_out, int out_size, void* d_ws, size_t ws_size,
                              hipStream_t stream) {
    const void* keys     = d_in[0];
    const void* values   = d_in[1];
    const int* label     = (const int*)d_in[2];
    const int* input_len = (const int*)d_in[4];

    float* F     = (float*)d_ws;
    float* q     = F + O_QUERY;
    float* nq    = F + O_NQ;
    float* wk    = F + O_WK;
    float* kb    = F + O_KB;
    int*   flag  = (int*)(F + O_FLAG);
    float* av    = F + O_AV;
    float* head  = F + O_HEAD;
    float* ctxT  = F + O_CTXT;
    float* embg  = F + O_EMBG;
    float* ctxg  = F + O_CTXG;
    float* ctxp1 = F + O_CTXP1;
    float* ybuf  = F + O_C0T;                   // y[2][32768] f32
    int*   labT  = (int*)(F + O_LABT);
    u16*   h0f   = (u16*)(F + O_H0T);           // [2][2][65536] bf16 frag
    u16*   h1f   = (u16*)(F + O_H1T);
    u16*   h2f   = (u16*)(F + O_H2T);           // [2][2][32768]
    u16*   cw    = (u16*)d_ws + 2 * (size_t)O_CANON;

    static const unsigned kLen[NSEG] = {
        17408, 34, 262144, 512, 262144, 512, 262144, 512, 262144, 512,
        262144, 512, 524288, 512, 4194304, 4194304, 4096, 4096, 1024, 1024,
        4194304, 4194304, 4096, 4096, 1024, 1024, 2097152, 1048576, 2048, 2048,
        512, 512
    };
    Cvt cv;
    const u16* cwp[NSEG];
    unsigned o = 0;
    for (int i = 0; i < NSEG; i++) {
        cv.src[i] = d_in[6 + i];
        cv.ofs[i] = o;
        cv.len[i] = kLen[i];
        cwp[i] = cw + o;
        o += (kLen[i] + 7u) & ~7u;
    }
    cv.ofs[NSEG] = o;

    const u16 *W_emb = cwp[0], *b_proj2 = cwp[1], *W_query = cwp[2], *b_query = cwp[3];
    const u16 *Wk = cwp[4], *bk = cwp[5], *Wq = cwp[6], *bq = cwp[7];
    const u16 *Wv = cwp[8], *bv = cwp[9], *W_mh = cwp[10], *b_mh = cwp[11];
    const u16 *W_p1 = cwp[12], *b_p1 = cwp[13], *Wih0 = cwp[14], *Whh0 = cwp[15];
    const u16 *bih0 = cwp[16], *bhh0 = cwp[17], *h00 = cwp[18], *c00 = cwp[19];
    const u16 *Wih1 = cwp[20], *Whh1 = cwp[21], *bih1 = cwp[22], *bhh1 = cwp[23];
    const u16 *h01 = cwp[24], *c01 = cwp[25], *Wih2 = cwp[26], *Whh2 = cwp[27];
    const u16 *bih2 = cwp[28], *bhh2 = cwp[29], *h02 = cwp[30], *c02 = cwp[31];

    // dtype detect + canonicalize (also zeroes nan + barrier counters)
    las_detect<<<1, 256, 0, stream>>>((const u16*)d_in[8], flag);
    las_convert<<<4096, 256, 0, stream>>>(cv, flag, cw);

    // one-time setup
    las_init<<<256, 256, 0, stream>>>(h00, h01, h02, label, h0f, h1f, h2f, labT);
    las_query<<<2, 256, 0, stream>>>(h02, W_query, b_query, q);
    las_nq<<<2, 256, 0, stream>>>(q, Wq, bq, nq);
    las_wk<<<8, 256, 0, stream>>>(nq, Wk, bk, wk, kb);
    las_attn<<<64, 256, 0, stream>>>(keys, values, input_len, flag, wk, kb, av);
    las_head<<<128, 256, 0, stream>>>(av, Wv, bv, head);
    las_ctx<<<128, 256, 0, stream>>>(head, W_mh, b_mh, ctxT);
    las_embg<<<545, 256, 0, stream>>>(W_emb, Wih0, embg);
    las_ctxg<<<1024, 256, 0, stream>>>(ctxT, Wih0, bih0, bhh0, ctxg);
    las_ctxp1<<<128, 256, 0, stream>>>(ctxT, W_p1, b_p1, ctxp1);

    // full decode: one persistent MFMA kernel
    las_decode<<<256, 256, 0, stream>>>(
        embg, ctxg, ctxp1, labT,
        Whh0, Wih1, Whh1, bih1, bhh1,
        Wih2, Whh2, bih2, bhh2,
        W_p1, W_emb, b_proj2,
        c00, c01, c02,
        h0f, h1f, h2f, ybuf,
        flag, flag + 2, d_out);

    int n_out = 64 * 255 * 34;
    las_nanscan<<<(n_out + 255) / 256, 256, 0, stream>>>(d_out, flag, flag + 1, n_out);
    las_nansig<<<1, 64, 0, stream>>>(d_out, flag, flag + 1);
}

// Round 3
// 9653.757 us; speedup vs baseline: 5.9349x; 2.1941x over previous
//
#include <hip/hip_runtime.h>

typedef unsigned short u16;
typedef unsigned int   u32;
typedef float f32x4 __attribute__((ext_vector_type(4)));
typedef short short8 __attribute__((ext_vector_type(8)));

#define SCALE_F 0.08838834764831845f  // 1/sqrt(128)

// ---------- ws layout (float offsets) ----------
#define O_QUERY  0           // 512
#define O_NQ     512         // 512
#define O_WK     1024        // 2048
#define O_KB     3072        // 4  (flag ints at 3080..: [0]=isbf16 [1]=nan [2]=release [16..271]=arrive)
#define O_FLAG   3080
#define O_AV     4096        // 64*4*512 = 131072
#define O_HEAD   135168      // 64*512  = 32768
#define O_CTXT   167936      // 512*64  = 32768
#define O_EMBG   200704      // 4096*34 = 139264
#define O_CTXG   339968      // 4096*64 = 262144
#define O_CTXP1  602112      // 512*64  = 32768
#define O_H0T    634880      // h0 frag bf16 [2 parity][2 hi/lo][65536] = 131072 floats
#define O_C0T    765952      // y[2][32768] f32 = 65536 floats (repurposed)
#define O_H1T    831488      // h1 frag = 131072 floats
#define O_C1T    962560      // (unused)
#define O_H2T    1028096     // h2 frag [2][2][32768] = 65536 floats
#define O_C2T    1093632     // (unused)
#define O_YT     1126400     // (unused)
#define O_LABT   1159168     // 255*64 ints
#define O_CANON  1175552     // canonical bf16 weights start (u16 ofs = 2*O_CANON)

__device__ __forceinline__ float bfc(u16 x) {
    return __uint_as_float(((u32)x) << 16);
}
__device__ __forceinline__ float2 bfpair(u32 u) {
    return make_float2(__uint_as_float(u << 16), __uint_as_float(u & 0xffff0000u));
}
__device__ __forceinline__ u16 f2bf(float f) {
    u32 u = __float_as_uint(f);
    u += 0x7fffu + ((u >> 16) & 1u);
    return (u16)(u >> 16);
}
__device__ __forceinline__ float sigf(float x) { return 1.0f / (1.0f + __expf(-x)); }
__device__ __forceinline__ float tanh_(float x) { return 2.0f / (1.0f + __expf(-2.0f * x)) - 1.0f; }

__device__ __forceinline__ void fma8(float& acc, uint4 a, const float h[8]) {
    float2 p;
    p = bfpair(a.x); acc = fmaf(h[0], p.x, acc); acc = fmaf(h[1], p.y, acc);
    p = bfpair(a.y); acc = fmaf(h[2], p.x, acc); acc = fmaf(h[3], p.y, acc);
    p = bfpair(a.z); acc = fmaf(h[4], p.x, acc); acc = fmaf(h[5], p.y, acc);
    p = bfpair(a.w); acc = fmaf(h[6], p.x, acc); acc = fmaf(h[7], p.y, acc);
}

__device__ __forceinline__ f32x4 mfma16(short8 a, short8 b, f32x4 c) {
    return __builtin_amdgcn_mfma_f32_16x16x32_bf16(a, b, c, 0, 0, 0);
}
__device__ __forceinline__ short8 ld8g(const u16* p) {
    uint4 v = *(const uint4*)p;
    return __builtin_bit_cast(short8, v);
}
// frag index of element (k,col) in a B-frag-layout h buffer
__device__ __forceinline__ int fidx(int k, int col) {
    return ((k >> 5) * 4 + (col >> 4)) * 512 + (((k >> 2) & 3) * 16 + (col & 15)) * 8 +
           ((k >> 4) & 1) * 4 + (k & 3);
}
// producer store: lane's h value for cell k=4*bx+(l>>4), col=w*16+(l&15); hi+lo split
__device__ __forceinline__ void storeH(u16* buf, int HL, int bx, int w, int l, float v) {
    int idx = ((bx >> 3) * 4 + w) * 512 + ((bx & 3) * 16 + (l & 15)) * 8 +
              ((bx >> 2) & 1) * 4 + (l >> 4);
    u16 hi = f2bf(v);
    buf[idx] = hi;
    buf[idx + HL] = f2bf(v - bfc(hi));
}

// ---------------- dtype detect + canonicalize ----------------

__global__ __launch_bounds__(256) void las_detect(const u16* w, int* flag) {
    __shared__ int s[256];
    int bad = 0;
    for (int i = threadIdx.x; i < 65536; i += 256) {
        u16 v = w[i];
        if ((v & 0x7F80u) == 0x7F80u) bad++;
        else if (fabsf(bfc(v)) > 1e4f) bad++;
    }
    s[threadIdx.x] = bad; __syncthreads();
    for (int o = 128; o; o >>= 1) {
        if (threadIdx.x < o) s[threadIdx.x] += s[threadIdx.x + o];
        __syncthreads();
    }
    flag[16 + threadIdx.x] = 0;   // zero the 256 arrive slots
    if (threadIdx.x == 0) { flag[0] = (s[0] == 0) ? 1 : 0; flag[1] = 0; flag[2] = 0; }
}

#define NSEG 32
struct Cvt {
    const void* src[NSEG];
    unsigned ofs[NSEG + 1];
    unsigned len[NSEG];
};

__global__ __launch_bounds__(256) void las_convert(Cvt c, const int* flag, u16* dst) {
    int isb = flag[0];
    unsigned total = c.ofs[NSEG] >> 1;
    for (unsigned p = blockIdx.x * 256 + threadIdx.x; p < total; p += gridDim.x * 256) {
        unsigned e = p << 1;
        int lo = 0, hi = NSEG;
        while (hi - lo > 1) { int mid = (lo + hi) >> 1; if (c.ofs[mid] <= e) lo = mid; else hi = mid; }
        unsigned local = e - c.ofs[lo];
        u32 out;
        if (local >= c.len[lo]) {
            out = 0;
        } else if (isb) {
            out = ((const u32*)c.src[lo])[local >> 1];
        } else {
            const float* s = (const float*)c.src[lo];
            u32 a = f2bf(s[local]), b = f2bf(s[local + 1]);
            out = a | (b << 16);
        }
        ((u32*)dst)[p] = out;
    }
}

// ---------------- one-time kernels ----------------

// initial states go to PARITY 1 (tick 0 reads parity 1 for all three h buffers)
__global__ __launch_bounds__(256) void las_init(
    const u16* h00, const u16* h01, const u16* h02, const int* label,
    u16* h0f, u16* h1f, u16* h2f, int* labT) {
    int idx = blockIdx.x * 256 + threadIdx.x;   // 65536 threads
    int k = idx >> 6, col = idx & 63;
    int fi = fidx(k, col);
    h0f[131072 + fi] = h00[k]; h0f[131072 + 65536 + fi] = 0;
    h1f[131072 + fi] = h01[k]; h1f[131072 + 65536 + fi] = 0;
    if (k < 512) { h2f[65536 + fi] = h02[k]; h2f[65536 + 32768 + fi] = 0; }
    if (k < 255) labT[idx] = label[col * 256 + k];
}

__global__ __launch_bounds__(256) void las_query(const u16* h02, const u16* W_query,
                                                 const u16* b_query, float* query) {
    int i = blockIdx.x * 256 + threadIdx.x;     // < 512
    float acc = bfc(b_query[i]);
    const u32* wr = (const u32*)(W_query + (size_t)i * 512);
    const u32* hp = (const u32*)h02;
    for (int h = 0; h < 512; h += 8) {
        uint4 wv = *(const uint4*)(wr + (h >> 1));
        uint4 hv = *(const uint4*)(hp + (h >> 1));
        float2 a, c;
        a = bfpair(wv.x); c = bfpair(hv.x); acc = fmaf(a.x, c.x, acc); acc = fmaf(a.y, c.y, acc);
        a = bfpair(wv.y); c = bfpair(hv.y); acc = fmaf(a.x, c.x, acc); acc = fmaf(a.y, c.y, acc);
        a = bfpair(wv.z); c = bfpair(hv.z); acc = fmaf(a.x, c.x, acc); acc = fmaf(a.y, c.y, acc);
        a = bfpair(wv.w); c = bfpair(hv.w); acc = fmaf(a.x, c.x, acc); acc = fmaf(a.y, c.y, acc);
    }
    query[i] = acc;
}

__global__ __launch_bounds__(256) void las_nq(const float* query, const u16* Wq,
                                              const u16* bq, float* nq) {
    int nd = blockIdx.x * 256 + threadIdx.x;    // < 512
    float acc = bfc(bq[nd]);
    const u32* wr = (const u32*)(Wq + (size_t)nd * 512);
    for (int h = 0; h < 512; h += 8) {
        uint4 wv = *(const uint4*)(wr + (h >> 1));
        float2 p;
        p = bfpair(wv.x); acc = fmaf(p.x, query[h + 0], acc); acc = fmaf(p.y, query[h + 1], acc);
        p = bfpair(wv.y); acc = fmaf(p.x, query[h + 2], acc); acc = fmaf(p.y, query[h + 3], acc);
        p = bfpair(wv.z); acc = fmaf(p.x, query[h + 4], acc); acc = fmaf(p.y, query[h + 5], acc);
        p = bfpair(wv.w); acc = fmaf(p.x, query[h + 6], acc); acc = fmaf(p.y, query[h + 7], acc);
    }
    nq[nd] = acc;
}

__global__ __launch_bounds__(256) void las_wk(const float* nq, const u16* Wk, const u16* bk,
                                              float* wk, float* kb) {
    int idx = blockIdx.x * 256 + threadIdx.x;   // < 2048
    int n = idx >> 9, h = idx & 511;
    float acc = 0.0f;
    for (int d = 0; d < 128; d++)
        acc = fmaf(nq[n * 128 + d], bfc(Wk[((size_t)(n * 128 + d)) * 512 + h]), acc);
    wk[idx] = acc;
    if (idx < 4) {
        float kk = 0.0f;
        for (int d = 0; d < 128; d++) kk = fmaf(nq[idx * 128 + d], bfc(bk[idx * 128 + d]), kk);
        kb[idx] = kk;
    }
}

__global__ __launch_bounds__(256) void las_attn(const void* keysv, const void* valuesv,
                                                const int* input_len, const int* flag,
                                                const float* wk, const float* kb, float* av) {
    __shared__ float wk_s[2048];
    __shared__ float kb_s[4];
    __shared__ float sm[4][1024];
    __shared__ float red[256];
    __shared__ float stat[4];
    const u16* keysB = (const u16*)keysv;
    const float* keysF = (const float*)keysv;
    const u16* valB = (const u16*)valuesv;
    const float* valF = (const float*)valuesv;
    int b = blockIdx.x;
    int tid = threadIdx.x;
    int isb = flag[0];
    for (int i = tid; i < 2048; i += 256) wk_s[i] = wk[i];
    if (tid < 4) kb_s[tid] = kb[tid];
    __syncthreads();
    int len = input_len[b];

    {
        float acc[4][4];
#pragma unroll
        for (int tl = 0; tl < 4; tl++)
#pragma unroll
            for (int n = 0; n < 4; n++) acc[tl][n] = kb_s[n];
        for (int h = 0; h < 512; h += 8) {
            float kf[4][8];
#pragma unroll
            for (int tl = 0; tl < 4; tl++) {
                int t = tid + 256 * tl;
                size_t base = ((size_t)t * 64 + b) * 512 + h;
                if (isb) {
                    uint4 kv = *(const uint4*)(keysB + base);
                    float2 p;
                    p = bfpair(kv.x); kf[tl][0] = p.x; kf[tl][1] = p.y;
                    p = bfpair(kv.y); kf[tl][2] = p.x; kf[tl][3] = p.y;
                    p = bfpair(kv.z); kf[tl][4] = p.x; kf[tl][5] = p.y;
                    p = bfpair(kv.w); kf[tl][6] = p.x; kf[tl][7] = p.y;
                } else {
                    const float4* kp = (const float4*)(keysF + base);
                    float4 q0 = kp[0], q1 = kp[1];
                    kf[tl][0] = q0.x; kf[tl][1] = q0.y; kf[tl][2] = q0.z; kf[tl][3] = q0.w;
                    kf[tl][4] = q1.x; kf[tl][5] = q1.y; kf[tl][6] = q1.z; kf[tl][7] = q1.w;
                }
            }
#pragma unroll
            for (int i = 0; i < 8; i++) {
                float w0 = wk_s[h + i], w1 = wk_s[512 + h + i];
                float w2 = wk_s[1024 + h + i], w3 = wk_s[1536 + h + i];
#pragma unroll
                for (int tl = 0; tl < 4; tl++) {
                    acc[tl][0] = fmaf(kf[tl][i], w0, acc[tl][0]);
                    acc[tl][1] = fmaf(kf[tl][i], w1, acc[tl][1]);
                    acc[tl][2] = fmaf(kf[tl][i], w2, acc[tl][2]);
                    acc[tl][3] = fmaf(kf[tl][i], w3, acc[tl][3]);
                }
            }
        }
#pragma unroll
        for (int tl = 0; tl < 4; tl++) {
            int t = tid + 256 * tl;
#pragma unroll
            for (int n = 0; n < 4; n++)
                sm[n][t] = (t < len) ? acc[tl][n] * SCALE_F : -1e30f;
        }
    }
    __syncthreads();

    for (int n = 0; n < 4; n++) {
        float m = -1e30f;
        for (int tl = 0; tl < 4; tl++) m = fmaxf(m, sm[n][tid + 256 * tl]);
        red[tid] = m; __syncthreads();
        for (int off = 128; off; off >>= 1) {
            if (tid < off) red[tid] = fmaxf(red[tid], red[tid + off]);
            __syncthreads();
        }
        m = red[0]; __syncthreads();
        float e = 0.0f;
        for (int tl = 0; tl < 4; tl++) {
            int t = tid + 256 * tl;
            float x = (t < len) ? __expf(sm[n][t] - m) : 0.0f;
            sm[n][t] = x; e += x;
        }
        red[tid] = e; __syncthreads();
        for (int off = 128; off; off >>= 1) {
            if (tid < off) red[tid] += red[tid + off];
            __syncthreads();
        }
        if (tid == 0) stat[n] = 1.0f / red[0];
        __syncthreads();
    }

    {
        float a[4][2] = {};
        int h0 = 2 * tid;
        for (int t = 0; t < len; t++) {
            size_t base = ((size_t)t * 64 + b) * 512 + h0;
            float2 p;
            if (isb) p = bfpair(*(const u32*)(valB + base));
            else     p = *(const float2*)(valF + base);
            float s0 = sm[0][t], s1 = sm[1][t], s2 = sm[2][t], s3 = sm[3][t];
            a[0][0] = fmaf(s0, p.x, a[0][0]); a[0][1] = fmaf(s0, p.y, a[0][1]);
            a[1][0] = fmaf(s1, p.x, a[1][0]); a[1][1] = fmaf(s1, p.y, a[1][1]);
            a[2][0] = fmaf(s2, p.x, a[2][0]); a[2][1] = fmaf(s2, p.y, a[2][1]);
            a[3][0] = fmaf(s3, p.x, a[3][0]); a[3][1] = fmaf(s3, p.y, a[3][1]);
        }
#pragma unroll
        for (int n = 0; n < 4; n++) {
            av[((size_t)b * 4 + n) * 512 + h0]     = a[n][0] * stat[n];
            av[((size_t)b * 4 + n) * 512 + h0 + 1] = a[n][1] * stat[n];
        }
    }
}

__global__ __launch_bounds__(256) void las_head(const float* av, const u16* Wv, const u16* bv,
                                                float* head) {
    int idx = blockIdx.x * 256 + threadIdx.x;   // < 32768
    int b = idx >> 9, nd = idx & 511, n = nd >> 7;
    float acc = bfc(bv[nd]);
    const u32* wr = (const u32*)(Wv + (size_t)nd * 512);
    const float* ap = av + ((size_t)b * 4 + n) * 512;
    for (int h = 0; h < 512; h += 8) {
        uint4 wv = *(const uint4*)(wr + (h >> 1));
        float2 p;
        p = bfpair(wv.x); acc = fmaf(p.x, ap[h + 0], acc); acc = fmaf(p.y, ap[h + 1], acc);
        p = bfpair(wv.y); acc = fmaf(p.x, ap[h + 2], acc); acc = fmaf(p.y, ap[h + 3], acc);
        p = bfpair(wv.z); acc = fmaf(p.x, ap[h + 4], acc); acc = fmaf(p.y, ap[h + 5], acc);
        p = bfpair(wv.w); acc = fmaf(p.x, ap[h + 6], acc); acc = fmaf(p.y, ap[h + 7], acc);
    }
    head[idx] = acc;
}

__global__ __launch_bounds__(256) void las_ctx(const float* head, const u16* W_mh, const u16* b_mh,
                                               float* ctxT) {
    int idx = blockIdx.x * 256 + threadIdx.x;   // < 32768
    int b = idx >> 9, i = idx & 511;
    float acc = bfc(b_mh[i]);
    const u32* wr = (const u32*)(W_mh + (size_t)i * 512);
    const float* hp = head + (size_t)b * 512;
    for (int h = 0; h < 512; h += 8) {
        uint4 wv = *(const uint4*)(wr + (h >> 1));
        float2 p;
        p = bfpair(wv.x); acc = fmaf(p.x, hp[h + 0], acc); acc = fmaf(p.y, hp[h + 1], acc);
        p = bfpair(wv.y); acc = fmaf(p.x, hp[h + 2], acc); acc = fmaf(p.y, hp[h + 3], acc);
        p = bfpair(wv.z); acc = fmaf(p.x, hp[h + 4], acc); acc = fmaf(p.y, hp[h + 5], acc);
        p = bfpair(wv.w); acc = fmaf(p.x, hp[h + 6], acc); acc = fmaf(p.y, hp[h + 7], acc);
    }
    ctxT[(size_t)i * 64 + b] = acc;
}

__global__ __launch_bounds__(256) void las_embg(const u16* W_emb, const u16* Wih0, float* embg) {
    int idx = blockIdx.x * 256 + threadIdx.x;
    if (idx >= 4096 * 34) return;
    int row = idx / 34, v = idx - row * 34;
    const u32* wr = (const u32*)(Wih0 + (size_t)row * 1024);
    const u32* er = (const u32*)(W_emb + (size_t)v * 512);
    float acc = 0.0f;
    for (int h = 0; h < 512; h += 8) {
        uint4 wv = *(const uint4*)(wr + (h >> 1));
        uint4 ev = *(const uint4*)(er + (h >> 1));
        float2 a, c;
        a = bfpair(wv.x); c = bfpair(ev.x); acc = fmaf(a.x, c.x, acc); acc = fmaf(a.y, c.y, acc);
        a = bfpair(wv.y); c = bfpair(ev.y); acc = fmaf(a.x, c.x, acc); acc = fmaf(a.y, c.y, acc);
        a = bfpair(wv.z); c = bfpair(ev.z); acc = fmaf(a.x, c.x, acc); acc = fmaf(a.y, c.y, acc);
        a = bfpair(wv.w); c = bfpair(ev.w); acc = fmaf(a.x, c.x, acc); acc = fmaf(a.y, c.y, acc);
    }
    embg[idx] = acc;
}

__global__ __launch_bounds__(256) void las_ctxg(const float* ctxT, const u16* Wih0,
                                                const u16* bih0, const u16* bhh0, float* ctxg) {
    int lane = threadIdx.x & 63, w = threadIdx.x >> 6;
    int row = blockIdx.x * 4 + w;               // < 4096
    float acc = bfc(bih0[row]) + bfc(bhh0[row]);
    const u32* wr = (const u32*)(Wih0 + (size_t)row * 1024 + 512);
    for (int h = 0; h < 512; h += 8) {
        float hv[8];
#pragma unroll
        for (int i = 0; i < 8; i++) hv[i] = ctxT[(size_t)(h + i) * 64 + lane];
        uint4 wv = *(const uint4*)(wr + (h >> 1));
        fma8(acc, wv, hv);
    }
    ctxg[(size_t)row * 64 + lane] = acc;
}

__global__ __launch_bounds__(256) void las_ctxp1(const float* ctxT, const u16* W_p1,
                                                 const u16* b_p1, float* ctxp1) {
    int lane = threadIdx.x & 63, w = threadIdx.x >> 6;
    int i = blockIdx.x * 4 + w;                 // < 512
    float acc = bfc(b_p1[i]);
    const u32* wr = (const u32*)(W_p1 + (size_t)i * 1024 + 512);
    for (int h = 0; h < 512; h += 8) {
        float hv[8];
#pragma unroll
        for (int k = 0; k < 8; k++) hv[k] = ctxT[(size_t)(h + k) * 64 + lane];
        uint4 wv = *(const uint4*)(wr + (h >> 1));
        fma8(acc, wv, hv);
    }
    ctxp1[(size_t)i * 64 + lane] = acc;
}

// ---------------- persistent MFMA decode kernel (layer-pipelined) ----------------
// At tick tau: l0(tau), l1(tau-1), l2(tau-2) [bx<128], p3a(tau-3) [128..159],
// p3b(tau-4) [160..223]. Every dependency is exactly one tick old -> ONE grid
// barrier per tick (259 ticks total). Shared B-loads: h0(tau-1) feeds l0+l1-x;
// h1(tau-2) feeds l1-h+l2-x. Barrier = store-arrive slots + aggregator (block
// 255) + load-polled release word: no atomic RMW anywhere.

__device__ __forceinline__ void gridbar(int* arr, int* rel, int epoch) {
    __syncthreads();                              // all waves' stores vmcnt-drained
    const int bx = blockIdx.x;
    if (threadIdx.x == 0) {
        __threadfence();                          // publish this XCD's L2 (release)
        __hip_atomic_store(&arr[bx], epoch, __ATOMIC_RELAXED, __HIP_MEMORY_SCOPE_AGENT);
    }
    if (bx == 255 && threadIdx.x < 64) {          // aggregator wave
        int iters = 0;
        for (;;) {
            int ok = 1;
#pragma unroll
            for (int q = 0; q < 4; q++) {
                int v = __hip_atomic_load(&arr[threadIdx.x * 4 + q],
                                          __ATOMIC_RELAXED, __HIP_MEMORY_SCOPE_AGENT);
                ok &= (v >= epoch);
            }
            if (__all(ok)) break;
            if (++iters > (1 << 22)) break;       // bounded: corrupts instead of hanging
            __builtin_amdgcn_s_sleep(1);
        }
        if (threadIdx.x == 0)
            __hip_atomic_store(rel, epoch, __ATOMIC_RELAXED, __HIP_MEMORY_SCOPE_AGENT);
    }
    if (threadIdx.x == 0) {
        int iters = 0;
        while (__hip_atomic_load(rel, __ATOMIC_RELAXED, __HIP_MEMORY_SCOPE_AGENT) < epoch) {
            __builtin_amdgcn_s_sleep(1);
            if (++iters > (1 << 22)) break;
        }
        __threadfence();                          // acquire: invalidate L1/L2
    }
    __syncthreads();
}

__global__ __launch_bounds__(256, 1) void las_decode(
    const float* embg, const float* ctxg, const float* ctxp1, const int* labT,
    const u16* Whh0, const u16* Wih1, const u16* Whh1,
    const u16* bih1, const u16* bhh1,
    const u16* Wih2, const u16* Whh2, const u16* bih2, const u16* bhh2,
    const u16* W_p1, const u16* W_emb, const u16* b_proj2,
    const u16* c00, const u16* c01, const u16* c02,
    u16* h0f, u16* h1f, u16* h2f, float* ybuf,
    int* flag, void* outp) {

    __shared__ __align__(16) u16 A0[32 * 64 * 8];   // 32 KB  Whh0 A-frags
    __shared__ __align__(16) u16 A1[64 * 64 * 8];   // 64 KB  Wih1|Whh1 A-frags
    __shared__ __align__(16) u16 A2[48 * 64 * 8];   // 48 KB  Wih2|Whh2 (bx<128) or W_p1 (128..159)
    __shared__ float ylds[512];                     //  2 KB  p3b scratch

    const int tid = threadIdx.x, l = tid & 63, w = tid >> 6;
    const int bx = blockIdx.x;
    const int isb = flag[0];
    int* arr = flag + 16;
    int* rel = flag + 2;
    const int HL0 = 65536, HL2 = 32768;

    // ---- stage A-fragments once ----
    for (int i = tid; i < 32 * 64 * 2; i += 256) {
        int kt = i >> 7, ll = (i >> 1) & 63, half = i & 1;
        int r = ll & 15;
        int row = (r & 3) * 1024 + 4 * bx + (r >> 2);
        int kc = kt * 32 + half * 16 + 4 * (ll >> 4);
        *(uint2*)&A0[(kt * 64 + ll) * 8 + half * 4] = *(const uint2*)(Whh0 + (size_t)row * 1024 + kc);
    }
    for (int i = tid; i < 64 * 64 * 2; i += 256) {
        int kt = i >> 7, ll = (i >> 1) & 63, half = i & 1;
        int r = ll & 15;
        int row = (r & 3) * 1024 + 4 * bx + (r >> 2);
        int kc = kt * 32 + half * 16 + 4 * (ll >> 4);
        const u16* src = (kc < 1024) ? (Wih1 + (size_t)row * 1024 + kc)
                                     : (Whh1 + (size_t)row * 1024 + (kc - 1024));
        *(uint2*)&A1[(kt * 64 + ll) * 8 + half * 4] = *(const uint2*)src;
    }
    if (bx < 128) {
        for (int i = tid; i < 48 * 64 * 2; i += 256) {
            int kt = i >> 7, ll = (i >> 1) & 63, half = i & 1;
            int r = ll & 15;
            int row = (r & 3) * 512 + 4 * bx + (r >> 2);
            int kc = kt * 32 + half * 16 + 4 * (ll >> 4);
            const u16* src = (kc < 1024) ? (Wih2 + (size_t)row * 1024 + kc)
                                         : (Whh2 + (size_t)row * 512 + (kc - 1024));
            *(uint2*)&A2[(kt * 64 + ll) * 8 + half * 4] = *(const uint2*)src;
        }
    } else if (bx < 160) {
        int mt = bx - 128;
        for (int i = tid; i < 16 * 64 * 2; i += 256) {
            int kt = i >> 7, ll = (i >> 1) & 63, half = i & 1;
            int row = 16 * mt + (ll & 15);
            int kc = kt * 32 + half * 16 + 4 * (ll >> 4);
            *(uint2*)&A2[(kt * 64 + ll) * 8 + half * 4] = *(const uint2*)(W_p1 + (size_t)row * 1024 + kc);
        }
    }

    // ---- persistent per-lane state ----
    const int cell01 = 4 * bx + (l >> 4);
    const int bcol = w * 16 + (l & 15);
    float c0reg = bfc(c00[cell01]);
    float c1reg = bfc(c01[cell01]);
    float pre0c[4], pre1c[4], pre2c[4], prep3[4];
#pragma unroll
    for (int r = 0; r < 4; r++) {
        int row = r * 1024 + cell01;
        pre0c[r] = ctxg[(size_t)row * 64 + bcol];
        pre1c[r] = bfc(bih1[row]) + bfc(bhh1[row]);
        pre2c[r] = 0.0f; prep3[r] = 0.0f;
    }
    float c2reg = 0.0f;
    if (bx < 128) {
        int cell2 = 4 * bx + (l >> 4);
        c2reg = bfc(c02[cell2]);
#pragma unroll
        for (int r = 0; r < 4; r++) {
            int row = r * 512 + cell2;
            pre2c[r] = bfc(bih2[row]) + bfc(bhh2[row]);
        }
    } else if (bx < 160) {
#pragma unroll
        for (int r = 0; r < 4; r++) {
            int yi = 16 * (bx - 128) + 4 * (l >> 4) + r;
            prep3[r] = ctxp1[(size_t)yi * 64 + bcol];
        }
    }
    __syncthreads();

    for (int tau = 0; tau < 259; tau++) {
        const bool do0 = (tau < 255);
        const bool do1 = (tau >= 1) && (tau <= 255);
        const bool do2 = (tau >= 2) && (tau <= 256) && (bx < 128);
        const bool do3 = (tau >= 3) && (tau <= 257) && (bx >= 128) && (bx < 160);
        const bool do4 = (tau >= 4) && (bx >= 160) && (bx < 224);

        // parity map: h_X(t) is stored at parity t&1; initial states at parity 1
        const u16* h0r = h0f + ((tau + 1) & 1) * 131072;   // h0(tau-1)
        u16*       h0w = h0f + (tau & 1) * 131072;         // h0(tau)
        const u16* h1r = h1f + (tau & 1) * 131072;         // h1(tau-2)
        u16*       h1w = h1f + ((tau + 1) & 1) * 131072;   // h1(tau-1)
        const u16* h2r = h2f + ((tau + 1) & 1) * 65536;    // h2(tau-3)
        u16*       h2w = h2f + (tau & 1) * 65536;          // h2(tau-2)
        float*     yw  = ybuf + ((tau + 1) & 1) * 32768;   // y(tau-3)
        const float* yr = ybuf + (tau & 1) * 32768;        // y(tau-4)

        f32x4 a0h = {0.f,0.f,0.f,0.f}, a0l = {0.f,0.f,0.f,0.f};
        f32x4 a1h = {0.f,0.f,0.f,0.f}, a1l = {0.f,0.f,0.f,0.f};
        f32x4 a2h = {0.f,0.f,0.f,0.f}, a2l = {0.f,0.f,0.f,0.f};

        // ---- h0(tau-1) sweep: feeds l0 (A0) and l1-x (A1[0..31]) ----
#pragma unroll 4
        for (int kt = 0; kt < 32; kt++) {
            const u16* bp = h0r + (kt * 4 + w) * 512 + l * 8;
            short8 bh = ld8g(bp), bl = ld8g(bp + HL0);
            short8 aA = *(const short8*)&A0[(kt * 64 + l) * 8];
            short8 aB = *(const short8*)&A1[(kt * 64 + l) * 8];
            a0h = mfma16(aA, bh, a0h); a0l = mfma16(aA, bl, a0l);
            a1h = mfma16(aB, bh, a1h); a1l = mfma16(aB, bl, a1l);
        }
        // ---- h1(tau-2) sweep: feeds l1-h (A1[32..63]) and l2-x (A2[0..31]) ----
        if (bx < 128) {
#pragma unroll 4
            for (int kt = 0; kt < 32; kt++) {
                const u16* bp = h1r + (kt * 4 + w) * 512 + l * 8;
                short8 bh = ld8g(bp), bl = ld8g(bp + HL0);
                short8 aB = *(const short8*)&A1[((kt + 32) * 64 + l) * 8];
                short8 aC = *(const short8*)&A2[(kt * 64 + l) * 8];
                a1h = mfma16(aB, bh, a1h); a1l = mfma16(aB, bl, a1l);
                a2h = mfma16(aC, bh, a2h); a2l = mfma16(aC, bl, a2l);
            }
            // ---- h2(tau-3) sweep: l2-h (A2[32..47]) ----
#pragma unroll 4
            for (int kt = 0; kt < 16; kt++) {
                const u16* bp = h2r + (kt * 4 + w) * 512 + l * 8;
                short8 bh = ld8g(bp), bl = ld8g(bp + HL2);
                short8 aC = *(const short8*)&A2[((kt + 32) * 64 + l) * 8];
                a2h = mfma16(aC, bh, a2h); a2l = mfma16(aC, bl, a2l);
            }
        } else {
#pragma unroll 4
            for (int kt = 0; kt < 32; kt++) {
                const u16* bp = h1r + (kt * 4 + w) * 512 + l * 8;
                short8 bh = ld8g(bp), bl = ld8g(bp + HL0);
                short8 aB = *(const short8*)&A1[((kt + 32) * 64 + l) * 8];
                a1h = mfma16(aB, bh, a1h); a1l = mfma16(aB, bl, a1l);
            }
            if (bx < 160) {
                // p3a: h2(tau-3) sweep with W_p1 frags (A2[0..15])
#pragma unroll 4
                for (int kt = 0; kt < 16; kt++) {
                    const u16* bp = h2r + (kt * 4 + w) * 512 + l * 8;
                    short8 bh = ld8g(bp), bl = ld8g(bp + HL2);
                    short8 aC = *(const short8*)&A2[(kt * 64 + l) * 8];
                    a2h = mfma16(aC, bh, a2h); a2l = mfma16(aC, bl, a2l);
                }
            }
        }

        // ---- epilogues (all writes; sweeps above did all reads) ----
        if (do0) {                                    // l0(tau)
            int vb = labT[tau * 64 + bcol];
            float g0 = a0h[0] + a0l[0] + pre0c[0] + embg[(size_t)(0 * 1024 + cell01) * 34 + vb];
            float g1 = a0h[1] + a0l[1] + pre0c[1] + embg[(size_t)(1 * 1024 + cell01) * 34 + vb];
            float g2 = a0h[2] + a0l[2] + pre0c[2] + embg[(size_t)(2 * 1024 + cell01) * 34 + vb];
            float g3 = a0h[3] + a0l[3] + pre0c[3] + embg[(size_t)(3 * 1024 + cell01) * 34 + vb];
            float c2 = fmaf(sigf(g1), c0reg, sigf(g0) * tanh_(g2));
            c0reg = c2;
            storeH(h0w, HL0, bx, w, l, sigf(g3) * tanh_(c2));
        }
        if (do1) {                                    // l1(tau-1)
            float g0 = a1h[0] + a1l[0] + pre1c[0];
            float g1 = a1h[1] + a1l[1] + pre1c[1];
            float g2 = a1h[2] + a1l[2] + pre1c[2];
            float g3 = a1h[3] + a1l[3] + pre1c[3];
            float c2 = fmaf(sigf(g1), c1reg, sigf(g0) * tanh_(g2));
            c1reg = c2;
            storeH(h1w, HL0, bx, w, l, sigf(g3) * tanh_(c2));
        }
        if (do2) {                                    // l2(tau-2)
            float g0 = a2h[0] + a2l[0] + pre2c[0];
            float g1 = a2h[1] + a2l[1] + pre2c[1];
            float g2 = a2h[2] + a2l[2] + pre2c[2];
            float g3 = a2h[3] + a2l[3] + pre2c[3];
            float c2 = fmaf(sigf(g1), c2reg, sigf(g0) * tanh_(g2));
            c2reg = c2;
            storeH(h2w, HL2, bx, w, l, sigf(g3) * tanh_(c2));
        }
        if (do3) {                                    // p3a(tau-3)
#pragma unroll
            for (int r = 0; r < 4; r++) {
                float v = a2h[r] + a2l[r] + prep3[r];
                v = v > 0.0f ? v : 0.01f * v;         // leaky_relu
                yw[(size_t)(16 * (bx - 128) + 4 * (l >> 4) + r) * 64 + bcol] = v;
            }
        }
        if (do4) {                                    // p3b(tau-4)
            int b = bx - 160;
            for (int i = tid; i < 512; i += 256) ylds[i] = yr[(size_t)i * 64 + b];
            __syncthreads();
            if (w == 0) {
                int v = l;
                float acc = -1e30f;
                if (v < 34) {
                    acc = bfc(b_proj2[v]);
                    const u32* wr = (const u32*)(W_emb + (size_t)v * 512);
                    for (int k2 = 0; k2 < 512; k2 += 8) {
                        uint4 wv = *(const uint4*)(wr + (k2 >> 1));
                        float2 p;
                        p = bfpair(wv.x); acc = fmaf(p.x, ylds[k2 + 0], acc); acc = fmaf(p.y, ylds[k2 + 1], acc);
                        p = bfpair(wv.y); acc = fmaf(p.x, ylds[k2 + 2], acc); acc = fmaf(p.y, ylds[k2 + 3], acc);
                        p = bfpair(wv.z); acc = fmaf(p.x, ylds[k2 + 4], acc); acc = fmaf(p.y, ylds[k2 + 5], acc);
                        p = bfpair(wv.w); acc = fmaf(p.x, ylds[k2 + 6], acc); acc = fmaf(p.y, ylds[k2 + 7], acc);
                    }
                }
                float m = acc;
                for (int off = 32; off; off >>= 1) m = fmaxf(m, __shfl_xor(m, off, 64));
                float e = (v < 34) ? __expf(acc - m) : 0.0f;
                float s = e;
                for (int off = 32; off; off >>= 1) s += __shfl_xor(s, off, 64);
                if (v < 34) {
                    float rr = acc - m - __logf(s);
                    size_t o = ((size_t)b * 255 + (tau - 4)) * 34 + v;
                    if (isb) ((u16*)outp)[o] = f2bf(rr);
                    else     ((float*)outp)[o] = rr;
                }
            }
        }

        gridbar(arr, rel, tau + 1);
    }
}

// ---------------- failure instrumentation ----------------

__global__ __launch_bounds__(256) void las_nanscan(const void* outp, const int* flag, int* cnt, int n) {
    int g = blockIdx.x * 256 + threadIdx.x;
    if (g >= n) return;
    bool bad;
    if (flag[0]) {
        u16 v = ((const u16*)outp)[g];
        bad = ((v & 0x7F80u) == 0x7F80u);
    } else {
        float f = ((const float*)outp)[g];
        bad = !isfinite(f);
    }
    if (bad) atomicAdd(cnt, 1);
}

__global__ __launch_bounds__(64) void las_nansig(void* outp, const int* flag, const int* cnt) {
    if (threadIdx.x != 0) return;
    int c = cnt[0];
    if (c > 0) {
        int cc = c < 9999 ? c : 9999;
        float sig = 10000.0f * (float)(1 + flag[0]) + (float)cc;
        if (flag[0]) ((u16*)outp)[0] = f2bf(sig);
        else         ((float*)outp)[0] = sig;
    }
}

// ---------------- host ----------------

extern "C" void kernel_launch(void* const* d_in, const int* in_sizes, int n_in,
                              void* d_out, int out_size, void* d_ws, size_t ws_size,
                              hipStream_t stream) {
    const void* keys     = d_in[0];
    const void* values   = d_in[1];
    const int* label     = (const int*)d_in[2];
    const int* input_len = (const int*)d_in[4];

    float* F     = (float*)d_ws;
    float* q     = F + O_QUERY;
    float* nq    = F + O_NQ;
    float* wk    = F + O_WK;
    float* kb    = F + O_KB;
    int*   flag  = (int*)(F + O_FLAG);
    float* av    = F + O_AV;
    float* head  = F + O_HEAD;
    float* ctxT  = F + O_CTXT;
    float* embg  = F + O_EMBG;
    float* ctxg  = F + O_CTXG;
    float* ctxp1 = F + O_CTXP1;
    float* ybuf  = F + O_C0T;                   // y[2][32768] f32
    int*   labT  = (int*)(F + O_LABT);
    u16*   h0f   = (u16*)(F + O_H0T);           // [2 parity][2 hi/lo][65536] bf16 frag
    u16*   h1f   = (u16*)(F + O_H1T);
    u16*   h2f   = (u16*)(F + O_H2T);           // [2][2][32768]
    u16*   cw    = (u16*)d_ws + 2 * (size_t)O_CANON;

    static const unsigned kLen[NSEG] = {
        17408, 34, 262144, 512, 262144, 512, 262144, 512, 262144, 512,
        262144, 512, 524288, 512, 4194304, 4194304, 4096, 4096, 1024, 1024,
        4194304, 4194304, 4096, 4096, 1024, 1024, 2097152, 1048576, 2048, 2048,
        512, 512
    };
    Cvt cv;
    const u16* cwp[NSEG];
    unsigned o = 0;
    for (int i = 0; i < NSEG; i++) {
        cv.src[i] = d_in[6 + i];
        cv.ofs[i] = o;
        cv.len[i] = kLen[i];
        cwp[i] = cw + o;
        o += (kLen[i] + 7u) & ~7u;
    }
    cv.ofs[NSEG] = o;

    const u16 *W_emb = cwp[0], *b_proj2 = cwp[1], *W_query = cwp[2], *b_query = cwp[3];
    const u16 *Wk = cwp[4], *bk = cwp[5], *Wq = cwp[6], *bq = cwp[7];
    const u16 *Wv = cwp[8], *bv = cwp[9], *W_mh = cwp[10], *b_mh = cwp[11];
    const u16 *W_p1 = cwp[12], *b_p1 = cwp[13], *Wih0 = cwp[14], *Whh0 = cwp[15];
    const u16 *bih0 = cwp[16], *bhh0 = cwp[17], *h00 = cwp[18], *c00 = cwp[19];
    const u16 *Wih1 = cwp[20], *Whh1 = cwp[21], *bih1 = cwp[22], *bhh1 = cwp[23];
    const u16 *h01 = cwp[24], *c01 = cwp[25], *Wih2 = cwp[26], *Whh2 = cwp[27];
    const u16 *bih2 = cwp[28], *bhh2 = cwp[29], *h02 = cwp[30], *c02 = cwp[31];

    // dtype detect + canonicalize (also zeroes nan ctr, release word, arrive slots)
    las_detect<<<1, 256, 0, stream>>>((const u16*)d_in[8], flag);
    las_convert<<<4096, 256, 0, stream>>>(cv, flag, cw);

    // one-time setup
    las_init<<<256, 256, 0, stream>>>(h00, h01, h02, label, h0f, h1f, h2f, labT);
    las_query<<<2, 256, 0, stream>>>(h02, W_query, b_query, q);
    las_nq<<<2, 256, 0, stream>>>(q, Wq, bq, nq);
    las_wk<<<8, 256, 0, stream>>>(nq, Wk, bk, wk, kb);
    las_attn<<<64, 256, 0, stream>>>(keys, values, input_len, flag, wk, kb, av);
    las_head<<<128, 256, 0, stream>>>(av, Wv, bv, head);
    las_ctx<<<128, 256, 0, stream>>>(head, W_mh, b_mh, ctxT);
    las_embg<<<545, 256, 0, stream>>>(W_emb, Wih0, embg);
    las_ctxg<<<1024, 256, 0, stream>>>(ctxT, Wih0, bih0, bhh0, ctxg);
    las_ctxp1<<<128, 256, 0, stream>>>(ctxT, W_p1, b_p1, ctxp1);

    // full decode: one persistent layer-pipelined MFMA kernel (1 barrier/tick)
    las_decode<<<256, 256, 0, stream>>>(
        embg, ctxg, ctxp1, labT,
        Whh0, Wih1, Whh1, bih1, bhh1,
        Wih2, Whh2, bih2, bhh2,
        W_p1, W_emb, b_proj2,
        c00, c01, c02,
        h0f, h1f, h2f, ybuf,
        flag, d_out);

    int n_out = 64 * 255 * 34;
    las_nanscan<<<(n_out + 255) / 256, 256, 0, stream>>>(d_out, flag, flag + 1, n_out);
    las_nansig<<<1, 64, 0, stream>>>(d_out, flag, flag + 1);
}

// Round 5
// 6545.961 us; speedup vs baseline: 8.7525x; 1.4748x over previous
//
#include <hip/hip_runtime.h>

typedef unsigned short u16;
typedef unsigned int   u32;
typedef float f32x4 __attribute__((ext_vector_type(4)));
typedef short short8 __attribute__((ext_vector_type(8)));

#define SCALE_F 0.08838834764831845f  // 1/sqrt(128)

// ---------- ws layout (float offsets) ----------
#define O_QUERY  0           // 512
#define O_NQ     512         // 512
#define O_WK     1024        // 2048
#define O_KB     3072        // 4  (flag ints at 3080..: [0]=isbf16 [1]=nan [16..271]=arrive,
                             //     [512+32*i] i<8 = release fanout copies)
#define O_FLAG   3080
#define O_AV     4096        // 64*4*512 = 131072
#define O_HEAD   135168      // 64*512  = 32768
#define O_CTXT   167936      // 512*64  = 32768
#define O_EMBG   200704      // 4096*34 = 139264
#define O_CTXG   339968      // 4096*64 = 262144
#define O_CTXP1  602112      // 512*64  = 32768
#define O_H0T    634880      // h0 frag bf16 [2 parity][2 hi/lo][65536] = 131072 floats
#define O_C0T    765952      // y[2][32768] f32 = 65536 floats (repurposed)
#define O_H1T    831488      // h1 frag = 131072 floats
#define O_C1T    962560      // (unused)
#define O_H2T    1028096     // h2 frag [2][2][32768] = 65536 floats
#define O_C2T    1093632     // (unused)
#define O_YT     1126400     // (unused)
#define O_LABT   1159168     // 255*64 ints
#define O_CANON  1175552     // canonical bf16 weights start (u16 ofs = 2*O_CANON)

__device__ __forceinline__ float bfc(u16 x) {
    return __uint_as_float(((u32)x) << 16);
}
__device__ __forceinline__ float2 bfpair(u32 u) {
    return make_float2(__uint_as_float(u << 16), __uint_as_float(u & 0xffff0000u));
}
__device__ __forceinline__ u16 f2bf(float f) {
    u32 u = __float_as_uint(f);
    u += 0x7fffu + ((u >> 16) & 1u);
    return (u16)(u >> 16);
}
__device__ __forceinline__ float sigf(float x) { return 1.0f / (1.0f + __expf(-x)); }
__device__ __forceinline__ float tanh_(float x) { return 2.0f / (1.0f + __expf(-2.0f * x)) - 1.0f; }

__device__ __forceinline__ void fma8(float& acc, uint4 a, const float h[8]) {
    float2 p;
    p = bfpair(a.x); acc = fmaf(h[0], p.x, acc); acc = fmaf(h[1], p.y, acc);
    p = bfpair(a.y); acc = fmaf(h[2], p.x, acc); acc = fmaf(h[3], p.y, acc);
    p = bfpair(a.z); acc = fmaf(h[4], p.x, acc); acc = fmaf(h[5], p.y, acc);
    p = bfpair(a.w); acc = fmaf(h[6], p.x, acc); acc = fmaf(h[7], p.y, acc);
}

__device__ __forceinline__ f32x4 mfma16(short8 a, short8 b, f32x4 c) {
    return __builtin_amdgcn_mfma_f32_16x16x32_bf16(a, b, c, 0, 0, 0);
}
__device__ __forceinline__ short8 ld8g(const u16* p) {
    uint4 v = *(const uint4*)p;
    return __builtin_bit_cast(short8, v);
}
// frag index of element (k,col) in a B-frag-layout h buffer
__device__ __forceinline__ int fidx(int k, int col) {
    return ((k >> 5) * 4 + (col >> 4)) * 512 + (((k >> 2) & 3) * 16 + (col & 15)) * 8 +
           ((k >> 4) & 1) * 4 + (k & 3);
}
// producer store: lane's h value for cell k=4*bx+(l>>4), col=w*16+(l&15); hi+lo split
__device__ __forceinline__ void storeH(u16* buf, int HL, int bx, int w, int l, float v) {
    int idx = ((bx >> 3) * 4 + w) * 512 + ((bx & 3) * 16 + (l & 15)) * 8 +
              ((bx >> 2) & 1) * 4 + (l >> 4);
    u16 hi = f2bf(v);
    buf[idx] = hi;
    buf[idx + HL] = f2bf(v - bfc(hi));
}

// ---------------- dtype detect + canonicalize ----------------

__global__ __launch_bounds__(256) void las_detect(const u16* w, int* flag) {
    __shared__ int s[256];
    int bad = 0;
    for (int i = threadIdx.x; i < 65536; i += 256) {
        u16 v = w[i];
        if ((v & 0x7F80u) == 0x7F80u) bad++;
        else if (fabsf(bfc(v)) > 1e4f) bad++;
    }
    s[threadIdx.x] = bad; __syncthreads();
    for (int o = 128; o; o >>= 1) {
        if (threadIdx.x < o) s[threadIdx.x] += s[threadIdx.x + o];
        __syncthreads();
    }
    flag[16 + threadIdx.x] = 0;                       // arrive slots
    if (threadIdx.x < 8) flag[512 + threadIdx.x * 32] = 0;  // release fanout copies
    if (threadIdx.x == 0) { flag[0] = (s[0] == 0) ? 1 : 0; flag[1] = 0; }
}

#define NSEG 32
struct Cvt {
    const void* src[NSEG];
    unsigned ofs[NSEG + 1];
    unsigned len[NSEG];
};

__global__ __launch_bounds__(256) void las_convert(Cvt c, const int* flag, u16* dst) {
    int isb = flag[0];
    unsigned total = c.ofs[NSEG] >> 1;
    for (unsigned p = blockIdx.x * 256 + threadIdx.x; p < total; p += gridDim.x * 256) {
        unsigned e = p << 1;
        int lo = 0, hi = NSEG;
        while (hi - lo > 1) { int mid = (lo + hi) >> 1; if (c.ofs[mid] <= e) lo = mid; else hi = mid; }
        unsigned local = e - c.ofs[lo];
        u32 out;
        if (local >= c.len[lo]) {
            out = 0;
        } else if (isb) {
            out = ((const u32*)c.src[lo])[local >> 1];
        } else {
            const float* s = (const float*)c.src[lo];
            u32 a = f2bf(s[local]), b = f2bf(s[local + 1]);
            out = a | (b << 16);
        }
        ((u32*)dst)[p] = out;
    }
}

// ---------------- one-time kernels ----------------

// initial states go to PARITY 1 (tick 0 reads parity 1 for all three h buffers)
__global__ __launch_bounds__(256) void las_init(
    const u16* h00, const u16* h01, const u16* h02, const int* label,
    u16* h0f, u16* h1f, u16* h2f, int* labT) {
    int idx = blockIdx.x * 256 + threadIdx.x;   // 65536 threads
    int k = idx >> 6, col = idx & 63;
    int fi = fidx(k, col);
    h0f[131072 + fi] = h00[k]; h0f[131072 + 65536 + fi] = 0;
    h1f[131072 + fi] = h01[k]; h1f[131072 + 65536 + fi] = 0;
    if (k < 512) { h2f[65536 + fi] = h02[k]; h2f[65536 + 32768 + fi] = 0; }
    if (k < 255) labT[idx] = label[col * 256 + k];
}

__global__ __launch_bounds__(256) void las_query(const u16* h02, const u16* W_query,
                                                 const u16* b_query, float* query) {
    int i = blockIdx.x * 256 + threadIdx.x;     // < 512
    float acc = bfc(b_query[i]);
    const u32* wr = (const u32*)(W_query + (size_t)i * 512);
    const u32* hp = (const u32*)h02;
    for (int h = 0; h < 512; h += 8) {
        uint4 wv = *(const uint4*)(wr + (h >> 1));
        uint4 hv = *(const uint4*)(hp + (h >> 1));
        float2 a, c;
        a = bfpair(wv.x); c = bfpair(hv.x); acc = fmaf(a.x, c.x, acc); acc = fmaf(a.y, c.y, acc);
        a = bfpair(wv.y); c = bfpair(hv.y); acc = fmaf(a.x, c.x, acc); acc = fmaf(a.y, c.y, acc);
        a = bfpair(wv.z); c = bfpair(hv.z); acc = fmaf(a.x, c.x, acc); acc = fmaf(a.y, c.y, acc);
        a = bfpair(wv.w); c = bfpair(hv.w); acc = fmaf(a.x, c.x, acc); acc = fmaf(a.y, c.y, acc);
    }
    query[i] = acc;
}

__global__ __launch_bounds__(256) void las_nq(const float* query, const u16* Wq,
                                              const u16* bq, float* nq) {
    int nd = blockIdx.x * 256 + threadIdx.x;    // < 512
    float acc = bfc(bq[nd]);
    const u32* wr = (const u32*)(Wq + (size_t)nd * 512);
    for (int h = 0; h < 512; h += 8) {
        uint4 wv = *(const uint4*)(wr + (h >> 1));
        float2 p;
        p = bfpair(wv.x); acc = fmaf(p.x, query[h + 0], acc); acc = fmaf(p.y, query[h + 1], acc);
        p = bfpair(wv.y); acc = fmaf(p.x, query[h + 2], acc); acc = fmaf(p.y, query[h + 3], acc);
        p = bfpair(wv.z); acc = fmaf(p.x, query[h + 4], acc); acc = fmaf(p.y, query[h + 5], acc);
        p = bfpair(wv.w); acc = fmaf(p.x, query[h + 6], acc); acc = fmaf(p.y, query[h + 7], acc);
    }
    nq[nd] = acc;
}

__global__ __launch_bounds__(256) void las_wk(const float* nq, const u16* Wk, const u16* bk,
                                              float* wk, float* kb) {
    int idx = blockIdx.x * 256 + threadIdx.x;   // < 2048
    int n = idx >> 9, h = idx & 511;
    float acc = 0.0f;
    for (int d = 0; d < 128; d++)
        acc = fmaf(nq[n * 128 + d], bfc(Wk[((size_t)(n * 128 + d)) * 512 + h]), acc);
    wk[idx] = acc;
    if (idx < 4) {
        float kk = 0.0f;
        for (int d = 0; d < 128; d++) kk = fmaf(nq[idx * 128 + d], bfc(bk[idx * 128 + d]), kk);
        kb[idx] = kk;
    }
}

__global__ __launch_bounds__(256) void las_attn(const void* keysv, const void* valuesv,
                                                const int* input_len, const int* flag,
                                                const float* wk, const float* kb, float* av) {
    __shared__ float wk_s[2048];
    __shared__ float kb_s[4];
    __shared__ float sm[4][1024];
    __shared__ float red[256];
    __shared__ float stat[4];
    const u16* keysB = (const u16*)keysv;
    const float* keysF = (const float*)keysv;
    const u16* valB = (const u16*)valuesv;
    const float* valF = (const float*)valuesv;
    int b = blockIdx.x;
    int tid = threadIdx.x;
    int isb = flag[0];
    for (int i = tid; i < 2048; i += 256) wk_s[i] = wk[i];
    if (tid < 4) kb_s[tid] = kb[tid];
    __syncthreads();
    int len = input_len[b];

    {
        float acc[4][4];
#pragma unroll
        for (int tl = 0; tl < 4; tl++)
#pragma unroll
            for (int n = 0; n < 4; n++) acc[tl][n] = kb_s[n];
        for (int h = 0; h < 512; h += 8) {
            float kf[4][8];
#pragma unroll
            for (int tl = 0; tl < 4; tl++) {
                int t = tid + 256 * tl;
                size_t base = ((size_t)t * 64 + b) * 512 + h;
                if (isb) {
                    uint4 kv = *(const uint4*)(keysB + base);
                    float2 p;
                    p = bfpair(kv.x); kf[tl][0] = p.x; kf[tl][1] = p.y;
                    p = bfpair(kv.y); kf[tl][2] = p.x; kf[tl][3] = p.y;
                    p = bfpair(kv.z); kf[tl][4] = p.x; kf[tl][5] = p.y;
                    p = bfpair(kv.w); kf[tl][6] = p.x; kf[tl][7] = p.y;
                } else {
                    const float4* kp = (const float4*)(keysF + base);
                    float4 q0 = kp[0], q1 = kp[1];
                    kf[tl][0] = q0.x; kf[tl][1] = q0.y; kf[tl][2] = q0.z; kf[tl][3] = q0.w;
                    kf[tl][4] = q1.x; kf[tl][5] = q1.y; kf[tl][6] = q1.z; kf[tl][7] = q1.w;
                }
            }
#pragma unroll
            for (int i = 0; i < 8; i++) {
                float w0 = wk_s[h + i], w1 = wk_s[512 + h + i];
                float w2 = wk_s[1024 + h + i], w3 = wk_s[1536 + h + i];
#pragma unroll
                for (int tl = 0; tl < 4; tl++) {
                    acc[tl][0] = fmaf(kf[tl][i], w0, acc[tl][0]);
                    acc[tl][1] = fmaf(kf[tl][i], w1, acc[tl][1]);
                    acc[tl][2] = fmaf(kf[tl][i], w2, acc[tl][2]);
                    acc[tl][3] = fmaf(kf[tl][i], w3, acc[tl][3]);
                }
            }
        }
#pragma unroll
        for (int tl = 0; tl < 4; tl++) {
            int t = tid + 256 * tl;
#pragma unroll
            for (int n = 0; n < 4; n++)
                sm[n][t] = (t < len) ? acc[tl][n] * SCALE_F : -1e30f;
        }
    }
    __syncthreads();

    for (int n = 0; n < 4; n++) {
        float m = -1e30f;
        for (int tl = 0; tl < 4; tl++) m = fmaxf(m, sm[n][tid + 256 * tl]);
        red[tid] = m; __syncthreads();
        for (int off = 128; off; off >>= 1) {
            if (tid < off) red[tid] = fmaxf(red[tid], red[tid + off]);
            __syncthreads();
        }
        m = red[0]; __syncthreads();
        float e = 0.0f;
        for (int tl = 0; tl < 4; tl++) {
            int t = tid + 256 * tl;
            float x = (t < len) ? __expf(sm[n][t] - m) : 0.0f;
            sm[n][t] = x; e += x;
        }
        red[tid] = e; __syncthreads();
        for (int off = 128; off; off >>= 1) {
            if (tid < off) red[tid] += red[tid + off];
            __syncthreads();
        }
        if (tid == 0) stat[n] = 1.0f / red[0];
        __syncthreads();
    }

    {
        float a[4][2] = {};
        int h0 = 2 * tid;
        for (int t = 0; t < len; t++) {
            size_t base = ((size_t)t * 64 + b) * 512 + h0;
            float2 p;
            if (isb) p = bfpair(*(const u32*)(valB + base));
            else     p = *(const float2*)(valF + base);
            float s0 = sm[0][t], s1 = sm[1][t], s2 = sm[2][t], s3 = sm[3][t];
            a[0][0] = fmaf(s0, p.x, a[0][0]); a[0][1] = fmaf(s0, p.y, a[0][1]);
            a[1][0] = fmaf(s1, p.x, a[1][0]); a[1][1] = fmaf(s1, p.y, a[1][1]);
            a[2][0] = fmaf(s2, p.x, a[2][0]); a[2][1] = fmaf(s2, p.y, a[2][1]);
            a[3][0] = fmaf(s3, p.x, a[3][0]); a[3][1] = fmaf(s3, p.y, a[3][1]);
        }
#pragma unroll
        for (int n = 0; n < 4; n++) {
            av[((size_t)b * 4 + n) * 512 + h0]     = a[n][0] * stat[n];
            av[((size_t)b * 4 + n) * 512 + h0 + 1] = a[n][1] * stat[n];
        }
    }
}

__global__ __launch_bounds__(256) void las_head(const float* av, const u16* Wv, const u16* bv,
                                                float* head) {
    int idx = blockIdx.x * 256 + threadIdx.x;   // < 32768
    int b = idx >> 9, nd = idx & 511, n = nd >> 7;
    float acc = bfc(bv[nd]);
    const u32* wr = (const u32*)(Wv + (size_t)nd * 512);
    const float* ap = av + ((size_t)b * 4 + n) * 512;
    for (int h = 0; h < 512; h += 8) {
        uint4 wv = *(const uint4*)(wr + (h >> 1));
        float2 p;
        p = bfpair(wv.x); acc = fmaf(p.x, ap[h + 0], acc); acc = fmaf(p.y, ap[h + 1], acc);
        p = bfpair(wv.y); acc = fmaf(p.x, ap[h + 2], acc); acc = fmaf(p.y, ap[h + 3], acc);
        p = bfpair(wv.z); acc = fmaf(p.x, ap[h + 4], acc); acc = fmaf(p.y, ap[h + 5], acc);
        p = bfpair(wv.w); acc = fmaf(p.x, ap[h + 6], acc); acc = fmaf(p.y, ap[h + 7], acc);
    }
    head[idx] = acc;
}

__global__ __launch_bounds__(256) void las_ctx(const float* head, const u16* W_mh, const u16* b_mh,
                                               float* ctxT) {
    int idx = blockIdx.x * 256 + threadIdx.x;   // < 32768
    int b = idx >> 9, i = idx & 511;
    float acc = bfc(b_mh[i]);
    const u32* wr = (const u32*)(W_mh + (size_t)i * 512);
    const float* hp = head + (size_t)b * 512;
    for (int h = 0; h < 512; h += 8) {
        uint4 wv = *(const uint4*)(wr + (h >> 1));
        float2 p;
        p = bfpair(wv.x); acc = fmaf(p.x, hp[h + 0], acc); acc = fmaf(p.y, hp[h + 1], acc);
        p = bfpair(wv.y); acc = fmaf(p.x, hp[h + 2], acc); acc = fmaf(p.y, hp[h + 3], acc);
        p = bfpair(wv.z); acc = fmaf(p.x, hp[h + 4], acc); acc = fmaf(p.y, hp[h + 5], acc);
        p = bfpair(wv.w); acc = fmaf(p.x, hp[h + 6], acc); acc = fmaf(p.y, hp[h + 7], acc);
    }
    ctxT[(size_t)i * 64 + b] = acc;
}

__global__ __launch_bounds__(256) void las_embg(const u16* W_emb, const u16* Wih0, float* embg) {
    int idx = blockIdx.x * 256 + threadIdx.x;
    if (idx >= 4096 * 34) return;
    int row = idx / 34, v = idx - row * 34;
    const u32* wr = (const u32*)(Wih0 + (size_t)row * 1024);
    const u32* er = (const u32*)(W_emb + (size_t)v * 512);
    float acc = 0.0f;
    for (int h = 0; h < 512; h += 8) {
        uint4 wv = *(const uint4*)(wr + (h >> 1));
        uint4 ev = *(const uint4*)(er + (h >> 1));
        float2 a, c;
        a = bfpair(wv.x); c = bfpair(ev.x); acc = fmaf(a.x, c.x, acc); acc = fmaf(a.y, c.y, acc);
        a = bfpair(wv.y); c = bfpair(ev.y); acc = fmaf(a.x, c.x, acc); acc = fmaf(a.y, c.y, acc);
        a = bfpair(wv.z); c = bfpair(ev.z); acc = fmaf(a.x, c.x, acc); acc = fmaf(a.y, c.y, acc);
        a = bfpair(wv.w); c = bfpair(ev.w); acc = fmaf(a.x, c.x, acc); acc = fmaf(a.y, c.y, acc);
    }
    embg[idx] = acc;
}

__global__ __launch_bounds__(256) void las_ctxg(const float* ctxT, const u16* Wih0,
                                                const u16* bih0, const u16* bhh0, float* ctxg) {
    int lane = threadIdx.x & 63, w = threadIdx.x >> 6;
    int row = blockIdx.x * 4 + w;               // < 4096
    float acc = bfc(bih0[row]) + bfc(bhh0[row]);
    const u32* wr = (const u32*)(Wih0 + (size_t)row * 1024 + 512);
    for (int h = 0; h < 512; h += 8) {
        float hv[8];
#pragma unroll
        for (int i = 0; i < 8; i++) hv[i] = ctxT[(size_t)(h + i) * 64 + lane];
        uint4 wv = *(const uint4*)(wr + (h >> 1));
        fma8(acc, wv, hv);
    }
    ctxg[(size_t)row * 64 + lane] = acc;
}

__global__ __launch_bounds__(256) void las_ctxp1(const float* ctxT, const u16* W_p1,
                                                 const u16* b_p1, float* ctxp1) {
    int lane = threadIdx.x & 63, w = threadIdx.x >> 6;
    int i = blockIdx.x * 4 + w;                 // < 512
    float acc = bfc(b_p1[i]);
    const u32* wr = (const u32*)(W_p1 + (size_t)i * 1024 + 512);
    for (int h = 0; h < 512; h += 8) {
        float hv[8];
#pragma unroll
        for (int k = 0; k < 8; k++) hv[k] = ctxT[(size_t)(h + k) * 64 + lane];
        uint4 wv = *(const uint4*)(wr + (h >> 1));
        fma8(acc, wv, hv);
    }
    ctxp1[(size_t)i * 64 + lane] = acc;
}

// ---------------- persistent MFMA decode kernel (layer-pipelined, 8-wave k-split) ----
// 512 threads: waves 0-3 = columns x k-half 0; waves 4-7 = same columns x k-half 1.
// Each wave sweeps half the k-tiles; partials combined via LDS reduce (scratch buf).
// At tick tau: l0(tau), l1(tau-1), l2(tau-2) [bx<128], p3a(tau-3) [128..159],
// p3b(tau-4) [160..223]. ONE grid barrier per tick. Barrier: store-arrive slots +
// aggregator (block 255) + 8-way fanned-out release words; release-only fence at
// arrive, acquire-only fence at depart (one wbL2 + one inv per tick, not two each).
// LDS total = 156672 B (< R1's proven 157696).

__device__ __forceinline__ void gridbar(int* arr, int* relv, int epoch) {
    __syncthreads();                              // all waves' stores vmcnt-drained
    const int bx = blockIdx.x;
    if (threadIdx.x == 0) {
        __builtin_amdgcn_fence(__ATOMIC_RELEASE, "agent");   // wbL2: publish to LLC
        __hip_atomic_store(&arr[bx], epoch, __ATOMIC_RELAXED, __HIP_MEMORY_SCOPE_AGENT);
    }
    if (bx == 255 && threadIdx.x < 64) {          // aggregator wave
        int iters = 0;
        for (;;) {
            int ok = 1;
#pragma unroll
            for (int q = 0; q < 4; q++) {
                int v = __hip_atomic_load(&arr[threadIdx.x * 4 + q],
                                          __ATOMIC_RELAXED, __HIP_MEMORY_SCOPE_AGENT);
                ok &= (v >= epoch);
            }
            if (__all(ok)) break;
            if (++iters > (1 << 20)) break;       // bounded: corrupts instead of hanging
            __builtin_amdgcn_s_sleep(1);
        }
        if (threadIdx.x < 8)                      // fan release out to 8 lines
            __hip_atomic_store(&relv[threadIdx.x * 32], epoch,
                               __ATOMIC_RELAXED, __HIP_MEMORY_SCOPE_AGENT);
    }
    if (threadIdx.x == 0) {
        int* myrel = relv + (blockIdx.x >> 5) * 32;   // 32 blocks per release line
        int iters = 0;
        while (__hip_atomic_load(myrel, __ATOMIC_RELAXED, __HIP_MEMORY_SCOPE_AGENT) < epoch) {
            __builtin_amdgcn_s_sleep(2);
            if (++iters > (1 << 20)) break;
        }
        __builtin_amdgcn_fence(__ATOMIC_ACQUIRE, "agent");   // inv L1+L2
    }
    __syncthreads();
}

__global__ __launch_bounds__(512, 1) void las_decode(
    const float* embg, const float* ctxg, const float* ctxp1, const int* labT,
    const u16* Whh0, const u16* Wih1, const u16* Whh1,
    const u16* bih1, const u16* bhh1,
    const u16* Wih2, const u16* Whh2, const u16* bih2, const u16* bhh2,
    const u16* W_p1, const u16* W_emb, const u16* b_proj2,
    const u16* c00, const u16* c01, const u16* c02,
    u16* h0f, u16* h1f, u16* h2f, float* ybuf,
    int* flag, void* outp) {

    __shared__ __align__(16) u16 A0[32 * 64 * 8];   // 32 KB  Whh0 A-frags
    __shared__ __align__(16) u16 A1[64 * 64 * 8];   // 64 KB  Wih1|Whh1 A-frags
    __shared__ __align__(16) u16 A2[48 * 64 * 8];   // 48 KB  Wih2|Whh2 (bx<128) or W_p1 (128..159)
    // union: k-split reduce pad-9 layout (4*64*9 = 2304 floats) OR p3b ylds[512].
    // Disjoint phases within a tick (reduce8 completes+syncs before epilogues).
    __shared__ float scratch[2304];                 //  9 KB

    const int tid = threadIdx.x, l = tid & 63, w = tid >> 6;   // w 0..7
    const int cw = w & 3;                            // column-wave (16 cols each)
    const int kh = w >> 2;                           // k-half
    const int bx = blockIdx.x;
    const int isb = flag[0];
    int* arr  = flag + 16;
    int* relv = flag + 512;
    const int HL0 = 65536, HL2 = 32768;
    const int rot16 = bx & 15, rot8 = bx & 7;        // de-phase LLC traffic across blocks

    // ---- stage A-fragments once ----
    for (int i = tid; i < 32 * 64 * 2; i += 512) {
        int kt = i >> 7, ll = (i >> 1) & 63, half = i & 1;
        int r = ll & 15;
        int row = (r & 3) * 1024 + 4 * bx + (r >> 2);
        int kc = kt * 32 + half * 16 + 4 * (ll >> 4);
        *(uint2*)&A0[(kt * 64 + ll) * 8 + half * 4] = *(const uint2*)(Whh0 + (size_t)row * 1024 + kc);
    }
    for (int i = tid; i < 64 * 64 * 2; i += 512) {
        int kt = i >> 7, ll = (i >> 1) & 63, half = i & 1;
        int r = ll & 15;
        int row = (r & 3) * 1024 + 4 * bx + (r >> 2);
        int kc = kt * 32 + half * 16 + 4 * (ll >> 4);
        const u16* src = (kc < 1024) ? (Wih1 + (size_t)row * 1024 + kc)
                                     : (Whh1 + (size_t)row * 1024 + (kc - 1024));
        *(uint2*)&A1[(kt * 64 + ll) * 8 + half * 4] = *(const uint2*)src;
    }
    if (bx < 128) {
        for (int i = tid; i < 48 * 64 * 2; i += 512) {
            int kt = i >> 7, ll = (i >> 1) & 63, half = i & 1;
            int r = ll & 15;
            int row = (r & 3) * 512 + 4 * bx + (r >> 2);
            int kc = kt * 32 + half * 16 + 4 * (ll >> 4);
            const u16* src = (kc < 1024) ? (Wih2 + (size_t)row * 1024 + kc)
                                         : (Whh2 + (size_t)row * 512 + (kc - 1024));
            *(uint2*)&A2[(kt * 64 + ll) * 8 + half * 4] = *(const uint2*)src;
        }
    } else if (bx < 160) {
        int mt = bx - 128;
        for (int i = tid; i < 16 * 64 * 2; i += 512) {
            int kt = i >> 7, ll = (i >> 1) & 63, half = i & 1;
            int row = 16 * mt + (ll & 15);
            int kc = kt * 32 + half * 16 + 4 * (ll >> 4);
            *(uint2*)&A2[(kt * 64 + ll) * 8 + half * 4] = *(const uint2*)(W_p1 + (size_t)row * 1024 + kc);
        }
    }

    // ---- persistent per-lane state (meaningful on waves 0-3) ----
    const int cell01 = 4 * bx + (l >> 4);
    const int bcol = cw * 16 + (l & 15);
    float c0reg = bfc(c00[cell01]);
    float c1reg = bfc(c01[cell01]);
    float pre0c[4], pre1c[4], pre2c[4], prep3[4];
#pragma unroll
    for (int r = 0; r < 4; r++) {
        int row = r * 1024 + cell01;
        pre0c[r] = ctxg[(size_t)row * 64 + bcol];
        pre1c[r] = bfc(bih1[row]) + bfc(bhh1[row]);
        pre2c[r] = 0.0f; prep3[r] = 0.0f;
    }
    float c2reg = 0.0f;
    if (bx < 128) {
        int cell2 = 4 * bx + (l >> 4);
        c2reg = bfc(c02[cell2]);
#pragma unroll
        for (int r = 0; r < 4; r++) {
            int row = r * 512 + cell2;
            pre2c[r] = bfc(bih2[row]) + bfc(bhh2[row]);
        }
    } else if (bx < 160) {
#pragma unroll
        for (int r = 0; r < 4; r++) {
            int yi = 16 * (bx - 128) + 4 * (l >> 4) + r;
            prep3[r] = ctxp1[(size_t)yi * 64 + bcol];
        }
    }

    // cross-wave k-split reduce: upper waves publish, lower waves accumulate
    auto reduce8 = [&](f32x4& xh, f32x4& xl) {
        __syncthreads();
        if (w >= 4) {
            float* r = &scratch[((w - 4) * 64 + l) * 9];
#pragma unroll
            for (int i = 0; i < 4; i++) { r[i] = xh[i]; r[4 + i] = xl[i]; }
        }
        __syncthreads();
        if (w < 4) {
            const float* r = &scratch[(w * 64 + l) * 9];
#pragma unroll
            for (int i = 0; i < 4; i++) { xh[i] += r[i]; xl[i] += r[4 + i]; }
        }
        __syncthreads();                          // buffer reuse guard
    };

    __syncthreads();

    for (int tau = 0; tau < 259; tau++) {
        const bool do0 = (tau < 255);
        const bool do1 = (tau >= 1) && (tau <= 255);
        const bool do2 = (tau >= 2) && (tau <= 256) && (bx < 128);
        const bool do3 = (tau >= 3) && (tau <= 257) && (bx >= 128) && (bx < 160);
        const bool do4 = (tau >= 4) && (bx >= 160) && (bx < 224);

        // parity map: h_X(t) is stored at parity t&1; initial states at parity 1
        const u16* h0r = h0f + ((tau + 1) & 1) * 131072;   // h0(tau-1)
        u16*       h0w = h0f + (tau & 1) * 131072;         // h0(tau)
        const u16* h1r = h1f + (tau & 1) * 131072;         // h1(tau-2)
        u16*       h1w = h1f + ((tau + 1) & 1) * 131072;   // h1(tau-1)
        const u16* h2r = h2f + ((tau + 1) & 1) * 65536;    // h2(tau-3)
        u16*       h2w = h2f + (tau & 1) * 65536;          // h2(tau-2)
        float*     yw  = ybuf + ((tau + 1) & 1) * 32768;   // y(tau-3)
        const float* yr = ybuf + (tau & 1) * 32768;        // y(tau-4)

        // early issue: l0 gather chain (labT -> embg) hides under the sweeps
        int vb = 0; float e0 = 0.f, e1 = 0.f, e2 = 0.f, e3 = 0.f;
        if (do0 && w < 4) {
            vb = labT[tau * 64 + bcol];
            e0 = embg[(size_t)(0 * 1024 + cell01) * 34 + vb];
            e1 = embg[(size_t)(1 * 1024 + cell01) * 34 + vb];
            e2 = embg[(size_t)(2 * 1024 + cell01) * 34 + vb];
            e3 = embg[(size_t)(3 * 1024 + cell01) * 34 + vb];
        }

        f32x4 a0h = {0.f,0.f,0.f,0.f}, a0l = {0.f,0.f,0.f,0.f};
        f32x4 a1h = {0.f,0.f,0.f,0.f}, a1l = {0.f,0.f,0.f,0.f};
        f32x4 a2h = {0.f,0.f,0.f,0.f}, a2l = {0.f,0.f,0.f,0.f};

        // ---- h0(tau-1) half-sweep: feeds l0 (A0) and l1-x (A1[0..31]) ----
#pragma unroll 8
        for (int i = 0; i < 16; i++) {
            int kt = kh * 16 + ((i + rot16) & 15);
            const u16* bp = h0r + (kt * 4 + cw) * 512 + l * 8;
            short8 bh = ld8g(bp), bl = ld8g(bp + HL0);
            short8 aA = *(const short8*)&A0[(kt * 64 + l) * 8];
            short8 aB = *(const short8*)&A1[(kt * 64 + l) * 8];
            a0h = mfma16(aA, bh, a0h); a0l = mfma16(aA, bl, a0l);
            a1h = mfma16(aB, bh, a1h); a1l = mfma16(aB, bl, a1l);
        }
        if (bx < 128) {
            // ---- h1(tau-2) half-sweep: l1-h (A1[32..63]) + l2-x (A2[0..31]) ----
#pragma unroll 8
            for (int i = 0; i < 16; i++) {
                int kt = kh * 16 + ((i + rot16) & 15);
                const u16* bp = h1r + (kt * 4 + cw) * 512 + l * 8;
                short8 bh = ld8g(bp), bl = ld8g(bp + HL0);
                short8 aB = *(const short8*)&A1[((32 + kt) * 64 + l) * 8];
                short8 aC = *(const short8*)&A2[(kt * 64 + l) * 8];
                a1h = mfma16(aB, bh, a1h); a1l = mfma16(aB, bl, a1l);
                a2h = mfma16(aC, bh, a2h); a2l = mfma16(aC, bl, a2l);
            }
            // ---- h2(tau-3) half-sweep: l2-h (A2[32..47]) ----
#pragma unroll 8
            for (int i = 0; i < 8; i++) {
                int kt = kh * 8 + ((i + rot8) & 7);
                const u16* bp = h2r + (kt * 4 + cw) * 512 + l * 8;
                short8 bh = ld8g(bp), bl = ld8g(bp + HL2);
                short8 aC = *(const short8*)&A2[((32 + kt) * 64 + l) * 8];
                a2h = mfma16(aC, bh, a2h); a2l = mfma16(aC, bl, a2l);
            }
        } else {
#pragma unroll 8
            for (int i = 0; i < 16; i++) {
                int kt = kh * 16 + ((i + rot16) & 15);
                const u16* bp = h1r + (kt * 4 + cw) * 512 + l * 8;
                short8 bh = ld8g(bp), bl = ld8g(bp + HL0);
                short8 aB = *(const short8*)&A1[((32 + kt) * 64 + l) * 8];
                a1h = mfma16(aB, bh, a1h); a1l = mfma16(aB, bl, a1l);
            }
            if (bx < 160) {
                // p3a: h2(tau-3) half-sweep with W_p1 frags (A2[0..15])
#pragma unroll 8
                for (int i = 0; i < 8; i++) {
                    int kt = kh * 8 + ((i + rot8) & 7);
                    const u16* bp = h2r + (kt * 4 + cw) * 512 + l * 8;
                    short8 bh = ld8g(bp), bl = ld8g(bp + HL2);
                    short8 aC = *(const short8*)&A2[(kt * 64 + l) * 8];
                    a2h = mfma16(aC, bh, a2h); a2l = mfma16(aC, bl, a2l);
                }
            }
        }

        // ---- combine k-halves ----
        reduce8(a0h, a0l);
        reduce8(a1h, a1l);
        if (bx < 160) reduce8(a2h, a2l);

        // ---- epilogues (waves 0-3 hold the reduced sums) ----
        if (do0 && w < 4) {                           // l0(tau)
            float g0 = a0h[0] + a0l[0] + pre0c[0] + e0;
            float g1 = a0h[1] + a0l[1] + pre0c[1] + e1;
            float g2 = a0h[2] + a0l[2] + pre0c[2] + e2;
            float g3 = a0h[3] + a0l[3] + pre0c[3] + e3;
            float c2 = fmaf(sigf(g1), c0reg, sigf(g0) * tanh_(g2));
            c0reg = c2;
            storeH(h0w, HL0, bx, w, l, sigf(g3) * tanh_(c2));
        }
        if (do1 && w < 4) {                           // l1(tau-1)
            float g0 = a1h[0] + a1l[0] + pre1c[0];
            float g1 = a1h[1] + a1l[1] + pre1c[1];
            float g2 = a1h[2] + a1l[2] + pre1c[2];
            float g3 = a1h[3] + a1l[3] + pre1c[3];
            float c2 = fmaf(sigf(g1), c1reg, sigf(g0) * tanh_(g2));
            c1reg = c2;
            storeH(h1w, HL0, bx, w, l, sigf(g3) * tanh_(c2));
        }
        if (do2 && w < 4) {                           // l2(tau-2)
            float g0 = a2h[0] + a2l[0] + pre2c[0];
            float g1 = a2h[1] + a2l[1] + pre2c[1];
            float g2 = a2h[2] + a2l[2] + pre2c[2];
            float g3 = a2h[3] + a2l[3] + pre2c[3];
            float c2 = fmaf(sigf(g1), c2reg, sigf(g0) * tanh_(g2));
            c2reg = c2;
            storeH(h2w, HL2, bx, w, l, sigf(g3) * tanh_(c2));
        }
        if (do3 && w < 4) {                           // p3a(tau-3)
#pragma unroll
            for (int r = 0; r < 4; r++) {
                float v = a2h[r] + a2l[r] + prep3[r];
                v = v > 0.0f ? v : 0.01f * v;         // leaky_relu
                yw[(size_t)(16 * (bx - 128) + 4 * (l >> 4) + r) * 64 + bcol] = v;
            }
        }
        if (do4) {                                    // p3b(tau-4)
            int b = bx - 160;
            scratch[tid] = yr[(size_t)tid * 64 + b];  // ylds: 512 threads, one each
            __syncthreads();
            if (w == 0) {
                int v = l;
                float acc = -1e30f;
                if (v < 34) {
                    acc = bfc(b_proj2[v]);
                    const u32* wr = (const u32*)(W_emb + (size_t)v * 512);
                    for (int k2 = 0; k2 < 512; k2 += 8) {
                        uint4 wv = *(const uint4*)(wr + (k2 >> 1));
                        float2 p;
                        p = bfpair(wv.x); acc = fmaf(p.x, scratch[k2 + 0], acc); acc = fmaf(p.y, scratch[k2 + 1], acc);
                        p = bfpair(wv.y); acc = fmaf(p.x, scratch[k2 + 2], acc); acc = fmaf(p.y, scratch[k2 + 3], acc);
                        p = bfpair(wv.z); acc = fmaf(p.x, scratch[k2 + 4], acc); acc = fmaf(p.y, scratch[k2 + 5], acc);
                        p = bfpair(wv.w); acc = fmaf(p.x, scratch[k2 + 6], acc); acc = fmaf(p.y, scratch[k2 + 7], acc);
                    }
                }
                float m = acc;
                for (int off = 32; off; off >>= 1) m = fmaxf(m, __shfl_xor(m, off, 64));
                float e = (v < 34) ? __expf(acc - m) : 0.0f;
                float s = e;
                for (int off = 32; off; off >>= 1) s += __shfl_xor(s, off, 64);
                if (v < 34) {
                    float rr = acc - m - __logf(s);
                    size_t o = ((size_t)b * 255 + (tau - 4)) * 34 + v;
                    if (isb) ((u16*)outp)[o] = f2bf(rr);
                    else     ((float*)outp)[o] = rr;
                }
            }
            __syncthreads();                          // scratch reused as red next tick
        }

        gridbar(arr, relv, tau + 1);
    }
}

// ---------------- failure instrumentation ----------------

__global__ __launch_bounds__(256) void las_nanscan(const void* outp, const int* flag, int* cnt, int n) {
    int g = blockIdx.x * 256 + threadIdx.x;
    if (g >= n) return;
    bool bad;
    if (flag[0]) {
        u16 v = ((const u16*)outp)[g];
        bad = ((v & 0x7F80u) == 0x7F80u);
    } else {
        float f = ((const float*)outp)[g];
        bad = !isfinite(f);
    }
    if (bad) atomicAdd(cnt, 1);
}

__global__ __launch_bounds__(64) void las_nansig(void* outp, const int* flag, const int* cnt) {
    if (threadIdx.x != 0) return;
    int c = cnt[0];
    if (c > 0) {
        int cc = c < 9999 ? c : 9999;
        float sig = 10000.0f * (float)(1 + flag[0]) + (float)cc;
        if (flag[0]) ((u16*)outp)[0] = f2bf(sig);
        else         ((float*)outp)[0] = sig;
    }
}

// ---------------- host ----------------

extern "C" void kernel_launch(void* const* d_in, const int* in_sizes, int n_in,
                              void* d_out, int out_size, void* d_ws, size_t ws_size,
                              hipStream_t stream) {
    const void* keys     = d_in[0];
    const void* values   = d_in[1];
    const int* label     = (const int*)d_in[2];
    const int* input_len = (const int*)d_in[4];

    float* F     = (float*)d_ws;
    float* q     = F + O_QUERY;
    float* nq    = F + O_NQ;
    float* wk    = F + O_WK;
    float* kb    = F + O_KB;
    int*   flag  = (int*)(F + O_FLAG);
    float* av    = F + O_AV;
    float* head  = F + O_HEAD;
    float* ctxT  = F + O_CTXT;
    float* embg  = F + O_EMBG;
    float* ctxg  = F + O_CTXG;
    float* ctxp1 = F + O_CTXP1;
    float* ybuf  = F + O_C0T;                   // y[2][32768] f32
    int*   labT  = (int*)(F + O_LABT);
    u16*   h0f   = (u16*)(F + O_H0T);           // [2 parity][2 hi/lo][65536] bf16 frag
    u16*   h1f   = (u16*)(F + O_H1T);
    u16*   h2f   = (u16*)(F + O_H2T);           // [2][2][32768]
    u16*   cw    = (u16*)d_ws + 2 * (size_t)O_CANON;

    static const unsigned kLen[NSEG] = {
        17408, 34, 262144, 512, 262144, 512, 262144, 512, 262144, 512,
        262144, 512, 524288, 512, 4194304, 4194304, 4096, 4096, 1024, 1024,
        4194304, 4194304, 4096, 4096, 1024, 1024, 2097152, 1048576, 2048, 2048,
        512, 512
    };
    Cvt cv;
    const u16* cwp[NSEG];
    unsigned o = 0;
    for (int i = 0; i < NSEG; i++) {
        cv.src[i] = d_in[6 + i];
        cv.ofs[i] = o;
        cv.len[i] = kLen[i];
        cwp[i] = cw + o;
        o += (kLen[i] + 7u) & ~7u;
    }
    cv.ofs[NSEG] = o;

    const u16 *W_emb = cwp[0], *b_proj2 = cwp[1], *W_query = cwp[2], *b_query = cwp[3];
    const u16 *Wk = cwp[4], *bk = cwp[5], *Wq = cwp[6], *bq = cwp[7];
    const u16 *Wv = cwp[8], *bv = cwp[9], *W_mh = cwp[10], *b_mh = cwp[11];
    const u16 *W_p1 = cwp[12], *b_p1 = cwp[13], *Wih0 = cwp[14], *Whh0 = cwp[15];
    const u16 *bih0 = cwp[16], *bhh0 = cwp[17], *h00 = cwp[18], *c00 = cwp[19];
    const u16 *Wih1 = cwp[20], *Whh1 = cwp[21], *bih1 = cwp[22], *bhh1 = cwp[23];
    const u16 *h01 = cwp[24], *c01 = cwp[25], *Wih2 = cwp[26], *Whh2 = cwp[27];
    const u16 *bih2 = cwp[28], *bhh2 = cwp[29], *h02 = cwp[30], *c02 = cwp[31];

    // dtype detect + canonicalize (also zeroes nan ctr, release words, arrive slots)
    las_detect<<<1, 256, 0, stream>>>((const u16*)d_in[8], flag);
    las_convert<<<4096, 256, 0, stream>>>(cv, flag, cw);

    // one-time setup
    las_init<<<256, 256, 0, stream>>>(h00, h01, h02, label, h0f, h1f, h2f, labT);
    las_query<<<2, 256, 0, stream>>>(h02, W_query, b_query, q);
    las_nq<<<2, 256, 0, stream>>>(q, Wq, bq, nq);
    las_wk<<<8, 256, 0, stream>>>(nq, Wk, bk, wk, kb);
    las_attn<<<64, 256, 0, stream>>>(keys, values, input_len, flag, wk, kb, av);
    las_head<<<128, 256, 0, stream>>>(av, Wv, bv, head);
    las_ctx<<<128, 256, 0, stream>>>(head, W_mh, b_mh, ctxT);
    las_embg<<<545, 256, 0, stream>>>(W_emb, Wih0, embg);
    las_ctxg<<<1024, 256, 0, stream>>>(ctxT, Wih0, bih0, bhh0, ctxg);
    las_ctxp1<<<128, 256, 0, stream>>>(ctxT, W_p1, b_p1, ctxp1);

    // full decode: one persistent layer-pipelined MFMA kernel (8-wave k-split)
    las_decode<<<256, 512, 0, stream>>>(
        embg, ctxg, ctxp1, labT,
        Whh0, Wih1, Whh1, bih1, bhh1,
        Wih2, Whh2, bih2, bhh2,
        W_p1, W_emb, b_proj2,
        c00, c01, c02,
        h0f, h1f, h2f, ybuf,
        flag, d_out);

    int n_out = 64 * 255 * 34;
    las_nanscan<<<(n_out + 255) / 256, 256, 0, stream>>>(d_out, flag, flag + 1, n_out);
    las_nansig<<<1, 64, 0, stream>>>(d_out, flag, flag + 1);
}

// Round 6
// 4167.999 us; speedup vs baseline: 13.7461x; 1.5705x over previous
//
#include <hip/hip_runtime.h>

typedef unsigned short u16;
typedef unsigned int   u32;
typedef float f32x4 __attribute__((ext_vector_type(4)));
typedef short short8 __attribute__((ext_vector_type(8)));

#define SCALE_F 0.08838834764831845f  // 1/sqrt(128)

// ---------- ws layout (float offsets) ----------
#define O_QUERY  0           // 512
#define O_NQ     512         // 512
#define O_WK     1024        // 2048
#define O_KB     3072        // 4  (flag ints at 3080..: [0]=isbf16 [1]=nan [16..271]=arrive,
                             //     [512+32*i] i<8 = release fanout copies)
#define O_FLAG   3080
#define O_AV     4096        // 64*4*512 = 131072
#define O_HEAD   135168      // 64*512  = 32768
#define O_CTXT   167936      // 512*64  = 32768
#define O_EMBG   200704      // 4096*34 = 139264
#define O_CTXG   339968      // 4096*64 = 262144
#define O_CTXP1  602112      // 512*64  = 32768
#define O_H0T    634880      // h0 frag bf16 [2 parity][2 hi/lo][65536] = 131072 floats
#define O_C0T    765952      // y[2][32768] f32 = 65536 floats (repurposed)
#define O_H1T    831488      // h1 frag = 131072 floats
#define O_C1T    962560      // (unused)
#define O_H2T    1028096     // h2 frag [2][2][32768] = 65536 floats
#define O_C2T    1093632     // (unused)
#define O_YT     1126400     // (unused)
#define O_LABT   1159168     // 255*64 ints
#define O_CANON  1175552     // canonical bf16 weights start (u16 ofs = 2*O_CANON)

__device__ __forceinline__ float bfc(u16 x) {
    return __uint_as_float(((u32)x) << 16);
}
__device__ __forceinline__ float2 bfpair(u32 u) {
    return make_float2(__uint_as_float(u << 16), __uint_as_float(u & 0xffff0000u));
}
__device__ __forceinline__ u16 f2bf(float f) {
    u32 u = __float_as_uint(f);
    u += 0x7fffu + ((u >> 16) & 1u);
    return (u16)(u >> 16);
}
__device__ __forceinline__ float sigf(float x) { return 1.0f / (1.0f + __expf(-x)); }
__device__ __forceinline__ float tanh_(float x) { return 2.0f / (1.0f + __expf(-2.0f * x)) - 1.0f; }

__device__ __forceinline__ void fma8(float& acc, uint4 a, const float h[8]) {
    float2 p;
    p = bfpair(a.x); acc = fmaf(h[0], p.x, acc); acc = fmaf(h[1], p.y, acc);
    p = bfpair(a.y); acc = fmaf(h[2], p.x, acc); acc = fmaf(h[3], p.y, acc);
    p = bfpair(a.z); acc = fmaf(h[4], p.x, acc); acc = fmaf(h[5], p.y, acc);
    p = bfpair(a.w); acc = fmaf(h[6], p.x, acc); acc = fmaf(h[7], p.y, acc);
}

__device__ __forceinline__ f32x4 mfma16(short8 a, short8 b, f32x4 c) {
    return __builtin_amdgcn_mfma_f32_16x16x32_bf16(a, b, c, 0, 0, 0);
}
__device__ __forceinline__ short8 ld8g(const u16* p) {
    uint4 v = *(const uint4*)p;
    return __builtin_bit_cast(short8, v);
}
// frag index of element (k,col) in a B-frag-layout h buffer
__device__ __forceinline__ int fidx(int k, int col) {
    return ((k >> 5) * 4 + (col >> 4)) * 512 + (((k >> 2) & 3) * 16 + (col & 15)) * 8 +
           ((k >> 4) & 1) * 4 + (k & 3);
}
// producer store: write-through to LLC (agent-scope relaxed atomic -> sc1) so the
// grid barrier needs NO release fence (no buffer_wbl2 walk per tick).
__device__ __forceinline__ void storeH(u16* buf, int HL, int bx, int w, int l, float v) {
    int idx = ((bx >> 3) * 4 + w) * 512 + ((bx & 3) * 16 + (l & 15)) * 8 +
              ((bx >> 2) & 1) * 4 + (l >> 4);
    u16 hi = f2bf(v);
    __hip_atomic_store(&buf[idx], hi, __ATOMIC_RELAXED, __HIP_MEMORY_SCOPE_AGENT);
    __hip_atomic_store(&buf[idx + HL], f2bf(v - bfc(hi)),
                       __ATOMIC_RELAXED, __HIP_MEMORY_SCOPE_AGENT);
}

// ---------------- dtype detect + canonicalize ----------------

__global__ __launch_bounds__(256) void las_detect(const u16* w, int* flag) {
    __shared__ int s[256];
    int bad = 0;
    for (int i = threadIdx.x; i < 65536; i += 256) {
        u16 v = w[i];
        if ((v & 0x7F80u) == 0x7F80u) bad++;
        else if (fabsf(bfc(v)) > 1e4f) bad++;
    }
    s[threadIdx.x] = bad; __syncthreads();
    for (int o = 128; o; o >>= 1) {
        if (threadIdx.x < o) s[threadIdx.x] += s[threadIdx.x + o];
        __syncthreads();
    }
    flag[16 + threadIdx.x] = 0;                       // arrive slots
    if (threadIdx.x < 8) flag[512 + threadIdx.x * 32] = 0;  // release fanout copies
    if (threadIdx.x == 0) { flag[0] = (s[0] == 0) ? 1 : 0; flag[1] = 0; }
}

#define NSEG 32
struct Cvt {
    const void* src[NSEG];
    unsigned ofs[NSEG + 1];
    unsigned len[NSEG];
};

__global__ __launch_bounds__(256) void las_convert(Cvt c, const int* flag, u16* dst) {
    int isb = flag[0];
    unsigned total = c.ofs[NSEG] >> 1;
    for (unsigned p = blockIdx.x * 256 + threadIdx.x; p < total; p += gridDim.x * 256) {
        unsigned e = p << 1;
        int lo = 0, hi = NSEG;
        while (hi - lo > 1) { int mid = (lo + hi) >> 1; if (c.ofs[mid] <= e) lo = mid; else hi = mid; }
        unsigned local = e - c.ofs[lo];
        u32 out;
        if (local >= c.len[lo]) {
            out = 0;
        } else if (isb) {
            out = ((const u32*)c.src[lo])[local >> 1];
        } else {
            const float* s = (const float*)c.src[lo];
            u32 a = f2bf(s[local]), b = f2bf(s[local + 1]);
            out = a | (b << 16);
        }
        ((u32*)dst)[p] = out;
    }
}

// ---------------- one-time kernels ----------------

// initial states go to PARITY 1 (tick 0 reads parity 1 for all three h buffers)
__global__ __launch_bounds__(256) void las_init(
    const u16* h00, const u16* h01, const u16* h02, const int* label,
    u16* h0f, u16* h1f, u16* h2f, int* labT) {
    int idx = blockIdx.x * 256 + threadIdx.x;   // 65536 threads
    int k = idx >> 6, col = idx & 63;
    int fi = fidx(k, col);
    h0f[131072 + fi] = h00[k]; h0f[131072 + 65536 + fi] = 0;
    h1f[131072 + fi] = h01[k]; h1f[131072 + 65536 + fi] = 0;
    if (k < 512) { h2f[65536 + fi] = h02[k]; h2f[65536 + 32768 + fi] = 0; }
    if (k < 255) labT[idx] = label[col * 256 + k];
}

__global__ __launch_bounds__(256) void las_query(const u16* h02, const u16* W_query,
                                                 const u16* b_query, float* query) {
    int i = blockIdx.x * 256 + threadIdx.x;     // < 512
    float acc = bfc(b_query[i]);
    const u32* wr = (const u32*)(W_query + (size_t)i * 512);
    const u32* hp = (const u32*)h02;
    for (int h = 0; h < 512; h += 8) {
        uint4 wv = *(const uint4*)(wr + (h >> 1));
        uint4 hv = *(const uint4*)(hp + (h >> 1));
        float2 a, c;
        a = bfpair(wv.x); c = bfpair(hv.x); acc = fmaf(a.x, c.x, acc); acc = fmaf(a.y, c.y, acc);
        a = bfpair(wv.y); c = bfpair(hv.y); acc = fmaf(a.x, c.x, acc); acc = fmaf(a.y, c.y, acc);
        a = bfpair(wv.z); c = bfpair(hv.z); acc = fmaf(a.x, c.x, acc); acc = fmaf(a.y, c.y, acc);
        a = bfpair(wv.w); c = bfpair(hv.w); acc = fmaf(a.x, c.x, acc); acc = fmaf(a.y, c.y, acc);
    }
    query[i] = acc;
}

__global__ __launch_bounds__(256) void las_nq(const float* query, const u16* Wq,
                                              const u16* bq, float* nq) {
    int nd = blockIdx.x * 256 + threadIdx.x;    // < 512
    float acc = bfc(bq[nd]);
    const u32* wr = (const u32*)(Wq + (size_t)nd * 512);
    for (int h = 0; h < 512; h += 8) {
        uint4 wv = *(const uint4*)(wr + (h >> 1));
        float2 p;
        p = bfpair(wv.x); acc = fmaf(p.x, query[h + 0], acc); acc = fmaf(p.y, query[h + 1], acc);
        p = bfpair(wv.y); acc = fmaf(p.x, query[h + 2], acc); acc = fmaf(p.y, query[h + 3], acc);
        p = bfpair(wv.z); acc = fmaf(p.x, query[h + 4], acc); acc = fmaf(p.y, query[h + 5], acc);
        p = bfpair(wv.w); acc = fmaf(p.x, query[h + 6], acc); acc = fmaf(p.y, query[h + 7], acc);
    }
    nq[nd] = acc;
}

__global__ __launch_bounds__(256) void las_wk(const float* nq, const u16* Wk, const u16* bk,
                                              float* wk, float* kb) {
    int idx = blockIdx.x * 256 + threadIdx.x;   // < 2048
    int n = idx >> 9, h = idx & 511;
    float acc = 0.0f;
    for (int d = 0; d < 128; d++)
        acc = fmaf(nq[n * 128 + d], bfc(Wk[((size_t)(n * 128 + d)) * 512 + h]), acc);
    wk[idx] = acc;
    if (idx < 4) {
        float kk = 0.0f;
        for (int d = 0; d < 128; d++) kk = fmaf(nq[idx * 128 + d], bfc(bk[idx * 128 + d]), kk);
        kb[idx] = kk;
    }
}

__global__ __launch_bounds__(256) void las_attn(const void* keysv, const void* valuesv,
                                                const int* input_len, const int* flag,
                                                const float* wk, const float* kb, float* av) {
    __shared__ float wk_s[2048];
    __shared__ float kb_s[4];
    __shared__ float sm[4][1024];
    __shared__ float red[256];
    __shared__ float stat[4];
    const u16* keysB = (const u16*)keysv;
    const float* keysF = (const float*)keysv;
    const u16* valB = (const u16*)valuesv;
    const float* valF = (const float*)valuesv;
    int b = blockIdx.x;
    int tid = threadIdx.x;
    int isb = flag[0];
    for (int i = tid; i < 2048; i += 256) wk_s[i] = wk[i];
    if (tid < 4) kb_s[tid] = kb[tid];
    __syncthreads();
    int len = input_len[b];

    {
        float acc[4][4];
#pragma unroll
        for (int tl = 0; tl < 4; tl++)
#pragma unroll
            for (int n = 0; n < 4; n++) acc[tl][n] = kb_s[n];
        for (int h = 0; h < 512; h += 8) {
            float kf[4][8];
#pragma unroll
            for (int tl = 0; tl < 4; tl++) {
                int t = tid + 256 * tl;
                size_t base = ((size_t)t * 64 + b) * 512 + h;
                if (isb) {
                    uint4 kv = *(const uint4*)(keysB + base);
                    float2 p;
                    p = bfpair(kv.x); kf[tl][0] = p.x; kf[tl][1] = p.y;
                    p = bfpair(kv.y); kf[tl][2] = p.x; kf[tl][3] = p.y;
                    p = bfpair(kv.z); kf[tl][4] = p.x; kf[tl][5] = p.y;
                    p = bfpair(kv.w); kf[tl][6] = p.x; kf[tl][7] = p.y;
                } else {
                    const float4* kp = (const float4*)(keysF + base);
                    float4 q0 = kp[0], q1 = kp[1];
                    kf[tl][0] = q0.x; kf[tl][1] = q0.y; kf[tl][2] = q0.z; kf[tl][3] = q0.w;
                    kf[tl][4] = q1.x; kf[tl][5] = q1.y; kf[tl][6] = q1.z; kf[tl][7] = q1.w;
                }
            }
#pragma unroll
            for (int i = 0; i < 8; i++) {
                float w0 = wk_s[h + i], w1 = wk_s[512 + h + i];
                float w2 = wk_s[1024 + h + i], w3 = wk_s[1536 + h + i];
#pragma unroll
                for (int tl = 0; tl < 4; tl++) {
                    acc[tl][0] = fmaf(kf[tl][i], w0, acc[tl][0]);
                    acc[tl][1] = fmaf(kf[tl][i], w1, acc[tl][1]);
                    acc[tl][2] = fmaf(kf[tl][i], w2, acc[tl][2]);
                    acc[tl][3] = fmaf(kf[tl][i], w3, acc[tl][3]);
                }
            }
        }
#pragma unroll
        for (int tl = 0; tl < 4; tl++) {
            int t = tid + 256 * tl;
#pragma unroll
            for (int n = 0; n < 4; n++)
                sm[n][t] = (t < len) ? acc[tl][n] * SCALE_F : -1e30f;
        }
    }
    __syncthreads();

    for (int n = 0; n < 4; n++) {
        float m = -1e30f;
        for (int tl = 0; tl < 4; tl++) m = fmaxf(m, sm[n][tid + 256 * tl]);
        red[tid] = m; __syncthreads();
        for (int off = 128; off; off >>= 1) {
            if (tid < off) red[tid] = fmaxf(red[tid], red[tid + off]);
            __syncthreads();
        }
        m = red[0]; __syncthreads();
        float e = 0.0f;
        for (int tl = 0; tl < 4; tl++) {
            int t = tid + 256 * tl;
            float x = (t < len) ? __expf(sm[n][t] - m) : 0.0f;
            sm[n][t] = x; e += x;
        }
        red[tid] = e; __syncthreads();
        for (int off = 128; off; off >>= 1) {
            if (tid < off) red[tid] += red[tid + off];
            __syncthreads();
        }
        if (tid == 0) stat[n] = 1.0f / red[0];
        __syncthreads();
    }

    {
        float a[4][2] = {};
        int h0 = 2 * tid;
        for (int t = 0; t < len; t++) {
            size_t base = ((size_t)t * 64 + b) * 512 + h0;
            float2 p;
            if (isb) p = bfpair(*(const u32*)(valB + base));
            else     p = *(const float2*)(valF + base);
            float s0 = sm[0][t], s1 = sm[1][t], s2 = sm[2][t], s3 = sm[3][t];
            a[0][0] = fmaf(s0, p.x, a[0][0]); a[0][1] = fmaf(s0, p.y, a[0][1]);
            a[1][0] = fmaf(s1, p.x, a[1][0]); a[1][1] = fmaf(s1, p.y, a[1][1]);
            a[2][0] = fmaf(s2, p.x, a[2][0]); a[2][1] = fmaf(s2, p.y, a[2][1]);
            a[3][0] = fmaf(s3, p.x, a[3][0]); a[3][1] = fmaf(s3, p.y, a[3][1]);
        }
#pragma unroll
        for (int n = 0; n < 4; n++) {
            av[((size_t)b * 4 + n) * 512 + h0]     = a[n][0] * stat[n];
            av[((size_t)b * 4 + n) * 512 + h0 + 1] = a[n][1] * stat[n];
        }
    }
}

__global__ __launch_bounds__(256) void las_head(const float* av, const u16* Wv, const u16* bv,
                                                float* head) {
    int idx = blockIdx.x * 256 + threadIdx.x;   // < 32768
    int b = idx >> 9, nd = idx & 511, n = nd >> 7;
    float acc = bfc(bv[nd]);
    const u32* wr = (const u32*)(Wv + (size_t)nd * 512);
    const float* ap = av + ((size_t)b * 4 + n) * 512;
    for (int h = 0; h < 512; h += 8) {
        uint4 wv = *(const uint4*)(wr + (h >> 1));
        float2 p;
        p = bfpair(wv.x); acc = fmaf(p.x, ap[h + 0], acc); acc = fmaf(p.y, ap[h + 1], acc);
        p = bfpair(wv.y); acc = fmaf(p.x, ap[h + 2], acc); acc = fmaf(p.y, ap[h + 3], acc);
        p = bfpair(wv.z); acc = fmaf(p.x, ap[h + 4], acc); acc = fmaf(p.y, ap[h + 5], acc);
        p = bfpair(wv.w); acc = fmaf(p.x, ap[h + 6], acc); acc = fmaf(p.y, ap[h + 7], acc);
    }
    head[idx] = acc;
}

__global__ __launch_bounds__(256) void las_ctx(const float* head, const u16* W_mh, const u16* b_mh,
                                               float* ctxT) {
    int idx = blockIdx.x * 256 + threadIdx.x;   // < 32768
    int b = idx >> 9, i = idx & 511;
    float acc = bfc(b_mh[i]);
    const u32* wr = (const u32*)(W_mh + (size_t)i * 512);
    const float* hp = head + (size_t)b * 512;
    for (int h = 0; h < 512; h += 8) {
        uint4 wv = *(const uint4*)(wr + (h >> 1));
        float2 p;
        p = bfpair(wv.x); acc = fmaf(p.x, hp[h + 0], acc); acc = fmaf(p.y, hp[h + 1], acc);
        p = bfpair(wv.y); acc = fmaf(p.x, hp[h + 2], acc); acc = fmaf(p.y, hp[h + 3], acc);
        p = bfpair(wv.z); acc = fmaf(p.x, hp[h + 4], acc); acc = fmaf(p.y, hp[h + 5], acc);
        p = bfpair(wv.w); acc = fmaf(p.x, hp[h + 6], acc); acc = fmaf(p.y, hp[h + 7], acc);
    }
    ctxT[(size_t)i * 64 + b] = acc;
}

__global__ __launch_bounds__(256) void las_embg(const u16* W_emb, const u16* Wih0, float* embg) {
    int idx = blockIdx.x * 256 + threadIdx.x;
    if (idx >= 4096 * 34) return;
    int row = idx / 34, v = idx - row * 34;
    const u32* wr = (const u32*)(Wih0 + (size_t)row * 1024);
    const u32* er = (const u32*)(W_emb + (size_t)v * 512);
    float acc = 0.0f;
    for (int h = 0; h < 512; h += 8) {
        uint4 wv = *(const uint4*)(wr + (h >> 1));
        uint4 ev = *(const uint4*)(er + (h >> 1));
        float2 a, c;
        a = bfpair(wv.x); c = bfpair(ev.x); acc = fmaf(a.x, c.x, acc); acc = fmaf(a.y, c.y, acc);
        a = bfpair(wv.y); c = bfpair(ev.y); acc = fmaf(a.x, c.x, acc); acc = fmaf(a.y, c.y, acc);
        a = bfpair(wv.z); c = bfpair(ev.z); acc = fmaf(a.x, c.x, acc); acc = fmaf(a.y, c.y, acc);
        a = bfpair(wv.w); c = bfpair(ev.w); acc = fmaf(a.x, c.x, acc); acc = fmaf(a.y, c.y, acc);
    }
    embg[idx] = acc;
}

__global__ __launch_bounds__(256) void las_ctxg(const float* ctxT, const u16* Wih0,
                                                const u16* bih0, const u16* bhh0, float* ctxg) {
    int lane = threadIdx.x & 63, w = threadIdx.x >> 6;
    int row = blockIdx.x * 4 + w;               // < 4096
    float acc = bfc(bih0[row]) + bfc(bhh0[row]);
    const u32* wr = (const u32*)(Wih0 + (size_t)row * 1024 + 512);
    for (int h = 0; h < 512; h += 8) {
        float hv[8];
#pragma unroll
        for (int i = 0; i < 8; i++) hv[i] = ctxT[(size_t)(h + i) * 64 + lane];
        uint4 wv = *(const uint4*)(wr + (h >> 1));
        fma8(acc, wv, hv);
    }
    ctxg[(size_t)row * 64 + lane] = acc;
}

__global__ __launch_bounds__(256) void las_ctxp1(const float* ctxT, const u16* W_p1,
                                                 const u16* b_p1, float* ctxp1) {
    int lane = threadIdx.x & 63, w = threadIdx.x >> 6;
    int i = blockIdx.x * 4 + w;                 // < 512
    float acc = bfc(b_p1[i]);
    const u32* wr = (const u32*)(W_p1 + (size_t)i * 1024 + 512);
    for (int h = 0; h < 512; h += 8) {
        float hv[8];
#pragma unroll
        for (int k = 0; k < 8; k++) hv[k] = ctxT[(size_t)(h + k) * 64 + lane];
        uint4 wv = *(const uint4*)(wr + (h >> 1));
        fma8(acc, wv, hv);
    }
    ctxp1[(size_t)i * 64 + lane] = acc;
}

// ---------------- persistent MFMA decode kernel (layer-pipelined, 8-wave k-split) ----
// As R5, plus: (1) cross-block stores are write-through (agent relaxed atomics, sc1)
// so the barrier has NO release fence (no buffer_wbl2 walk per tick); acquire-inv
// kept (cheap tag flash, lets h loads share L2 within a tick). (2) p3b staged:
// W_emb lives in A2 LDS for blocks 160-223 and the projection is k-split across
// all 8 waves (was a 64-deep single-wave chain on L2-cold W_emb = per-tick straggler).

__device__ __forceinline__ void gridbar(int* arr, int* relv, int epoch) {
    asm volatile("s_waitcnt vmcnt(0)" ::: "memory");  // write-through stores at LLC
    __syncthreads();
    const int bx = blockIdx.x;
    if (threadIdx.x == 0) {
        __hip_atomic_store(&arr[bx], epoch, __ATOMIC_RELAXED, __HIP_MEMORY_SCOPE_AGENT);
    }
    if (bx == 255 && threadIdx.x < 64) {          // aggregator wave
        int iters = 0;
        for (;;) {
            int ok = 1;
#pragma unroll
            for (int q = 0; q < 4; q++) {
                int v = __hip_atomic_load(&arr[threadIdx.x * 4 + q],
                                          __ATOMIC_RELAXED, __HIP_MEMORY_SCOPE_AGENT);
                ok &= (v >= epoch);
            }
            if (__all(ok)) break;
            if (++iters > (1 << 20)) break;       // bounded: corrupts instead of hanging
            __builtin_amdgcn_s_sleep(1);
        }
        if (threadIdx.x < 8)                      // fan release out to 8 lines
            __hip_atomic_store(&relv[threadIdx.x * 32], epoch,
                               __ATOMIC_RELAXED, __HIP_MEMORY_SCOPE_AGENT);
    }
    if (threadIdx.x == 0) {
        int* myrel = relv + (blockIdx.x >> 5) * 32;   // 32 blocks per release line
        int iters = 0;
        while (__hip_atomic_load(myrel, __ATOMIC_RELAXED, __HIP_MEMORY_SCOPE_AGENT) < epoch) {
            __builtin_amdgcn_s_sleep(2);
            if (++iters > (1 << 20)) break;
        }
        __builtin_amdgcn_fence(__ATOMIC_ACQUIRE, "agent");   // inv L1+L2 (cheap)
    }
    __syncthreads();
}

__global__ __launch_bounds__(512, 1) void las_decode(
    const float* embg, const float* ctxg, const float* ctxp1, const int* labT,
    const u16* Whh0, const u16* Wih1, const u16* Whh1,
    const u16* bih1, const u16* bhh1,
    const u16* Wih2, const u16* Whh2, const u16* bih2, const u16* bhh2,
    const u16* W_p1, const u16* W_emb, const u16* b_proj2,
    const u16* c00, const u16* c01, const u16* c02,
    u16* h0f, u16* h1f, u16* h2f, float* ybuf,
    int* flag, void* outp) {

    __shared__ __align__(16) u16 A0[32 * 64 * 8];   // 32 KB  Whh0 A-frags
    __shared__ __align__(16) u16 A1[64 * 64 * 8];   // 64 KB  Wih1|Whh1 A-frags
    __shared__ __align__(16) u16 A2[48 * 64 * 8];   // 48 KB  Wih2|Whh2 | W_p1 | W_emb(row-major)
    // union: k-split reduce pad-9 (4*64*9=2304 floats) OR p3b {ylds[512] + partials[512]}
    __shared__ float scratch[2304];                 //  9 KB

    const int tid = threadIdx.x, l = tid & 63, w = tid >> 6;   // w 0..7
    const int cw = w & 3;                            // column-wave (16 cols each)
    const int kh = w >> 2;                           // k-half
    const int bx = blockIdx.x;
    const int isb = flag[0];
    int* arr  = flag + 16;
    int* relv = flag + 512;
    const int HL0 = 65536, HL2 = 32768;
    const int rot16 = bx & 15, rot8 = bx & 7;        // de-phase LLC traffic across blocks

    // ---- stage A-fragments once ----
    for (int i = tid; i < 32 * 64 * 2; i += 512) {
        int kt = i >> 7, ll = (i >> 1) & 63, half = i & 1;
        int r = ll & 15;
        int row = (r & 3) * 1024 + 4 * bx + (r >> 2);
        int kc = kt * 32 + half * 16 + 4 * (ll >> 4);
        *(uint2*)&A0[(kt * 64 + ll) * 8 + half * 4] = *(const uint2*)(Whh0 + (size_t)row * 1024 + kc);
    }
    for (int i = tid; i < 64 * 64 * 2; i += 512) {
        int kt = i >> 7, ll = (i >> 1) & 63, half = i & 1;
        int r = ll & 15;
        int row = (r & 3) * 1024 + 4 * bx + (r >> 2);
        int kc = kt * 32 + half * 16 + 4 * (ll >> 4);
        const u16* src = (kc < 1024) ? (Wih1 + (size_t)row * 1024 + kc)
                                     : (Whh1 + (size_t)row * 1024 + (kc - 1024));
        *(uint2*)&A1[(kt * 64 + ll) * 8 + half * 4] = *(const uint2*)src;
    }
    if (bx < 128) {
        for (int i = tid; i < 48 * 64 * 2; i += 512) {
            int kt = i >> 7, ll = (i >> 1) & 63, half = i & 1;
            int r = ll & 15;
            int row = (r & 3) * 512 + 4 * bx + (r >> 2);
            int kc = kt * 32 + half * 16 + 4 * (ll >> 4);
            const u16* src = (kc < 1024) ? (Wih2 + (size_t)row * 1024 + kc)
                                         : (Whh2 + (size_t)row * 512 + (kc - 1024));
            *(uint2*)&A2[(kt * 64 + ll) * 8 + half * 4] = *(const uint2*)src;
        }
    } else if (bx < 160) {
        int mt = bx - 128;
        for (int i = tid; i < 16 * 64 * 2; i += 512) {
            int kt = i >> 7, ll = (i >> 1) & 63, half = i & 1;
            int row = 16 * mt + (ll & 15);
            int kc = kt * 32 + half * 16 + 4 * (ll >> 4);
            *(uint2*)&A2[(kt * 64 + ll) * 8 + half * 4] = *(const uint2*)(W_p1 + (size_t)row * 1024 + kc);
        }
    } else if (bx < 224) {
        // stage W_emb [34][512] bf16 row-major into A2 (17408 u16 = 2176 uint4)
        for (int i = tid; i < 2176; i += 512)
            *(uint4*)&A2[i * 8] = *(const uint4*)(W_emb + (size_t)i * 8);
    }

    // ---- persistent per-lane state (meaningful on waves 0-3) ----
    const int cell01 = 4 * bx + (l >> 4);
    const int bcol = cw * 16 + (l & 15);
    float c0reg = bfc(c00[cell01]);
    float c1reg = bfc(c01[cell01]);
    float pre0c[4], pre1c[4], pre2c[4], prep3[4];
#pragma unroll
    for (int r = 0; r < 4; r++) {
        int row = r * 1024 + cell01;
        pre0c[r] = ctxg[(size_t)row * 64 + bcol];
        pre1c[r] = bfc(bih1[row]) + bfc(bhh1[row]);
        pre2c[r] = 0.0f; prep3[r] = 0.0f;
    }
    float c2reg = 0.0f;
    if (bx < 128) {
        int cell2 = 4 * bx + (l >> 4);
        c2reg = bfc(c02[cell2]);
#pragma unroll
        for (int r = 0; r < 4; r++) {
            int row = r * 512 + cell2;
            pre2c[r] = bfc(bih2[row]) + bfc(bhh2[row]);
        }
    } else if (bx < 160) {
#pragma unroll
        for (int r = 0; r < 4; r++) {
            int yi = 16 * (bx - 128) + 4 * (l >> 4) + r;
            prep3[r] = ctxp1[(size_t)yi * 64 + bcol];
        }
    }

    // cross-wave k-split reduce: upper waves publish, lower waves accumulate
    auto reduce8 = [&](f32x4& xh, f32x4& xl) {
        __syncthreads();
        if (w >= 4) {
            float* r = &scratch[((w - 4) * 64 + l) * 9];
#pragma unroll
            for (int i = 0; i < 4; i++) { r[i] = xh[i]; r[4 + i] = xl[i]; }
        }
        __syncthreads();
        if (w < 4) {
            const float* r = &scratch[(w * 64 + l) * 9];
#pragma unroll
            for (int i = 0; i < 4; i++) { xh[i] += r[i]; xl[i] += r[4 + i]; }
        }
        __syncthreads();                          // buffer reuse guard
    };

    __syncthreads();

    for (int tau = 0; tau < 259; tau++) {
        const bool do0 = (tau < 255);
        const bool do1 = (tau >= 1) && (tau <= 255);
        const bool do2 = (tau >= 2) && (tau <= 256) && (bx < 128);
        const bool do3 = (tau >= 3) && (tau <= 257) && (bx >= 128) && (bx < 160);
        const bool do4 = (tau >= 4) && (bx >= 160) && (bx < 224);

        // parity map: h_X(t) is stored at parity t&1; initial states at parity 1
        const u16* h0r = h0f + ((tau + 1) & 1) * 131072;   // h0(tau-1)
        u16*       h0w = h0f + (tau & 1) * 131072;         // h0(tau)
        const u16* h1r = h1f + (tau & 1) * 131072;         // h1(tau-2)
        u16*       h1w = h1f + ((tau + 1) & 1) * 131072;   // h1(tau-1)
        const u16* h2r = h2f + ((tau + 1) & 1) * 65536;    // h2(tau-3)
        u16*       h2w = h2f + (tau & 1) * 65536;          // h2(tau-2)
        float*     yw  = ybuf + ((tau + 1) & 1) * 32768;   // y(tau-3)
        const float* yr = ybuf + (tau & 1) * 32768;        // y(tau-4)

        // early issue: l0 gather chain (labT -> embg) hides under the sweeps
        int vb = 0; float e0 = 0.f, e1 = 0.f, e2 = 0.f, e3 = 0.f;
        if (do0 && w < 4) {
            vb = labT[tau * 64 + bcol];
            e0 = embg[(size_t)(0 * 1024 + cell01) * 34 + vb];
            e1 = embg[(size_t)(1 * 1024 + cell01) * 34 + vb];
            e2 = embg[(size_t)(2 * 1024 + cell01) * 34 + vb];
            e3 = embg[(size_t)(3 * 1024 + cell01) * 34 + vb];
        }

        f32x4 a0h = {0.f,0.f,0.f,0.f}, a0l = {0.f,0.f,0.f,0.f};
        f32x4 a1h = {0.f,0.f,0.f,0.f}, a1l = {0.f,0.f,0.f,0.f};
        f32x4 a2h = {0.f,0.f,0.f,0.f}, a2l = {0.f,0.f,0.f,0.f};

        // ---- h0(tau-1) half-sweep: feeds l0 (A0) and l1-x (A1[0..31]) ----
#pragma unroll 8
        for (int i = 0; i < 16; i++) {
            int kt = kh * 16 + ((i + rot16) & 15);
            const u16* bp = h0r + (kt * 4 + cw) * 512 + l * 8;
            short8 bh = ld8g(bp), bl = ld8g(bp + HL0);
            short8 aA = *(const short8*)&A0[(kt * 64 + l) * 8];
            short8 aB = *(const short8*)&A1[(kt * 64 + l) * 8];
            a0h = mfma16(aA, bh, a0h); a0l = mfma16(aA, bl, a0l);
            a1h = mfma16(aB, bh, a1h); a1l = mfma16(aB, bl, a1l);
        }
        if (bx < 128) {
            // ---- h1(tau-2) half-sweep: l1-h (A1[32..63]) + l2-x (A2[0..31]) ----
#pragma unroll 8
            for (int i = 0; i < 16; i++) {
                int kt = kh * 16 + ((i + rot16) & 15);
                const u16* bp = h1r + (kt * 4 + cw) * 512 + l * 8;
                short8 bh = ld8g(bp), bl = ld8g(bp + HL0);
                short8 aB = *(const short8*)&A1[((32 + kt) * 64 + l) * 8];
                short8 aC = *(const short8*)&A2[(kt * 64 + l) * 8];
                a1h = mfma16(aB, bh, a1h); a1l = mfma16(aB, bl, a1l);
                a2h = mfma16(aC, bh, a2h); a2l = mfma16(aC, bl, a2l);
            }
            // ---- h2(tau-3) half-sweep: l2-h (A2[32..47]) ----
#pragma unroll 8
            for (int i = 0; i < 8; i++) {
                int kt = kh * 8 + ((i + rot8) & 7);
                const u16* bp = h2r + (kt * 4 + cw) * 512 + l * 8;
                short8 bh = ld8g(bp), bl = ld8g(bp + HL2);
                short8 aC = *(const short8*)&A2[((32 + kt) * 64 + l) * 8];
                a2h = mfma16(aC, bh, a2h); a2l = mfma16(aC, bl, a2l);
            }
        } else {
#pragma unroll 8
            for (int i = 0; i < 16; i++) {
                int kt = kh * 16 + ((i + rot16) & 15);
                const u16* bp = h1r + (kt * 4 + cw) * 512 + l * 8;
                short8 bh = ld8g(bp), bl = ld8g(bp + HL0);
                short8 aB = *(const short8*)&A1[((32 + kt) * 64 + l) * 8];
                a1h = mfma16(aB, bh, a1h); a1l = mfma16(aB, bl, a1l);
            }
            if (bx < 160) {
                // p3a: h2(tau-3) half-sweep with W_p1 frags (A2[0..15])
#pragma unroll 8
                for (int i = 0; i < 8; i++) {
                    int kt = kh * 8 + ((i + rot8) & 7);
                    const u16* bp = h2r + (kt * 4 + cw) * 512 + l * 8;
                    short8 bh = ld8g(bp), bl = ld8g(bp + HL2);
                    short8 aC = *(const short8*)&A2[(kt * 64 + l) * 8];
                    a2h = mfma16(aC, bh, a2h); a2l = mfma16(aC, bl, a2l);
                }
            }
        }

        // ---- combine k-halves ----
        reduce8(a0h, a0l);
        reduce8(a1h, a1l);
        if (bx < 160) reduce8(a2h, a2l);

        // ---- epilogues (waves 0-3 hold the reduced sums) ----
        if (do0 && w < 4) {                           // l0(tau)
            float g0 = a0h[0] + a0l[0] + pre0c[0] + e0;
            float g1 = a0h[1] + a0l[1] + pre0c[1] + e1;
            float g2 = a0h[2] + a0l[2] + pre0c[2] + e2;
            float g3 = a0h[3] + a0l[3] + pre0c[3] + e3;
            float c2 = fmaf(sigf(g1), c0reg, sigf(g0) * tanh_(g2));
            c0reg = c2;
            storeH(h0w, HL0, bx, w, l, sigf(g3) * tanh_(c2));
        }
        if (do1 && w < 4) {                           // l1(tau-1)
            float g0 = a1h[0] + a1l[0] + pre1c[0];
            float g1 = a1h[1] + a1l[1] + pre1c[1];
            float g2 = a1h[2] + a1l[2] + pre1c[2];
            float g3 = a1h[3] + a1l[3] + pre1c[3];
            float c2 = fmaf(sigf(g1), c1reg, sigf(g0) * tanh_(g2));
            c1reg = c2;
            storeH(h1w, HL0, bx, w, l, sigf(g3) * tanh_(c2));
        }
        if (do2 && w < 4) {                           // l2(tau-2)
            float g0 = a2h[0] + a2l[0] + pre2c[0];
            float g1 = a2h[1] + a2l[1] + pre2c[1];
            float g2 = a2h[2] + a2l[2] + pre2c[2];
            float g3 = a2h[3] + a2l[3] + pre2c[3];
            float c2 = fmaf(sigf(g1), c2reg, sigf(g0) * tanh_(g2));
            c2reg = c2;
            storeH(h2w, HL2, bx, w, l, sigf(g3) * tanh_(c2));
        }
        if (do3 && w < 4) {                           // p3a(tau-3)
#pragma unroll
            for (int r = 0; r < 4; r++) {
                float v = a2h[r] + a2l[r] + prep3[r];
                v = v > 0.0f ? v : 0.01f * v;         // leaky_relu
                __hip_atomic_store(&yw[(size_t)(16 * (bx - 128) + 4 * (l >> 4) + r) * 64 + bcol],
                                   v, __ATOMIC_RELAXED, __HIP_MEMORY_SCOPE_AGENT);
            }
        }
        if (do4) {                                    // p3b(tau-4), k-split over 8 waves
            int b = bx - 160;
            scratch[tid] = yr[(size_t)tid * 64 + b];  // ylds: scratch[0..511]
            __syncthreads();
            float pw = 0.0f;
            if (l < 34) {                             // wave w covers k2 in [w*64, w*64+64)
                const u32* wr = (const u32*)&A2[(size_t)l * 512 + w * 64];
                const float* yk = &scratch[w * 64];
#pragma unroll
                for (int k2 = 0; k2 < 64; k2 += 8) {
                    uint4 wv = *(const uint4*)(wr + (k2 >> 1));
                    float2 p;
                    p = bfpair(wv.x); pw = fmaf(p.x, yk[k2 + 0], pw); pw = fmaf(p.y, yk[k2 + 1], pw);
                    p = bfpair(wv.y); pw = fmaf(p.x, yk[k2 + 2], pw); pw = fmaf(p.y, yk[k2 + 3], pw);
                    p = bfpair(wv.z); pw = fmaf(p.x, yk[k2 + 4], pw); pw = fmaf(p.y, yk[k2 + 5], pw);
                    p = bfpair(wv.w); pw = fmaf(p.x, yk[k2 + 6], pw); pw = fmaf(p.y, yk[k2 + 7], pw);
                }
            }
            __syncthreads();                          // ylds reads done before overwrite below
            scratch[512 + w * 64 + l] = pw;           // partials: scratch[512..1023]
            __syncthreads();
            if (w == 0) {
                int v = l;
                float acc = -1e30f;
                if (v < 34) {
                    acc = bfc(b_proj2[v]);
#pragma unroll
                    for (int q = 0; q < 8; q++) acc += scratch[512 + q * 64 + v];
                }
                float m = acc;
                for (int off = 32; off; off >>= 1) m = fmaxf(m, __shfl_xor(m, off, 64));
                float e = (v < 34) ? __expf(acc - m) : 0.0f;
                float s = e;
                for (int off = 32; off; off >>= 1) s += __shfl_xor(s, off, 64);
                if (v < 34) {
                    float rr = acc - m - __logf(s);
                    size_t o = ((size_t)b * 255 + (tau - 4)) * 34 + v;
                    if (isb) ((u16*)outp)[o] = f2bf(rr);
                    else     ((float*)outp)[o] = rr;
                }
            }
            __syncthreads();                          // scratch reused as red next tick
        }

        gridbar(arr, relv, tau + 1);
    }
}

// ---------------- failure instrumentation ----------------

__global__ __launch_bounds__(256) void las_nanscan(const void* outp, const int* flag, int* cnt, int n) {
    int g = blockIdx.x * 256 + threadIdx.x;
    if (g >= n) return;
    bool bad;
    if (flag[0]) {
        u16 v = ((const u16*)outp)[g];
        bad = ((v & 0x7F80u) == 0x7F80u);
    } else {
        float f = ((const float*)outp)[g];
        bad = !isfinite(f);
    }
    if (bad) atomicAdd(cnt, 1);
}

__global__ __launch_bounds__(64) void las_nansig(void* outp, const int* flag, const int* cnt) {
    if (threadIdx.x != 0) return;
    int c = cnt[0];
    if (c > 0) {
        int cc = c < 9999 ? c : 9999;
        float sig = 10000.0f * (float)(1 + flag[0]) + (float)cc;
        if (flag[0]) ((u16*)outp)[0] = f2bf(sig);
        else         ((float*)outp)[0] = sig;
    }
}

// ---------------- host ----------------

extern "C" void kernel_launch(void* const* d_in, const int* in_sizes, int n_in,
                              void* d_out, int out_size, void* d_ws, size_t ws_size,
                              hipStream_t stream) {
    const void* keys     = d_in[0];
    const void* values   = d_in[1];
    const int* label     = (const int*)d_in[2];
    const int* input_len = (const int*)d_in[4];

    float* F     = (float*)d_ws;
    float* q     = F + O_QUERY;
    float* nq    = F + O_NQ;
    float* wk    = F + O_WK;
    float* kb    = F + O_KB;
    int*   flag  = (int*)(F + O_FLAG);
    float* av    = F + O_AV;
    float* head  = F + O_HEAD;
    float* ctxT  = F + O_CTXT;
    float* embg  = F + O_EMBG;
    float* ctxg  = F + O_CTXG;
    float* ctxp1 = F + O_CTXP1;
    float* ybuf  = F + O_C0T;                   // y[2][32768] f32
    int*   labT  = (int*)(F + O_LABT);
    u16*   h0f   = (u16*)(F + O_H0T);           // [2 parity][2 hi/lo][65536] bf16 frag
    u16*   h1f   = (u16*)(F + O_H1T);
    u16*   h2f   = (u16*)(F + O_H2T);           // [2][2][32768]
    u16*   cw    = (u16*)d_ws + 2 * (size_t)O_CANON;

    static const unsigned kLen[NSEG] = {
        17408, 34, 262144, 512, 262144, 512, 262144, 512, 262144, 512,
        262144, 512, 524288, 512, 4194304, 4194304, 4096, 4096, 1024, 1024,
        4194304, 4194304, 4096, 4096, 1024, 1024, 2097152, 1048576, 2048, 2048,
        512, 512
    };
    Cvt cv;
    const u16* cwp[NSEG];
    unsigned o = 0;
    for (int i = 0; i < NSEG; i++) {
        cv.src[i] = d_in[6 + i];
        cv.ofs[i] = o;
        cv.len[i] = kLen[i];
        cwp[i] = cw + o;
        o += (kLen[i] + 7u) & ~7u;
    }
    cv.ofs[NSEG] = o;

    const u16 *W_emb = cwp[0], *b_proj2 = cwp[1], *W_query = cwp[2], *b_query = cwp[3];
    const u16 *Wk = cwp[4], *bk = cwp[5], *Wq = cwp[6], *bq = cwp[7];
    const u16 *Wv = cwp[8], *bv = cwp[9], *W_mh = cwp[10], *b_mh = cwp[11];
    const u16 *W_p1 = cwp[12], *b_p1 = cwp[13], *Wih0 = cwp[14], *Whh0 = cwp[15];
    const u16 *bih0 = cwp[16], *bhh0 = cwp[17], *h00 = cwp[18], *c00 = cwp[19];
    const u16 *Wih1 = cwp[20], *Whh1 = cwp[21], *bih1 = cwp[22], *bhh1 = cwp[23];
    const u16 *h01 = cwp[24], *c01 = cwp[25], *Wih2 = cwp[26], *Whh2 = cwp[27];
    const u16 *bih2 = cwp[28], *bhh2 = cwp[29], *h02 = cwp[30], *c02 = cwp[31];

    // dtype detect + canonicalize (also zeroes nan ctr, release words, arrive slots)
    las_detect<<<1, 256, 0, stream>>>((const u16*)d_in[8], flag);
    las_convert<<<4096, 256, 0, stream>>>(cv, flag, cw);

    // one-time setup
    las_init<<<256, 256, 0, stream>>>(h00, h01, h02, label, h0f, h1f, h2f, labT);
    las_query<<<2, 256, 0, stream>>>(h02, W_query, b_query, q);
    las_nq<<<2, 256, 0, stream>>>(q, Wq, bq, nq);
    las_wk<<<8, 256, 0, stream>>>(nq, Wk, bk, wk, kb);
    las_attn<<<64, 256, 0, stream>>>(keys, values, input_len, flag, wk, kb, av);
    las_head<<<128, 256, 0, stream>>>(av, Wv, bv, head);
    las_ctx<<<128, 256, 0, stream>>>(head, W_mh, b_mh, ctxT);
    las_embg<<<545, 256, 0, stream>>>(W_emb, Wih0, embg);
    las_ctxg<<<1024, 256, 0, stream>>>(ctxT, Wih0, bih0, bhh0, ctxg);
    las_ctxp1<<<128, 256, 0, stream>>>(ctxT, W_p1, b_p1, ctxp1);

    // full decode: one persistent layer-pipelined MFMA kernel (8-wave k-split)
    las_decode<<<256, 512, 0, stream>>>(
        embg, ctxg, ctxp1, labT,
        Whh0, Wih1, Whh1, bih1, bhh1,
        Wih2, Whh2, bih2, bhh2,
        W_p1, W_emb, b_proj2,
        c00, c01, c02,
        h0f, h1f, h2f, ybuf,
        flag, d_out);

    int n_out = 64 * 255 * 34;
    las_nanscan<<<(n_out + 255) / 256, 256, 0, stream>>>(d_out, flag, flag + 1, n_out);
    las_nansig<<<1, 64, 0, stream>>>(d_out, flag, flag + 1);
}